// Round 1
// baseline (582.309 us; speedup 1.0000x reference)
//
#include <hip/hip_runtime.h>
#include <hip/hip_bf16.h>

#define BB 64
#define NN 512
#define DIN 33
#define DD 32
#define EE 8192
#define NHEADS 4
#define DH 8
#define FFD 64

// ---------------------------------------------------------------------------
// CSR build: one block, 512 threads. cnt per dst node, offsets, src lists.
// ---------------------------------------------------------------------------
__global__ __launch_bounds__(512) void k_csr(const int* __restrict__ ei,
                                             float* __restrict__ cnt_f,
                                             int* __restrict__ csr_off,
                                             int* __restrict__ csr_src) {
    __shared__ int cnt_s[NN];
    __shared__ int off_s[NN + 1];
    int tid = threadIdx.x;
    cnt_s[tid] = 0;
    __syncthreads();
    const int* src = ei;
    const int* dst = ei + EE;
    for (int e = tid; e < EE; e += 512) atomicAdd(&cnt_s[dst[e]], 1);
    __syncthreads();
    if (tid == 0) {
        int acc = 0;
        for (int n = 0; n < NN; ++n) { off_s[n] = acc; acc += cnt_s[n]; }
        off_s[NN] = acc;
    }
    __syncthreads();
    cnt_f[tid] = (float)cnt_s[tid];
    csr_off[tid] = off_s[tid];
    if (tid == 0) csr_off[NN] = off_s[NN];
    cnt_s[tid] = off_s[tid];   // reuse as cursors
    __syncthreads();
    for (int e = tid; e < EE; e += 512) {
        int d = dst[e];
        int p = atomicAdd(&cnt_s[d], 1);
        csr_src[p] = src[e];
    }
}

// ---------------------------------------------------------------------------
// Embedding: relu(H@W1+b1) -> relu(@W2+b2) -> LN.  8 nodes/block, 32 lanes/node.
// ---------------------------------------------------------------------------
__global__ __launch_bounds__(256) void k_emb(const float* __restrict__ H,
                                             const float* __restrict__ W1, const float* __restrict__ b1,
                                             const float* __restrict__ W2, const float* __restrict__ b2,
                                             const float* __restrict__ g,  const float* __restrict__ be,
                                             float* __restrict__ x) {
    __shared__ float sW1[DIN * DD];
    __shared__ float sW2[DD * DD];
    __shared__ float sb1[DD], sb2[DD], sg[DD], sbe[DD];
    __shared__ float sin_[8][DIN + 3];
    int tid = threadIdx.x;
    for (int i = tid; i < DIN * DD; i += 256) sW1[i] = W1[i];
    for (int i = tid; i < DD * DD; i += 256) sW2[i] = W2[i];
    if (tid < DD) { sb1[tid] = b1[tid]; sb2[tid] = b2[tid]; sg[tid] = g[tid]; sbe[tid] = be[tid]; }
    int grp = tid >> 5, lane = tid & 31;
    size_t node = (size_t)blockIdx.x * 8 + grp;
    const float* hrow = H + node * DIN;
    sin_[grp][lane] = hrow[lane];
    if (lane == 0) sin_[grp][32] = hrow[32];
    __syncthreads();
    float acc = sb1[lane];
    #pragma unroll
    for (int i = 0; i < DIN; ++i) acc += sin_[grp][i] * sW1[i * DD + lane];
    acc = fmaxf(acc, 0.f);
    float acc2 = sb2[lane];
    #pragma unroll
    for (int i = 0; i < DD; ++i) acc2 += __shfl(acc, i, 32) * sW2[i * DD + lane];
    acc2 = fmaxf(acc2, 0.f);
    float s = acc2;
    for (int off = 16; off; off >>= 1) s += __shfl_xor(s, off, 32);
    float m = s * (1.f / 32.f);
    float dv = acc2 - m;
    float sq = dv * dv;
    for (int off = 16; off; off >>= 1) sq += __shfl_xor(sq, off, 32);
    float var = sq * (1.f / 32.f);
    x[node * DD + lane] = dv * rsqrtf(var + 1e-5f) * sg[lane] + sbe[lane];
}

// ---------------------------------------------------------------------------
// GNN hop: per node gather sum/max over incoming edges, then
// relu(concat[h,mean,mx,s] @ W(128x32) + b).  8 nodes/block, 32 lanes/node.
// ---------------------------------------------------------------------------
__global__ __launch_bounds__(256) void k_gnn(const float* __restrict__ hin, float* __restrict__ hout,
                                             const float* __restrict__ cnt_f,
                                             const int* __restrict__ csr_off,
                                             const int* __restrict__ csr_src,
                                             const float* __restrict__ W, const float* __restrict__ bias) {
    __shared__ float sW[128 * DD];   // 16 KB
    __shared__ float sb[DD];
    __shared__ float sbuf[8][128];   // concat inputs per node
    int tid = threadIdx.x;
    for (int i = tid; i < 128 * DD; i += 256) sW[i] = W[i];
    if (tid < DD) sb[tid] = bias[tid];
    int grp = tid >> 5, lane = tid & 31;
    int node = blockIdx.x * 8 + grp;
    int b = node >> 9, n = node & 511;
    const float* hbp = hin + ((size_t)b << 14);   // b*512*32
    float hval = hbp[n * DD + lane];
    float s = 0.f, mx = -1e30f;
    int beg = csr_off[n], end = csr_off[n + 1];
    for (int idx = beg; idx < end; ++idx) {
        int sn = csr_src[idx];
        float m = hbp[sn * DD + lane];
        s += m;
        mx = fmaxf(mx, m);
    }
    float c = cnt_f[n];
    float mean = s / fmaxf(c, 1.f);
    if (!(c > 0.f)) mx = 0.f;
    sbuf[grp][lane]      = hval;
    sbuf[grp][32 + lane] = mean;
    sbuf[grp][64 + lane] = mx;
    sbuf[grp][96 + lane] = s;
    __syncthreads();
    float acc = sb[lane];
    #pragma unroll
    for (int i4 = 0; i4 < 32; ++i4) {
        float4 xv = *(const float4*)&sbuf[grp][i4 * 4];
        acc += xv.x * sW[(i4 * 4 + 0) * DD + lane];
        acc += xv.y * sW[(i4 * 4 + 1) * DD + lane];
        acc += xv.z * sW[(i4 * 4 + 2) * DD + lane];
        acc += xv.w * sW[(i4 * 4 + 3) * DD + lane];
    }
    hout[(size_t)node * DD + lane] = fmaxf(acc, 0.f);
}

// ---------------------------------------------------------------------------
// QKV projections: q=h@Wq, k=h@Wk, v=x@Wv.  shfl-broadcast dot per node.
// ---------------------------------------------------------------------------
__global__ __launch_bounds__(256) void k_qkv(const float* __restrict__ h, const float* __restrict__ x,
                                             const float* __restrict__ Wq, const float* __restrict__ Wk,
                                             const float* __restrict__ Wv,
                                             float* __restrict__ qb, float* __restrict__ kb,
                                             float* __restrict__ vb) {
    __shared__ float sWq[DD * DD], sWk[DD * DD], sWv[DD * DD];
    int tid = threadIdx.x;
    for (int i = tid; i < DD * DD; i += 256) { sWq[i] = Wq[i]; sWk[i] = Wk[i]; sWv[i] = Wv[i]; }
    __syncthreads();
    int grp = tid >> 5, lane = tid & 31;
    size_t node = (size_t)blockIdx.x * 8 + grp;
    float hv = h[node * DD + lane];
    float xv = x[node * DD + lane];
    float aq = 0.f, ak = 0.f, av = 0.f;
    #pragma unroll
    for (int i = 0; i < DD; ++i) {
        float hi = __shfl(hv, i, 32);
        float xi = __shfl(xv, i, 32);
        aq += hi * sWq[i * DD + lane];
        ak += hi * sWk[i * DD + lane];
        av += xi * sWv[i * DD + lane];
    }
    qb[node * DD + lane] = aq;
    kb[node * DD + lane] = ak;
    vb[node * DD + lane] = av;
}

// ---------------------------------------------------------------------------
// Attention: one block per (b, head).  K,V (512x8 each) staged in LDS.
// 256 threads, 2 query rows/thread, single-pass online softmax (16-key chunks).
// ---------------------------------------------------------------------------
__global__ __launch_bounds__(256) void k_attn(const float* __restrict__ qb, const float* __restrict__ kb,
                                              const float* __restrict__ vb, float* __restrict__ ob) {
    __shared__ float ks[NN * DH];   // 16 KB
    __shared__ float vs[NN * DH];   // 16 KB
    int bh = blockIdx.x;
    int b = bh >> 2, head = bh & 3;
    int tid = threadIdx.x;
    const float* kbase = kb + ((size_t)b * NN) * DD + head * DH;
    const float* vbase = vb + ((size_t)b * NN) * DD + head * DH;
    for (int i = tid; i < NN * DH / 4; i += 256) {
        int r = i >> 1, hf = i & 1;
        *(float4*)&ks[r * DH + hf * 4] = *(const float4*)&kbase[(size_t)r * DD + hf * 4];
        *(float4*)&vs[r * DH + hf * 4] = *(const float4*)&vbase[(size_t)r * DD + hf * 4];
    }
    __syncthreads();
    const float isq = 0.35355339059327373f;   // 1/sqrt(8)
    float q0[DH], q1[DH];
    const float* q0p = qb + (((size_t)b * NN) + tid) * DD + head * DH;
    const float* q1p = q0p + 256 * DD;
    #pragma unroll
    for (int d = 0; d < DH; ++d) { q0[d] = q0p[d] * isq; q1[d] = q1p[d] * isq; }
    float m0 = -1e30f, m1 = -1e30f, l0 = 0.f, l1 = 0.f;
    float o0[DH] = {0}, o1[DH] = {0};
    for (int t16 = 0; t16 < NN / 16; ++t16) {
        float s0[16], s1[16];
        float cm0 = -1e30f, cm1 = -1e30f;
        #pragma unroll
        for (int j = 0; j < 16; ++j) {
            const float* kr = &ks[(t16 * 16 + j) * DH];
            float a0 = 0.f, a1 = 0.f;
            #pragma unroll
            for (int d = 0; d < DH; ++d) { a0 += q0[d] * kr[d]; a1 += q1[d] * kr[d]; }
            s0[j] = a0; s1[j] = a1;
            cm0 = fmaxf(cm0, a0); cm1 = fmaxf(cm1, a1);
        }
        float mn0 = fmaxf(m0, cm0), mn1 = fmaxf(m1, cm1);
        float sc0 = __expf(m0 - mn0), sc1 = __expf(m1 - mn1);
        l0 *= sc0; l1 *= sc1;
        #pragma unroll
        for (int d = 0; d < DH; ++d) { o0[d] *= sc0; o1[d] *= sc1; }
        #pragma unroll
        for (int j = 0; j < 16; ++j) {
            float p0 = __expf(s0[j] - mn0), p1 = __expf(s1[j] - mn1);
            l0 += p0; l1 += p1;
            const float* vr = &vs[(t16 * 16 + j) * DH];
            #pragma unroll
            for (int d = 0; d < DH; ++d) { o0[d] += p0 * vr[d]; o1[d] += p1 * vr[d]; }
        }
        m0 = mn0; m1 = mn1;
    }
    float i0 = 1.f / l0, i1 = 1.f / l1;
    float* o0p = ob + (((size_t)b * NN) + tid) * DD + head * DH;
    float* o1p = o0p + 256 * DD;
    #pragma unroll
    for (int d = 0; d < DH; ++d) { o0p[d] = o0[d] * i0; o1p[d] = o1[d] * i1; }
}

// ---------------------------------------------------------------------------
// t = x + o@Wo ; accumulate per-channel sum/sumsq into stats[0:64].
// grid 256 x 256, 16 node-groups per block.
// ---------------------------------------------------------------------------
__global__ __launch_bounds__(256) void k_proj_stats(const float* __restrict__ ob, const float* __restrict__ x,
                                                    const float* __restrict__ Wo,
                                                    float* __restrict__ t, float* __restrict__ stats) {
    __shared__ float sW[DD * DD];
    __shared__ float rs[8][DD], rq[8][DD];
    int tid = threadIdx.x;
    for (int i = tid; i < DD * DD; i += 256) sW[i] = Wo[i];
    __syncthreads();
    int grp = tid >> 5, lane = tid & 31;
    float ls = 0.f, lsq = 0.f;
    for (int it = 0; it < 16; ++it) {
        size_t node = ((size_t)blockIdx.x * 16 + it) * 8 + grp;
        float ov = ob[node * DD + lane];
        float acc = 0.f;
        #pragma unroll
        for (int i = 0; i < DD; ++i) acc += __shfl(ov, i, 32) * sW[i * DD + lane];
        float tv = x[node * DD + lane] + acc;
        t[node * DD + lane] = tv;
        ls += tv; lsq += tv * tv;
    }
    rs[grp][lane] = ls; rq[grp][lane] = lsq;
    __syncthreads();
    if (tid < DD) {
        float a = 0.f, b2 = 0.f;
        for (int g2 = 0; g2 < 8; ++g2) { a += rs[g2][tid]; b2 += rq[g2][tid]; }
        atomicAdd(&stats[tid], a);
        atomicAdd(&stats[DD + tid], b2);
    }
}

// ---------------------------------------------------------------------------
// x1 = BN1(t) ; f = relu(x1@W1+b1)@W2+b2 ; t2 = x1+f ; stats2 accumulate.
// ---------------------------------------------------------------------------
__global__ __launch_bounds__(256) void k_ff_stats(const float* __restrict__ t, const float* __restrict__ stats,
                                                  const float* __restrict__ g1, const float* __restrict__ be1,
                                                  const float* __restrict__ W1, const float* __restrict__ fb1,
                                                  const float* __restrict__ W2, const float* __restrict__ fb2,
                                                  float* __restrict__ x1, float* __restrict__ t2,
                                                  float* __restrict__ stats2) {
    __shared__ float sW1[DD * FFD];   // 8 KB
    __shared__ float sW2[FFD * DD];   // 8 KB
    __shared__ float sfb1[FFD];
    __shared__ float rs[8][DD], rq[8][DD];
    int tid = threadIdx.x;
    for (int i = tid; i < DD * FFD; i += 256) { sW1[i] = W1[i]; sW2[i] = W2[i]; }
    if (tid < FFD) sfb1[tid] = fb1[tid];
    __syncthreads();
    int grp = tid >> 5, lane = tid & 31;
    float mean  = stats[lane] * (1.f / 32768.f);
    float var   = stats[DD + lane] * (1.f / 32768.f) - mean * mean;
    float scale = rsqrtf(var + 1e-5f) * g1[lane];
    float shift = be1[lane];
    float fb2v  = fb2[lane];
    float ls = 0.f, lsq = 0.f;
    for (int it = 0; it < 16; ++it) {
        size_t node = ((size_t)blockIdx.x * 16 + it) * 8 + grp;
        float tv = t[node * DD + lane];
        float xv = (tv - mean) * scale + shift;
        x1[node * DD + lane] = xv;
        float a0 = sfb1[lane], a1 = sfb1[lane + 32];
        #pragma unroll
        for (int i = 0; i < DD; ++i) {
            float xi = __shfl(xv, i, 32);
            a0 += xi * sW1[i * FFD + lane];
            a1 += xi * sW1[i * FFD + lane + 32];
        }
        a0 = fmaxf(a0, 0.f); a1 = fmaxf(a1, 0.f);
        float f = fb2v;
        #pragma unroll
        for (int i = 0; i < DD; ++i) {
            float h0 = __shfl(a0, i, 32);
            float h1 = __shfl(a1, i, 32);
            f += h0 * sW2[i * DD + lane] + h1 * sW2[(i + 32) * DD + lane];
        }
        float t2v = xv + f;
        t2[node * DD + lane] = t2v;
        ls += t2v; lsq += t2v * t2v;
    }
    rs[grp][lane] = ls; rq[grp][lane] = lsq;
    __syncthreads();
    if (tid < DD) {
        float a = 0.f, b2 = 0.f;
        for (int g2 = 0; g2 < 8; ++g2) { a += rs[g2][tid]; b2 += rq[g2][tid]; }
        atomicAdd(&stats2[tid], a);
        atomicAdd(&stats2[DD + tid], b2);
    }
}

// ---------------------------------------------------------------------------
// x = BN2(t2); if do_proj: out = x@out_W + out_b (final output).
// ---------------------------------------------------------------------------
__global__ __launch_bounds__(256) void k_bn2(const float* __restrict__ t2, const float* __restrict__ stats2,
                                             const float* __restrict__ g, const float* __restrict__ be,
                                             float* __restrict__ xout,
                                             const float* __restrict__ outW, const float* __restrict__ outb,
                                             float* __restrict__ fout, int do_proj) {
    __shared__ float sW[DD * DD];
    int tid = threadIdx.x;
    if (do_proj) for (int i = tid; i < DD * DD; i += 256) sW[i] = outW[i];
    __syncthreads();
    int grp = tid >> 5, lane = tid & 31;
    float mean  = stats2[lane] * (1.f / 32768.f);
    float var   = stats2[DD + lane] * (1.f / 32768.f) - mean * mean;
    float scale = rsqrtf(var + 1e-5f) * g[lane];
    float shift = be[lane];
    size_t node = (size_t)blockIdx.x * 8 + grp;
    float tv = t2[node * DD + lane];
    float xv = (tv - mean) * scale + shift;
    xout[node * DD + lane] = xv;
    if (do_proj) {
        float acc = outb[lane];
        #pragma unroll
        for (int i = 0; i < DD; ++i) acc += __shfl(xv, i, 32) * sW[i * DD + lane];
        fout[node * DD + lane] = acc;
    }
}

// ---------------------------------------------------------------------------
extern "C" void kernel_launch(void* const* d_in, const int* in_sizes, int n_in,
                              void* d_out, int out_size, void* d_ws, size_t ws_size,
                              hipStream_t stream) {
    const float* H    = (const float*)d_in[0];
    const int*   ei   = (const int*)  d_in[1];
    const float* eW1  = (const float*)d_in[2];
    const float* eb1  = (const float*)d_in[3];
    const float* eW2  = (const float*)d_in[4];
    const float* eb2  = (const float*)d_in[5];
    const float* elg  = (const float*)d_in[6];
    const float* elb  = (const float*)d_in[7];
    const float* gW   = (const float*)d_in[8];
    const float* gb   = (const float*)d_in[9];
    const float* Wq   = (const float*)d_in[10];
    const float* Wk   = (const float*)d_in[11];
    const float* Wv   = (const float*)d_in[12];
    const float* Wo   = (const float*)d_in[13];
    const float* bn1g = (const float*)d_in[14];
    const float* bn1b = (const float*)d_in[15];
    const float* fW1  = (const float*)d_in[16];
    const float* fb1  = (const float*)d_in[17];
    const float* fW2  = (const float*)d_in[18];
    const float* fb2  = (const float*)d_in[19];
    const float* bn2g = (const float*)d_in[20];
    const float* bn2b = (const float*)d_in[21];
    const float* oW   = (const float*)d_in[22];
    const float* obv  = (const float*)d_in[23];
    float* out = (float*)d_out;

    float* ws = (float*)d_ws;
    const size_t BIGSZ = (size_t)BB * NN * DD;   // 1048576 floats
    float* xb = ws;
    float* hA = ws + 1 * BIGSZ;
    float* hB = ws + 2 * BIGSZ;
    float* qb = ws + 3 * BIGSZ;
    float* kb = ws + 4 * BIGSZ;
    float* vb = ws + 5 * BIGSZ;
    float* ob = ws + 6 * BIGSZ;
    float* tb = ws + 7 * BIGSZ;
    float* smalls = ws + 8 * BIGSZ;
    float* cnt_f   = smalls;                       // 512
    int*   csr_off = (int*)(smalls + 512);         // 513 (+3 pad)
    int*   csr_src = (int*)(smalls + 512 + 516);   // 8192
    float* stats   = smalls + 512 + 516 + 8192;    // 128 (sum|sumsq, bn1 then bn2)

    k_csr<<<1, 512, 0, stream>>>(ei, cnt_f, csr_off, csr_src);
    k_emb<<<BB * NN / 8, 256, 0, stream>>>(H, eW1, eb1, eW2, eb2, elg, elb, xb);

    for (int l = 0; l < 2; ++l) {
        const float* gW0 = gW + (size_t)(l * 2 + 0) * 128 * DD;
        const float* gW1 = gW + (size_t)(l * 2 + 1) * 128 * DD;
        const float* gb0 = gb + (size_t)(l * 2 + 0) * DD;
        const float* gb1 = gb + (size_t)(l * 2 + 1) * DD;
        k_gnn<<<BB * NN / 8, 256, 0, stream>>>(xb, hA, cnt_f, csr_off, csr_src, gW0, gb0);
        k_gnn<<<BB * NN / 8, 256, 0, stream>>>(hA, hB, cnt_f, csr_off, csr_src, gW1, gb1);
        k_qkv<<<BB * NN / 8, 256, 0, stream>>>(hB, xb, Wq + l * DD * DD, Wk + l * DD * DD,
                                               Wv + l * DD * DD, qb, kb, vb);
        k_attn<<<BB * NHEADS, 256, 0, stream>>>(qb, kb, vb, ob);
        hipMemsetAsync(stats, 0, 128 * sizeof(float), stream);
        k_proj_stats<<<256, 256, 0, stream>>>(ob, xb, Wo + l * DD * DD, tb, stats);
        // x1 -> hA (free), t2 -> hB (free)
        k_ff_stats<<<256, 256, 0, stream>>>(tb, stats, bn1g + l * DD, bn1b + l * DD,
                                            fW1 + l * DD * FFD, fb1 + l * FFD,
                                            fW2 + l * FFD * DD, fb2 + l * DD,
                                            hA, hB, stats + 64);
        k_bn2<<<BB * NN / 8, 256, 0, stream>>>(hB, stats + 64, bn2g + l * DD, bn2b + l * DD,
                                               xb, oW, obv, out, (l == 1) ? 1 : 0);
    }
}

// Round 2
// 493.153 us; speedup vs baseline: 1.1808x; 1.1808x over previous
//
#include <hip/hip_runtime.h>
#include <hip/hip_bf16.h>

#define BB 64
#define NN 512
#define DIN 33
#define DD 32
#define EE 8192
#define NHEADS 4
#define DH 8
#define FFD 64

typedef __attribute__((ext_vector_type(4))) float f32x4;
typedef __attribute__((ext_vector_type(4))) short bf16x4;

static __device__ __forceinline__ short f2bf(float x) {
    unsigned u = __float_as_uint(x);
    u = (u + 0x7FFFu + ((u >> 16) & 1u)) >> 16;
    return (short)u;
}

static __device__ __forceinline__ void mfma16(f32x4& d, bf16x4 a, bf16x4 b) {
#if __has_builtin(__builtin_amdgcn_mfma_f32_16x16x16bf16_1k)
    d = __builtin_amdgcn_mfma_f32_16x16x16bf16_1k(a, b, d, 0, 0, 0);
#else
    asm volatile("s_nop 1\n\tv_mfma_f32_16x16x16_bf16 %0, %1, %2, %0\n\ts_nop 7"
                 : "+v"(d) : "v"(a), "v"(b));
#endif
}

// ---------------------------------------------------------------------------
// CSR build + zero BN stats: one block, 512 threads.
// ---------------------------------------------------------------------------
__global__ __launch_bounds__(512) void k_csr(const int* __restrict__ ei,
                                             float* __restrict__ cnt_f,
                                             int* __restrict__ csr_off,
                                             int* __restrict__ csr_src,
                                             float* __restrict__ stats) {
    __shared__ int cnt_s[NN];
    __shared__ int off_s[NN + 1];
    int tid = threadIdx.x;
    cnt_s[tid] = 0;
    if (tid < 256) stats[tid] = 0.f;   // [2 layers][bn1|bn2][sum|sumsq][32]
    __syncthreads();
    const int* src = ei;
    const int* dst = ei + EE;
    for (int e = tid; e < EE; e += 512) atomicAdd(&cnt_s[dst[e]], 1);
    __syncthreads();
    if (tid == 0) {
        int acc = 0;
        for (int n = 0; n < NN; ++n) { off_s[n] = acc; acc += cnt_s[n]; }
        off_s[NN] = acc;
    }
    __syncthreads();
    cnt_f[tid] = (float)cnt_s[tid];
    csr_off[tid] = off_s[tid];
    if (tid == 0) csr_off[NN] = off_s[NN];
    cnt_s[tid] = off_s[tid];   // reuse as cursors
    __syncthreads();
    for (int e = tid; e < EE; e += 512) {
        int d = dst[e];
        int p = atomicAdd(&cnt_s[d], 1);
        csr_src[p] = src[e];
    }
}

// ---------------------------------------------------------------------------
// Embedding: relu(H@W1+b1) -> relu(@W2+b2) -> LN.  8 nodes/block.
// ---------------------------------------------------------------------------
__global__ __launch_bounds__(256) void k_emb(const float* __restrict__ H,
                                             const float* __restrict__ W1, const float* __restrict__ b1,
                                             const float* __restrict__ W2, const float* __restrict__ b2,
                                             const float* __restrict__ g,  const float* __restrict__ be,
                                             float* __restrict__ x) {
    __shared__ float sW1[DIN * DD];
    __shared__ float sW2[DD * DD];
    __shared__ float sb1[DD], sb2[DD], sg[DD], sbe[DD];
    __shared__ float sin_[8][DIN + 3];
    int tid = threadIdx.x;
    for (int i = tid; i < DIN * DD; i += 256) sW1[i] = W1[i];
    for (int i = tid; i < DD * DD; i += 256) sW2[i] = W2[i];
    if (tid < DD) { sb1[tid] = b1[tid]; sb2[tid] = b2[tid]; sg[tid] = g[tid]; sbe[tid] = be[tid]; }
    int grp = tid >> 5, lane = tid & 31;
    size_t node = (size_t)blockIdx.x * 8 + grp;
    const float* hrow = H + node * DIN;
    sin_[grp][lane] = hrow[lane];
    if (lane == 0) sin_[grp][32] = hrow[32];
    __syncthreads();
    float acc = sb1[lane];
    #pragma unroll
    for (int i = 0; i < DIN; ++i) acc += sin_[grp][i] * sW1[i * DD + lane];
    acc = fmaxf(acc, 0.f);
    float acc2 = sb2[lane];
    #pragma unroll
    for (int i = 0; i < DD; ++i) acc2 += __shfl(acc, i, 32) * sW2[i * DD + lane];
    acc2 = fmaxf(acc2, 0.f);
    float s = acc2;
    for (int off = 16; off; off >>= 1) s += __shfl_xor(s, off, 32);
    float m = s * (1.f / 32.f);
    float dv = acc2 - m;
    float sq = dv * dv;
    for (int off = 16; off; off >>= 1) sq += __shfl_xor(sq, off, 32);
    float var = sq * (1.f / 32.f);
    x[node * DD + lane] = dv * rsqrtf(var + 1e-5f) * sg[lane] + sbe[lane];
}

// ---------------------------------------------------------------------------
// GNN hop: gather sum/max + relu(concat @ W(128x32) + b).  8 nodes/block.
// ---------------------------------------------------------------------------
__global__ __launch_bounds__(256) void k_gnn(const float* __restrict__ hin, float* __restrict__ hout,
                                             const float* __restrict__ cnt_f,
                                             const int* __restrict__ csr_off,
                                             const int* __restrict__ csr_src,
                                             const float* __restrict__ W, const float* __restrict__ bias) {
    __shared__ float sW[128 * DD];   // 16 KB
    __shared__ float sb[DD];
    __shared__ float sbuf[8][128];
    int tid = threadIdx.x;
    for (int i = tid; i < 128 * DD; i += 256) sW[i] = W[i];
    if (tid < DD) sb[tid] = bias[tid];
    int grp = tid >> 5, lane = tid & 31;
    int node = blockIdx.x * 8 + grp;
    int b = node >> 9, n = node & 511;
    const float* hbp = hin + ((size_t)b << 14);
    float hval = hbp[n * DD + lane];
    float s = 0.f, mx = -1e30f;
    int beg = csr_off[n], end = csr_off[n + 1];
    for (int idx = beg; idx < end; ++idx) {
        int sn = csr_src[idx];
        float m = hbp[sn * DD + lane];
        s += m;
        mx = fmaxf(mx, m);
    }
    float c = cnt_f[n];
    float mean = s / fmaxf(c, 1.f);
    if (!(c > 0.f)) mx = 0.f;
    sbuf[grp][lane]      = hval;
    sbuf[grp][32 + lane] = mean;
    sbuf[grp][64 + lane] = mx;
    sbuf[grp][96 + lane] = s;
    __syncthreads();
    float acc = sb[lane];
    #pragma unroll
    for (int i4 = 0; i4 < 32; ++i4) {
        float4 xv = *(const float4*)&sbuf[grp][i4 * 4];
        acc += xv.x * sW[(i4 * 4 + 0) * DD + lane];
        acc += xv.y * sW[(i4 * 4 + 1) * DD + lane];
        acc += xv.z * sW[(i4 * 4 + 2) * DD + lane];
        acc += xv.w * sW[(i4 * 4 + 3) * DD + lane];
    }
    hout[(size_t)node * DD + lane] = fmaxf(acc, 0.f);
}

// ---------------------------------------------------------------------------
// QKV projections.
// ---------------------------------------------------------------------------
__global__ __launch_bounds__(256) void k_qkv(const float* __restrict__ h, const float* __restrict__ x,
                                             const float* __restrict__ Wq, const float* __restrict__ Wk,
                                             const float* __restrict__ Wv,
                                             float* __restrict__ qb, float* __restrict__ kb,
                                             float* __restrict__ vb) {
    __shared__ float sWq[DD * DD], sWk[DD * DD], sWv[DD * DD];
    int tid = threadIdx.x;
    for (int i = tid; i < DD * DD; i += 256) { sWq[i] = Wq[i]; sWk[i] = Wk[i]; sWv[i] = Wv[i]; }
    __syncthreads();
    int grp = tid >> 5, lane = tid & 31;
    size_t node = (size_t)blockIdx.x * 8 + grp;
    float hv = h[node * DD + lane];
    float xv = x[node * DD + lane];
    float aq = 0.f, ak = 0.f, av = 0.f;
    #pragma unroll
    for (int i = 0; i < DD; ++i) {
        float hi = __shfl(hv, i, 32);
        float xi = __shfl(xv, i, 32);
        aq += hi * sWq[i * DD + lane];
        ak += hi * sWk[i * DD + lane];
        av += xi * sWv[i * DD + lane];
    }
    qb[node * DD + lane] = aq;
    kb[node * DD + lane] = ak;
    vb[node * DD + lane] = av;
}

// ---------------------------------------------------------------------------
// MFMA attention.  Block = (b, head, qsplit of 128 rows), 256 threads.
// S^T = mfma(K,Q) so softmax state is per-column (lane-local) and exp'd P^T
// is directly the B-fragment for O^T = mfma(V^T, P^T).  bf16 in, fp32 acc.
// ---------------------------------------------------------------------------
__global__ __launch_bounds__(256) void k_attn(const float* __restrict__ qb, const float* __restrict__ kb,
                                              const float* __restrict__ vb, float* __restrict__ ob) {
    __shared__ short Ks[NN * DH];      // [512][8] bf16, 8 KB
    __shared__ short Vt[DH * 528];     // [8][528] bf16 transposed, padded, 8.25 KB
    __shared__ short Qs[128 * DH];     // [128][8] bf16 (pre-scaled), 2 KB
    int bid = blockIdx.x;
    int qs = bid & 3;
    int bh = bid >> 2;
    int h = bh & 3, b = bh >> 2;
    int tid = threadIdx.x;
    const float isq = 0.35355339059327373f;   // 1/sqrt(8)

    for (int i = tid; i < 1024; i += 256) {
        int row = i >> 1, half = i & 1;
        size_t gofs = (((size_t)b * NN + row) * DD) + h * DH + half * 4;
        float4 kv = *(const float4*)&kb[gofs];
        bf16x4 kp; kp.x = f2bf(kv.x); kp.y = f2bf(kv.y); kp.z = f2bf(kv.z); kp.w = f2bf(kv.w);
        *(bf16x4*)&Ks[row * DH + half * 4] = kp;
        float4 vv = *(const float4*)&vb[gofs];
        Vt[(half * 4 + 0) * 528 + row] = f2bf(vv.x);
        Vt[(half * 4 + 1) * 528 + row] = f2bf(vv.y);
        Vt[(half * 4 + 2) * 528 + row] = f2bf(vv.z);
        Vt[(half * 4 + 3) * 528 + row] = f2bf(vv.w);
    }
    {
        int row = tid >> 1, half = tid & 1;
        size_t gofs = (((size_t)b * NN + qs * 128 + row) * DD) + h * DH + half * 4;
        float4 qv = *(const float4*)&qb[gofs];
        bf16x4 qp; qp.x = f2bf(qv.x * isq); qp.y = f2bf(qv.y * isq);
        qp.z = f2bf(qv.z * isq); qp.w = f2bf(qv.w * isq);
        *(bf16x4*)&Qs[row * DH + half * 4] = qp;
    }
    __syncthreads();

    int wid = tid >> 6, lane = tid & 63;
    int c = lane & 15, g = lane >> 4;
    bf16x4 z4 = {0, 0, 0, 0};
    int lt0 = wid * 2, lt1 = lt0 + 1;
    bf16x4 qf0 = z4, qf1 = z4;
    if (g < 2) {
        qf0 = *(const bf16x4*)&Qs[(lt0 * 16 + c) * DH + g * 4];
        qf1 = *(const bf16x4*)&Qs[(lt1 * 16 + c) * DH + g * 4];
    }
    float m0 = -1e30f, l0 = 0.f, m1 = -1e30f, l1 = 0.f;
    f32x4 o0 = {0.f, 0.f, 0.f, 0.f}, o1 = {0.f, 0.f, 0.f, 0.f};
    int c7 = c & 7;

    for (int kc = 0; kc < 32; ++kc) {
        bf16x4 kf = z4;
        if (g < 2) kf = *(const bf16x4*)&Ks[(kc * 16 + c) * DH + g * 4];
        bf16x4 vf = z4;
        {
            bf16x4 vl = *(const bf16x4*)&Vt[c7 * 528 + kc * 16 + g * 4];
            if (c < 8) vf = vl;
        }
        f32x4 st0 = {0.f, 0.f, 0.f, 0.f};
        f32x4 st1 = {0.f, 0.f, 0.f, 0.f};
        mfma16(st0, kf, qf0);
        mfma16(st1, kf, qf1);
        // --- softmax + PV accumulate, tile 0 ---
        {
            float lm = fmaxf(fmaxf(st0[0], st0[1]), fmaxf(st0[2], st0[3]));
            lm = fmaxf(lm, __shfl_xor(lm, 16, 64));
            lm = fmaxf(lm, __shfl_xor(lm, 32, 64));
            float mn = fmaxf(m0, lm);
            float fac = __expf(m0 - mn);
            float p0 = __expf(st0[0] - mn), p1 = __expf(st0[1] - mn);
            float p2 = __expf(st0[2] - mn), p3 = __expf(st0[3] - mn);
            float ps = (p0 + p1) + (p2 + p3);
            ps += __shfl_xor(ps, 16, 64);
            ps += __shfl_xor(ps, 32, 64);
            l0 = l0 * fac + ps; m0 = mn;
            o0[0] *= fac; o0[1] *= fac; o0[2] *= fac; o0[3] *= fac;
            bf16x4 pf; pf.x = f2bf(p0); pf.y = f2bf(p1); pf.z = f2bf(p2); pf.w = f2bf(p3);
            mfma16(o0, vf, pf);
        }
        // --- tile 1 ---
        {
            float lm = fmaxf(fmaxf(st1[0], st1[1]), fmaxf(st1[2], st1[3]));
            lm = fmaxf(lm, __shfl_xor(lm, 16, 64));
            lm = fmaxf(lm, __shfl_xor(lm, 32, 64));
            float mn = fmaxf(m1, lm);
            float fac = __expf(m1 - mn);
            float p0 = __expf(st1[0] - mn), p1 = __expf(st1[1] - mn);
            float p2 = __expf(st1[2] - mn), p3 = __expf(st1[3] - mn);
            float ps = (p0 + p1) + (p2 + p3);
            ps += __shfl_xor(ps, 16, 64);
            ps += __shfl_xor(ps, 32, 64);
            l1 = l1 * fac + ps; m1 = mn;
            o1[0] *= fac; o1[1] *= fac; o1[2] *= fac; o1[3] *= fac;
            bf16x4 pf; pf.x = f2bf(p0); pf.y = f2bf(p1); pf.z = f2bf(p2); pf.w = f2bf(p3);
            mfma16(o1, vf, pf);
        }
    }
    if (g < 2) {
        {
            float inv = 1.f / l0;
            int qg = qs * 128 + lt0 * 16 + c;
            float4 r; r.x = o0[0] * inv; r.y = o0[1] * inv; r.z = o0[2] * inv; r.w = o0[3] * inv;
            *(float4*)&ob[(((size_t)b * NN + qg) * DD) + h * DH + g * 4] = r;
        }
        {
            float inv = 1.f / l1;
            int qg = qs * 128 + lt1 * 16 + c;
            float4 r; r.x = o1[0] * inv; r.y = o1[1] * inv; r.z = o1[2] * inv; r.w = o1[3] * inv;
            *(float4*)&ob[(((size_t)b * NN + qg) * DD) + h * DH + g * 4] = r;
        }
    }
}

// ---------------------------------------------------------------------------
// t = x + o@Wo ; per-channel sum/sumsq partials.  512 blocks x 8 iters.
// ---------------------------------------------------------------------------
__global__ __launch_bounds__(256) void k_proj_stats(const float* __restrict__ ob, const float* __restrict__ x,
                                                    const float* __restrict__ Wo,
                                                    float* __restrict__ t, float* __restrict__ stats) {
    __shared__ float sW[DD * DD];
    __shared__ float rs[8][DD], rq[8][DD];
    int tid = threadIdx.x;
    for (int i = tid; i < DD * DD; i += 256) sW[i] = Wo[i];
    __syncthreads();
    int grp = tid >> 5, lane = tid & 31;
    float ls = 0.f, lsq = 0.f;
    for (int it = 0; it < 8; ++it) {
        size_t node = ((size_t)blockIdx.x * 8 + it) * 8 + grp;
        float ov = ob[node * DD + lane];
        float acc = 0.f;
        #pragma unroll
        for (int i = 0; i < DD; ++i) acc += __shfl(ov, i, 32) * sW[i * DD + lane];
        float tv = x[node * DD + lane] + acc;
        t[node * DD + lane] = tv;
        ls += tv; lsq += tv * tv;
    }
    rs[grp][lane] = ls; rq[grp][lane] = lsq;
    __syncthreads();
    if (tid < DD) {
        float a = 0.f, b2 = 0.f;
        for (int g2 = 0; g2 < 8; ++g2) { a += rs[g2][tid]; b2 += rq[g2][tid]; }
        atomicAdd(&stats[tid], a);
        atomicAdd(&stats[DD + tid], b2);
    }
}

// ---------------------------------------------------------------------------
// x1 = BN1(t) ; f = relu(x1@W1+b1)@W2+b2 ; t2 = x1+f ; stats2 accumulate.
// ---------------------------------------------------------------------------
__global__ __launch_bounds__(256) void k_ff_stats(const float* __restrict__ t, const float* __restrict__ stats,
                                                  const float* __restrict__ g1, const float* __restrict__ be1,
                                                  const float* __restrict__ W1, const float* __restrict__ fb1,
                                                  const float* __restrict__ W2, const float* __restrict__ fb2,
                                                  float* __restrict__ x1, float* __restrict__ t2,
                                                  float* __restrict__ stats2) {
    __shared__ float sW1[DD * FFD];
    __shared__ float sW2[FFD * DD];
    __shared__ float sfb1[FFD];
    __shared__ float rs[8][DD], rq[8][DD];
    int tid = threadIdx.x;
    for (int i = tid; i < DD * FFD; i += 256) { sW1[i] = W1[i]; sW2[i] = W2[i]; }
    if (tid < FFD) sfb1[tid] = fb1[tid];
    __syncthreads();
    int grp = tid >> 5, lane = tid & 31;
    float mean  = stats[lane] * (1.f / 32768.f);
    float var   = stats[DD + lane] * (1.f / 32768.f) - mean * mean;
    float scale = rsqrtf(var + 1e-5f) * g1[lane];
    float shift = be1[lane];
    float fb2v  = fb2[lane];
    float ls = 0.f, lsq = 0.f;
    for (int it = 0; it < 8; ++it) {
        size_t node = ((size_t)blockIdx.x * 8 + it) * 8 + grp;
        float tv = t[node * DD + lane];
        float xv = (tv - mean) * scale + shift;
        x1[node * DD + lane] = xv;
        float a0 = sfb1[lane], a1 = sfb1[lane + 32];
        #pragma unroll
        for (int i = 0; i < DD; ++i) {
            float xi = __shfl(xv, i, 32);
            a0 += xi * sW1[i * FFD + lane];
            a1 += xi * sW1[i * FFD + lane + 32];
        }
        a0 = fmaxf(a0, 0.f); a1 = fmaxf(a1, 0.f);
        float f = fb2v;
        #pragma unroll
        for (int i = 0; i < DD; ++i) {
            float h0 = __shfl(a0, i, 32);
            float h1 = __shfl(a1, i, 32);
            f += h0 * sW2[i * DD + lane] + h1 * sW2[(i + 32) * DD + lane];
        }
        float t2v = xv + f;
        t2[node * DD + lane] = t2v;
        ls += t2v; lsq += t2v * t2v;
    }
    rs[grp][lane] = ls; rq[grp][lane] = lsq;
    __syncthreads();
    if (tid < DD) {
        float a = 0.f, b2 = 0.f;
        for (int g2 = 0; g2 < 8; ++g2) { a += rs[g2][tid]; b2 += rq[g2][tid]; }
        atomicAdd(&stats2[tid], a);
        atomicAdd(&stats2[DD + tid], b2);
    }
}

// ---------------------------------------------------------------------------
// x = BN2(t2); if do_proj: out = x@out_W + out_b.
// ---------------------------------------------------------------------------
__global__ __launch_bounds__(256) void k_bn2(const float* __restrict__ t2, const float* __restrict__ stats2,
                                             const float* __restrict__ g, const float* __restrict__ be,
                                             float* __restrict__ xout,
                                             const float* __restrict__ outW, const float* __restrict__ outb,
                                             float* __restrict__ fout, int do_proj) {
    __shared__ float sW[DD * DD];
    int tid = threadIdx.x;
    if (do_proj) for (int i = tid; i < DD * DD; i += 256) sW[i] = outW[i];
    __syncthreads();
    int grp = tid >> 5, lane = tid & 31;
    float mean  = stats2[lane] * (1.f / 32768.f);
    float var   = stats2[DD + lane] * (1.f / 32768.f) - mean * mean;
    float scale = rsqrtf(var + 1e-5f) * g[lane];
    float shift = be[lane];
    size_t node = (size_t)blockIdx.x * 8 + grp;
    float tv = t2[node * DD + lane];
    float xv = (tv - mean) * scale + shift;
    xout[node * DD + lane] = xv;
    if (do_proj) {
        float acc = outb[lane];
        #pragma unroll
        for (int i = 0; i < DD; ++i) acc += __shfl(xv, i, 32) * sW[i * DD + lane];
        fout[node * DD + lane] = acc;
    }
}

// ---------------------------------------------------------------------------
extern "C" void kernel_launch(void* const* d_in, const int* in_sizes, int n_in,
                              void* d_out, int out_size, void* d_ws, size_t ws_size,
                              hipStream_t stream) {
    const float* H    = (const float*)d_in[0];
    const int*   ei   = (const int*)  d_in[1];
    const float* eW1  = (const float*)d_in[2];
    const float* eb1  = (const float*)d_in[3];
    const float* eW2  = (const float*)d_in[4];
    const float* eb2  = (const float*)d_in[5];
    const float* elg  = (const float*)d_in[6];
    const float* elb  = (const float*)d_in[7];
    const float* gW   = (const float*)d_in[8];
    const float* gb   = (const float*)d_in[9];
    const float* Wq   = (const float*)d_in[10];
    const float* Wk   = (const float*)d_in[11];
    const float* Wv   = (const float*)d_in[12];
    const float* Wo   = (const float*)d_in[13];
    const float* bn1g = (const float*)d_in[14];
    const float* bn1b = (const float*)d_in[15];
    const float* fW1  = (const float*)d_in[16];
    const float* fb1  = (const float*)d_in[17];
    const float* fW2  = (const float*)d_in[18];
    const float* fb2  = (const float*)d_in[19];
    const float* bn2g = (const float*)d_in[20];
    const float* bn2b = (const float*)d_in[21];
    const float* oW   = (const float*)d_in[22];
    const float* obv  = (const float*)d_in[23];
    float* out = (float*)d_out;

    float* ws = (float*)d_ws;
    const size_t BIGSZ = (size_t)BB * NN * DD;   // 1048576 floats
    float* xb = ws;
    float* hA = ws + 1 * BIGSZ;
    float* hB = ws + 2 * BIGSZ;
    float* qb = ws + 3 * BIGSZ;
    float* kb = ws + 4 * BIGSZ;
    float* vb = ws + 5 * BIGSZ;
    float* ob = ws + 6 * BIGSZ;
    float* tb = ws + 7 * BIGSZ;
    float* smalls = ws + 8 * BIGSZ;
    float* cnt_f   = smalls;                       // 512
    int*   csr_off = (int*)(smalls + 512);         // 513 (+3 pad)
    int*   csr_src = (int*)(smalls + 512 + 516);   // 8192
    float* stats   = smalls + 512 + 516 + 8192;    // 256: [l][bn1|bn2][64]

    k_csr<<<1, 512, 0, stream>>>(ei, cnt_f, csr_off, csr_src, stats);
    k_emb<<<BB * NN / 8, 256, 0, stream>>>(H, eW1, eb1, eW2, eb2, elg, elb, xb);

    for (int l = 0; l < 2; ++l) {
        const float* gW0 = gW + (size_t)(l * 2 + 0) * 128 * DD;
        const float* gW1 = gW + (size_t)(l * 2 + 1) * 128 * DD;
        const float* gb0 = gb + (size_t)(l * 2 + 0) * DD;
        const float* gb1 = gb + (size_t)(l * 2 + 1) * DD;
        float* st1 = stats + l * 128;
        float* st2 = stats + l * 128 + 64;
        k_gnn<<<BB * NN / 8, 256, 0, stream>>>(xb, hA, cnt_f, csr_off, csr_src, gW0, gb0);
        k_gnn<<<BB * NN / 8, 256, 0, stream>>>(hA, hB, cnt_f, csr_off, csr_src, gW1, gb1);
        k_qkv<<<BB * NN / 8, 256, 0, stream>>>(hB, xb, Wq + l * DD * DD, Wk + l * DD * DD,
                                               Wv + l * DD * DD, qb, kb, vb);
        k_attn<<<BB * NHEADS * 4, 256, 0, stream>>>(qb, kb, vb, ob);
        k_proj_stats<<<512, 256, 0, stream>>>(ob, xb, Wo + l * DD * DD, tb, st1);
        k_ff_stats<<<512, 256, 0, stream>>>(tb, st1, bn1g + l * DD, bn1b + l * DD,
                                            fW1 + l * DD * FFD, fb1 + l * FFD,
                                            fW2 + l * FFD * DD, fb2 + l * DD,
                                            hA, hB, st2);
        k_bn2<<<BB * NN / 8, 256, 0, stream>>>(hB, st2, bn2g + l * DD, bn2b + l * DD,
                                               xb, oW, obv, out, (l == 1) ? 1 : 0);
    }
}

// Round 3
// 340.989 us; speedup vs baseline: 1.7077x; 1.4462x over previous
//
#include <hip/hip_runtime.h>
#include <hip/hip_bf16.h>

#define BB 64
#define NN 512
#define DIN 33
#define DD 32
#define EE 8192
#define NHEADS 4
#define DH 8
#define FFD 64

typedef __attribute__((ext_vector_type(4))) float f32x4;
typedef __attribute__((ext_vector_type(4))) short bf16x4;

static __device__ __forceinline__ short f2bf(float x) {
    unsigned u = __float_as_uint(x);
    u = (u + 0x7FFFu + ((u >> 16) & 1u)) >> 16;
    return (short)u;
}

static __device__ __forceinline__ void mfma16(f32x4& d, bf16x4 a, bf16x4 b) {
#if __has_builtin(__builtin_amdgcn_mfma_f32_16x16x16bf16_1k)
    d = __builtin_amdgcn_mfma_f32_16x16x16bf16_1k(a, b, d, 0, 0, 0);
#else
    asm volatile("s_nop 1\n\tv_mfma_f32_16x16x16_bf16 %0, %1, %2, %0\n\ts_nop 7"
                 : "+v"(d) : "v"(a), "v"(b));
#endif
}

// ---------------------------------------------------------------------------
// CSR build + zero BN stats: one block, 512 threads.
// ---------------------------------------------------------------------------
__global__ __launch_bounds__(512) void k_csr(const int* __restrict__ ei,
                                             float* __restrict__ cnt_f,
                                             int* __restrict__ csr_off,
                                             int* __restrict__ csr_src,
                                             float* __restrict__ stats) {
    __shared__ int cnt_s[NN];
    __shared__ int off_s[NN + 1];
    int tid = threadIdx.x;
    cnt_s[tid] = 0;
    if (tid < 256) stats[tid] = 0.f;   // [2 layers][bn1|bn2][sum|sumsq][32]
    __syncthreads();
    const int* src = ei;
    const int* dst = ei + EE;
    for (int e = tid; e < EE; e += 512) atomicAdd(&cnt_s[dst[e]], 1);
    __syncthreads();
    if (tid == 0) {
        int acc = 0;
        for (int n = 0; n < NN; ++n) { off_s[n] = acc; acc += cnt_s[n]; }
        off_s[NN] = acc;
    }
    __syncthreads();
    cnt_f[tid] = (float)cnt_s[tid];
    csr_off[tid] = off_s[tid];
    if (tid == 0) csr_off[NN] = off_s[NN];
    cnt_s[tid] = off_s[tid];   // reuse as cursors
    __syncthreads();
    for (int e = tid; e < EE; e += 512) {
        int d = dst[e];
        int p = atomicAdd(&cnt_s[d], 1);
        csr_src[p] = src[e];
    }
}

// ---------------------------------------------------------------------------
// Embedding: relu(H@W1+b1) -> relu(@W2+b2) -> LN.  Writes batch-major xb AND
// node-major xt.
// ---------------------------------------------------------------------------
__global__ __launch_bounds__(256) void k_emb(const float* __restrict__ H,
                                             const float* __restrict__ W1, const float* __restrict__ b1,
                                             const float* __restrict__ W2, const float* __restrict__ b2,
                                             const float* __restrict__ g,  const float* __restrict__ be,
                                             float* __restrict__ xb, float* __restrict__ xt) {
    __shared__ float sW1[DIN * DD];
    __shared__ float sW2[DD * DD];
    __shared__ float sb1[DD], sb2[DD], sg[DD], sbe[DD];
    __shared__ float sin_[8][DIN + 3];
    int tid = threadIdx.x;
    for (int i = tid; i < DIN * DD; i += 256) sW1[i] = W1[i];
    for (int i = tid; i < DD * DD; i += 256) sW2[i] = W2[i];
    if (tid < DD) { sb1[tid] = b1[tid]; sb2[tid] = b2[tid]; sg[tid] = g[tid]; sbe[tid] = be[tid]; }
    int grp = tid >> 5, lane = tid & 31;
    size_t node = (size_t)blockIdx.x * 8 + grp;
    const float* hrow = H + node * DIN;
    sin_[grp][lane] = hrow[lane];
    if (lane == 0) sin_[grp][32] = hrow[32];
    __syncthreads();
    float acc = sb1[lane];
    #pragma unroll
    for (int i = 0; i < DIN; ++i) acc += sin_[grp][i] * sW1[i * DD + lane];
    acc = fmaxf(acc, 0.f);
    float acc2 = sb2[lane];
    #pragma unroll
    for (int i = 0; i < DD; ++i) acc2 += __shfl(acc, i, 32) * sW2[i * DD + lane];
    acc2 = fmaxf(acc2, 0.f);
    float s = acc2;
    for (int off = 16; off; off >>= 1) s += __shfl_xor(s, off, 32);
    float m = s * (1.f / 32.f);
    float dv = acc2 - m;
    float sq = dv * dv;
    for (int off = 16; off; off >>= 1) sq += __shfl_xor(sq, off, 32);
    float var = sq * (1.f / 32.f);
    float v = dv * rsqrtf(var + 1e-5f) * sg[lane] + sbe[lane];
    xb[node * DD + lane] = v;
    int b = (int)(node >> 9), n = (int)(node & 511);
    xt[(size_t)n * 2048 + b * DD + lane] = v;
}

// ---------------------------------------------------------------------------
// GNN hop (node-major): block = (node, batch-half).  Uniform-index coalesced
// gather (4-deep unrolled) + bf16 MFMA for the 128x32 GEMM.
// ---------------------------------------------------------------------------
__global__ __launch_bounds__(256) void k_gnn(const float* __restrict__ xt, float* __restrict__ ht,
                                             const float* __restrict__ cnt_f,
                                             const int* __restrict__ csr_off,
                                             const int* __restrict__ csr_src,
                                             const float* __restrict__ W, const float* __restrict__ bias) {
    __shared__ short conc[32 * 132];   // [b_local][128] bf16, stride 132
    __shared__ short sWt[32 * 132];    // [d][128] bf16 (W transposed), stride 132
    __shared__ float sb[DD];
    int tid = threadIdx.x;
    int n = blockIdx.x >> 1, half = blockIdx.x & 1;
    for (int i = tid; i < 128 * DD; i += 256) {
        int k = i >> 5, d = i & 31;
        sWt[d * 132 + k] = f2bf(W[i]);
    }
    if (tid < DD) sb[tid] = bias[tid];
    const float* xbase = xt + (size_t)half * 1024 + tid * 4;
    float4 hv = *(const float4*)&xbase[(size_t)n * 2048];
    float4 s = {0.f, 0.f, 0.f, 0.f};
    float4 mx = {-1e30f, -1e30f, -1e30f, -1e30f};
    int beg = csr_off[n], end = csr_off[n + 1];
    int idx = beg;
    for (; idx + 3 < end; idx += 4) {
        int s0 = csr_src[idx], s1 = csr_src[idx + 1], s2 = csr_src[idx + 2], s3 = csr_src[idx + 3];
        float4 v0 = *(const float4*)&xbase[(size_t)s0 * 2048];
        float4 v1 = *(const float4*)&xbase[(size_t)s1 * 2048];
        float4 v2 = *(const float4*)&xbase[(size_t)s2 * 2048];
        float4 v3 = *(const float4*)&xbase[(size_t)s3 * 2048];
        s.x += (v0.x + v1.x) + (v2.x + v3.x);
        s.y += (v0.y + v1.y) + (v2.y + v3.y);
        s.z += (v0.z + v1.z) + (v2.z + v3.z);
        s.w += (v0.w + v1.w) + (v2.w + v3.w);
        mx.x = fmaxf(fmaxf(mx.x, v0.x), fmaxf(v1.x, fmaxf(v2.x, v3.x)));
        mx.y = fmaxf(fmaxf(mx.y, v0.y), fmaxf(v1.y, fmaxf(v2.y, v3.y)));
        mx.z = fmaxf(fmaxf(mx.z, v0.z), fmaxf(v1.z, fmaxf(v2.z, v3.z)));
        mx.w = fmaxf(fmaxf(mx.w, v0.w), fmaxf(v1.w, fmaxf(v2.w, v3.w)));
    }
    for (; idx < end; ++idx) {
        int s0 = csr_src[idx];
        float4 v0 = *(const float4*)&xbase[(size_t)s0 * 2048];
        s.x += v0.x; s.y += v0.y; s.z += v0.z; s.w += v0.w;
        mx.x = fmaxf(mx.x, v0.x); mx.y = fmaxf(mx.y, v0.y);
        mx.z = fmaxf(mx.z, v0.z); mx.w = fmaxf(mx.w, v0.w);
    }
    float c = cnt_f[n];
    float rinv = 1.f / fmaxf(c, 1.f);
    if (!(c > 0.f)) { mx.x = 0.f; mx.y = 0.f; mx.z = 0.f; mx.w = 0.f; }
    int bl = tid >> 3, d0 = (tid & 7) * 4;
    short* cp = &conc[bl * 132];
    bf16x4 t;
    t.x = f2bf(hv.x); t.y = f2bf(hv.y); t.z = f2bf(hv.z); t.w = f2bf(hv.w);
    *(bf16x4*)&cp[d0] = t;
    t.x = f2bf(s.x * rinv); t.y = f2bf(s.y * rinv); t.z = f2bf(s.z * rinv); t.w = f2bf(s.w * rinv);
    *(bf16x4*)&cp[32 + d0] = t;
    t.x = f2bf(mx.x); t.y = f2bf(mx.y); t.z = f2bf(mx.z); t.w = f2bf(mx.w);
    *(bf16x4*)&cp[64 + d0] = t;
    t.x = f2bf(s.x); t.y = f2bf(s.y); t.z = f2bf(s.z); t.w = f2bf(s.w);
    *(bf16x4*)&cp[96 + d0] = t;
    __syncthreads();
    // 32x32 output via 4 waves x one 16x16 C-tile, K=128 in 8 steps.
    int wid = tid >> 6, lane = tid & 63;
    int cc = lane & 15, g = lane >> 4;
    int arow = (wid >> 1) * 16 + cc;     // b_local row of A
    int bcol = (wid & 1) * 16 + cc;      // d col of B
    f32x4 acc = {0.f, 0.f, 0.f, 0.f};
    #pragma unroll
    for (int ks = 0; ks < 8; ++ks) {
        bf16x4 af = *(const bf16x4*)&conc[arow * 132 + ks * 16 + g * 4];
        bf16x4 bfr = *(const bf16x4*)&sWt[bcol * 132 + ks * 16 + g * 4];
        mfma16(acc, af, bfr);
    }
    float bia = sb[bcol];
    int brow = (wid >> 1) * 16 + g * 4;
    float* obase = &ht[(size_t)n * 2048 + half * 1024 + bcol];
    #pragma unroll
    for (int r = 0; r < 4; ++r) {
        obase[(size_t)(brow + r) * DD] = fmaxf(acc[r] + bia, 0.f);
    }
}

// ---------------------------------------------------------------------------
// QKV projections: h (node-major), x (batch-major) -> q,k,v batch-major.
// ---------------------------------------------------------------------------
__global__ __launch_bounds__(256) void k_qkv(const float* __restrict__ ht, const float* __restrict__ x,
                                             const float* __restrict__ Wq, const float* __restrict__ Wk,
                                             const float* __restrict__ Wv,
                                             float* __restrict__ qb, float* __restrict__ kb,
                                             float* __restrict__ vb) {
    __shared__ float sWq[DD * DD], sWk[DD * DD], sWv[DD * DD];
    int tid = threadIdx.x;
    for (int i = tid; i < DD * DD; i += 256) { sWq[i] = Wq[i]; sWk[i] = Wk[i]; sWv[i] = Wv[i]; }
    __syncthreads();
    int grp = tid >> 5, lane = tid & 31;
    size_t node = (size_t)blockIdx.x * 8 + grp;
    int b = (int)(node >> 9), n = (int)(node & 511);
    float hv = ht[(size_t)n * 2048 + b * DD + lane];
    float xv = x[node * DD + lane];
    float aq = 0.f, ak = 0.f, av = 0.f;
    #pragma unroll
    for (int i = 0; i < DD; ++i) {
        float hi = __shfl(hv, i, 32);
        float xi = __shfl(xv, i, 32);
        aq += hi * sWq[i * DD + lane];
        ak += hi * sWk[i * DD + lane];
        av += xi * sWv[i * DD + lane];
    }
    qb[node * DD + lane] = aq;
    kb[node * DD + lane] = ak;
    vb[node * DD + lane] = av;
}

// ---------------------------------------------------------------------------
// MFMA attention.  Block = (b, head, qsplit of 128 rows), 256 threads.
// ---------------------------------------------------------------------------
__global__ __launch_bounds__(256) void k_attn(const float* __restrict__ qb, const float* __restrict__ kb,
                                              const float* __restrict__ vb, float* __restrict__ ob) {
    __shared__ short Ks[NN * DH];      // [512][8] bf16
    __shared__ short Vt[DH * 528];     // [8][528] bf16 transposed
    __shared__ short Qs[128 * DH];     // [128][8] bf16 (pre-scaled)
    int bid = blockIdx.x;
    int qs = bid & 3;
    int bh = bid >> 2;
    int h = bh & 3, b = bh >> 2;
    int tid = threadIdx.x;
    const float isq = 0.35355339059327373f;

    for (int i = tid; i < 1024; i += 256) {
        int row = i >> 1, half = i & 1;
        size_t gofs = (((size_t)b * NN + row) * DD) + h * DH + half * 4;
        float4 kv = *(const float4*)&kb[gofs];
        bf16x4 kp; kp.x = f2bf(kv.x); kp.y = f2bf(kv.y); kp.z = f2bf(kv.z); kp.w = f2bf(kv.w);
        *(bf16x4*)&Ks[row * DH + half * 4] = kp;
        float4 vv = *(const float4*)&vb[gofs];
        Vt[(half * 4 + 0) * 528 + row] = f2bf(vv.x);
        Vt[(half * 4 + 1) * 528 + row] = f2bf(vv.y);
        Vt[(half * 4 + 2) * 528 + row] = f2bf(vv.z);
        Vt[(half * 4 + 3) * 528 + row] = f2bf(vv.w);
    }
    {
        int row = tid >> 1, half = tid & 1;
        size_t gofs = (((size_t)b * NN + qs * 128 + row) * DD) + h * DH + half * 4;
        float4 qv = *(const float4*)&qb[gofs];
        bf16x4 qp; qp.x = f2bf(qv.x * isq); qp.y = f2bf(qv.y * isq);
        qp.z = f2bf(qv.z * isq); qp.w = f2bf(qv.w * isq);
        *(bf16x4*)&Qs[row * DH + half * 4] = qp;
    }
    __syncthreads();

    int wid = tid >> 6, lane = tid & 63;
    int c = lane & 15, g = lane >> 4;
    bf16x4 z4 = {0, 0, 0, 0};
    int lt0 = wid * 2, lt1 = lt0 + 1;
    bf16x4 qf0 = z4, qf1 = z4;
    if (g < 2) {
        qf0 = *(const bf16x4*)&Qs[(lt0 * 16 + c) * DH + g * 4];
        qf1 = *(const bf16x4*)&Qs[(lt1 * 16 + c) * DH + g * 4];
    }
    float m0 = -1e30f, l0 = 0.f, m1 = -1e30f, l1 = 0.f;
    f32x4 o0 = {0.f, 0.f, 0.f, 0.f}, o1 = {0.f, 0.f, 0.f, 0.f};
    int c7 = c & 7;

    for (int kc = 0; kc < 32; ++kc) {
        bf16x4 kf = z4;
        if (g < 2) kf = *(const bf16x4*)&Ks[(kc * 16 + c) * DH + g * 4];
        bf16x4 vf = z4;
        {
            bf16x4 vl = *(const bf16x4*)&Vt[c7 * 528 + kc * 16 + g * 4];
            if (c < 8) vf = vl;
        }
        f32x4 st0 = {0.f, 0.f, 0.f, 0.f};
        f32x4 st1 = {0.f, 0.f, 0.f, 0.f};
        mfma16(st0, kf, qf0);
        mfma16(st1, kf, qf1);
        {
            float lm = fmaxf(fmaxf(st0[0], st0[1]), fmaxf(st0[2], st0[3]));
            lm = fmaxf(lm, __shfl_xor(lm, 16, 64));
            lm = fmaxf(lm, __shfl_xor(lm, 32, 64));
            float mn = fmaxf(m0, lm);
            float fac = __expf(m0 - mn);
            float p0 = __expf(st0[0] - mn), p1 = __expf(st0[1] - mn);
            float p2 = __expf(st0[2] - mn), p3 = __expf(st0[3] - mn);
            float ps = (p0 + p1) + (p2 + p3);
            ps += __shfl_xor(ps, 16, 64);
            ps += __shfl_xor(ps, 32, 64);
            l0 = l0 * fac + ps; m0 = mn;
            o0[0] *= fac; o0[1] *= fac; o0[2] *= fac; o0[3] *= fac;
            bf16x4 pf; pf.x = f2bf(p0); pf.y = f2bf(p1); pf.z = f2bf(p2); pf.w = f2bf(p3);
            mfma16(o0, vf, pf);
        }
        {
            float lm = fmaxf(fmaxf(st1[0], st1[1]), fmaxf(st1[2], st1[3]));
            lm = fmaxf(lm, __shfl_xor(lm, 16, 64));
            lm = fmaxf(lm, __shfl_xor(lm, 32, 64));
            float mn = fmaxf(m1, lm);
            float fac = __expf(m1 - mn);
            float p0 = __expf(st1[0] - mn), p1 = __expf(st1[1] - mn);
            float p2 = __expf(st1[2] - mn), p3 = __expf(st1[3] - mn);
            float ps = (p0 + p1) + (p2 + p3);
            ps += __shfl_xor(ps, 16, 64);
            ps += __shfl_xor(ps, 32, 64);
            l1 = l1 * fac + ps; m1 = mn;
            o1[0] *= fac; o1[1] *= fac; o1[2] *= fac; o1[3] *= fac;
            bf16x4 pf; pf.x = f2bf(p0); pf.y = f2bf(p1); pf.z = f2bf(p2); pf.w = f2bf(p3);
            mfma16(o1, vf, pf);
        }
    }
    if (g < 2) {
        {
            float inv = 1.f / l0;
            int qg = qs * 128 + lt0 * 16 + c;
            float4 r; r.x = o0[0] * inv; r.y = o0[1] * inv; r.z = o0[2] * inv; r.w = o0[3] * inv;
            *(float4*)&ob[(((size_t)b * NN + qg) * DD) + h * DH + g * 4] = r;
        }
        {
            float inv = 1.f / l1;
            int qg = qs * 128 + lt1 * 16 + c;
            float4 r; r.x = o1[0] * inv; r.y = o1[1] * inv; r.z = o1[2] * inv; r.w = o1[3] * inv;
            *(float4*)&ob[(((size_t)b * NN + qg) * DD) + h * DH + g * 4] = r;
        }
    }
}

// ---------------------------------------------------------------------------
// t = x + o@Wo ; per-channel sum/sumsq partials.
// ---------------------------------------------------------------------------
__global__ __launch_bounds__(256) void k_proj_stats(const float* __restrict__ ob, const float* __restrict__ x,
                                                    const float* __restrict__ Wo,
                                                    float* __restrict__ t, float* __restrict__ stats) {
    __shared__ float sW[DD * DD];
    __shared__ float rs[8][DD], rq[8][DD];
    int tid = threadIdx.x;
    for (int i = tid; i < DD * DD; i += 256) sW[i] = Wo[i];
    __syncthreads();
    int grp = tid >> 5, lane = tid & 31;
    float ls = 0.f, lsq = 0.f;
    for (int it = 0; it < 8; ++it) {
        size_t node = ((size_t)blockIdx.x * 8 + it) * 8 + grp;
        float ov = ob[node * DD + lane];
        float acc = 0.f;
        #pragma unroll
        for (int i = 0; i < DD; ++i) acc += __shfl(ov, i, 32) * sW[i * DD + lane];
        float tv = x[node * DD + lane] + acc;
        t[node * DD + lane] = tv;
        ls += tv; lsq += tv * tv;
    }
    rs[grp][lane] = ls; rq[grp][lane] = lsq;
    __syncthreads();
    if (tid < DD) {
        float a = 0.f, b2 = 0.f;
        for (int g2 = 0; g2 < 8; ++g2) { a += rs[g2][tid]; b2 += rq[g2][tid]; }
        atomicAdd(&stats[tid], a);
        atomicAdd(&stats[DD + tid], b2);
    }
}

// ---------------------------------------------------------------------------
// x1 = BN1(t) ; f = relu(x1@W1+b1)@W2+b2 ; t2 = x1+f ; stats2 accumulate.
// ---------------------------------------------------------------------------
__global__ __launch_bounds__(256) void k_ff_stats(const float* __restrict__ t, const float* __restrict__ stats,
                                                  const float* __restrict__ g1, const float* __restrict__ be1,
                                                  const float* __restrict__ W1, const float* __restrict__ fb1,
                                                  const float* __restrict__ W2, const float* __restrict__ fb2,
                                                  float* __restrict__ x1, float* __restrict__ t2,
                                                  float* __restrict__ stats2) {
    __shared__ float sW1[DD * FFD];
    __shared__ float sW2[FFD * DD];
    __shared__ float sfb1[FFD];
    __shared__ float rs[8][DD], rq[8][DD];
    int tid = threadIdx.x;
    for (int i = tid; i < DD * FFD; i += 256) { sW1[i] = W1[i]; sW2[i] = W2[i]; }
    if (tid < FFD) sfb1[tid] = fb1[tid];
    __syncthreads();
    int grp = tid >> 5, lane = tid & 31;
    float mean  = stats[lane] * (1.f / 32768.f);
    float var   = stats[DD + lane] * (1.f / 32768.f) - mean * mean;
    float scale = rsqrtf(var + 1e-5f) * g1[lane];
    float shift = be1[lane];
    float fb2v  = fb2[lane];
    float ls = 0.f, lsq = 0.f;
    for (int it = 0; it < 8; ++it) {
        size_t node = ((size_t)blockIdx.x * 8 + it) * 8 + grp;
        float tv = t[node * DD + lane];
        float xv = (tv - mean) * scale + shift;
        x1[node * DD + lane] = xv;
        float a0 = sfb1[lane], a1 = sfb1[lane + 32];
        #pragma unroll
        for (int i = 0; i < DD; ++i) {
            float xi = __shfl(xv, i, 32);
            a0 += xi * sW1[i * FFD + lane];
            a1 += xi * sW1[i * FFD + lane + 32];
        }
        a0 = fmaxf(a0, 0.f); a1 = fmaxf(a1, 0.f);
        float f = fb2v;
        #pragma unroll
        for (int i = 0; i < DD; ++i) {
            float h0 = __shfl(a0, i, 32);
            float h1 = __shfl(a1, i, 32);
            f += h0 * sW2[i * DD + lane] + h1 * sW2[(i + 32) * DD + lane];
        }
        float t2v = xv + f;
        t2[node * DD + lane] = t2v;
        ls += t2v; lsq += t2v * t2v;
    }
    rs[grp][lane] = ls; rq[grp][lane] = lsq;
    __syncthreads();
    if (tid < DD) {
        float a = 0.f, b2 = 0.f;
        for (int g2 = 0; g2 < 8; ++g2) { a += rs[g2][tid]; b2 += rq[g2][tid]; }
        atomicAdd(&stats2[tid], a);
        atomicAdd(&stats2[DD + tid], b2);
    }
}

// ---------------------------------------------------------------------------
// x = BN2(t2) -> xb, xt; if do_proj: out = x@out_W + out_b.
// ---------------------------------------------------------------------------
__global__ __launch_bounds__(256) void k_bn2(const float* __restrict__ t2, const float* __restrict__ stats2,
                                             const float* __restrict__ g, const float* __restrict__ be,
                                             float* __restrict__ xout, float* __restrict__ xtout,
                                             const float* __restrict__ outW, const float* __restrict__ outb,
                                             float* __restrict__ fout, int do_proj) {
    __shared__ float sW[DD * DD];
    int tid = threadIdx.x;
    if (do_proj) for (int i = tid; i < DD * DD; i += 256) sW[i] = outW[i];
    __syncthreads();
    int grp = tid >> 5, lane = tid & 31;
    float mean  = stats2[lane] * (1.f / 32768.f);
    float var   = stats2[DD + lane] * (1.f / 32768.f) - mean * mean;
    float scale = rsqrtf(var + 1e-5f) * g[lane];
    float shift = be[lane];
    size_t node = (size_t)blockIdx.x * 8 + grp;
    float tv = t2[node * DD + lane];
    float xv = (tv - mean) * scale + shift;
    xout[node * DD + lane] = xv;
    int b = (int)(node >> 9), n = (int)(node & 511);
    xtout[(size_t)n * 2048 + b * DD + lane] = xv;
    if (do_proj) {
        float acc = outb[lane];
        #pragma unroll
        for (int i = 0; i < DD; ++i) acc += __shfl(xv, i, 32) * sW[i * DD + lane];
        fout[node * DD + lane] = acc;
    }
}

// ---------------------------------------------------------------------------
extern "C" void kernel_launch(void* const* d_in, const int* in_sizes, int n_in,
                              void* d_out, int out_size, void* d_ws, size_t ws_size,
                              hipStream_t stream) {
    const float* H    = (const float*)d_in[0];
    const int*   ei   = (const int*)  d_in[1];
    const float* eW1  = (const float*)d_in[2];
    const float* eb1  = (const float*)d_in[3];
    const float* eW2  = (const float*)d_in[4];
    const float* eb2  = (const float*)d_in[5];
    const float* elg  = (const float*)d_in[6];
    const float* elb  = (const float*)d_in[7];
    const float* gW   = (const float*)d_in[8];
    const float* gb   = (const float*)d_in[9];
    const float* Wq   = (const float*)d_in[10];
    const float* Wk   = (const float*)d_in[11];
    const float* Wv   = (const float*)d_in[12];
    const float* Wo   = (const float*)d_in[13];
    const float* bn1g = (const float*)d_in[14];
    const float* bn1b = (const float*)d_in[15];
    const float* fW1  = (const float*)d_in[16];
    const float* fb1  = (const float*)d_in[17];
    const float* fW2  = (const float*)d_in[18];
    const float* fb2  = (const float*)d_in[19];
    const float* bn2g = (const float*)d_in[20];
    const float* bn2b = (const float*)d_in[21];
    const float* oW   = (const float*)d_in[22];
    const float* obv  = (const float*)d_in[23];
    float* out = (float*)d_out;

    float* ws = (float*)d_ws;
    const size_t BIGSZ = (size_t)BB * NN * DD;   // 1048576 floats
    float* xb = ws;                 // batch-major x
    float* xt = ws + 1 * BIGSZ;     // node-major x
    float* hA = ws + 2 * BIGSZ;     // gnn hop1 out (node-major) / x1 (batch-major)
    float* hB = ws + 3 * BIGSZ;     // gnn hop2 out (node-major) / t2 (batch-major)
    float* qb = ws + 4 * BIGSZ;     // q / later t
    float* kb = ws + 5 * BIGSZ;
    float* vb = ws + 6 * BIGSZ;
    float* ob = ws + 7 * BIGSZ;
    float* tb = qb;                 // overlay: q dead after k_attn
    float* smalls = ws + 8 * BIGSZ;
    float* cnt_f   = smalls;                       // 512
    int*   csr_off = (int*)(smalls + 512);         // 513 (+3 pad)
    int*   csr_src = (int*)(smalls + 512 + 516);   // 8192
    float* stats   = smalls + 512 + 516 + 8192;    // 256: [l][bn1|bn2][64]

    k_csr<<<1, 512, 0, stream>>>(ei, cnt_f, csr_off, csr_src, stats);
    k_emb<<<BB * NN / 8, 256, 0, stream>>>(H, eW1, eb1, eW2, eb2, elg, elb, xb, xt);

    for (int l = 0; l < 2; ++l) {
        const float* gW0 = gW + (size_t)(l * 2 + 0) * 128 * DD;
        const float* gW1 = gW + (size_t)(l * 2 + 1) * 128 * DD;
        const float* gb0 = gb + (size_t)(l * 2 + 0) * DD;
        const float* gb1 = gb + (size_t)(l * 2 + 1) * DD;
        float* st1 = stats + l * 128;
        float* st2 = stats + l * 128 + 64;
        k_gnn<<<NN * 2, 256, 0, stream>>>(xt, hA, cnt_f, csr_off, csr_src, gW0, gb0);
        k_gnn<<<NN * 2, 256, 0, stream>>>(hA, hB, cnt_f, csr_off, csr_src, gW1, gb1);
        k_qkv<<<BB * NN / 8, 256, 0, stream>>>(hB, xb, Wq + l * DD * DD, Wk + l * DD * DD,
                                               Wv + l * DD * DD, qb, kb, vb);
        k_attn<<<BB * NHEADS * 4, 256, 0, stream>>>(qb, kb, vb, ob);
        k_proj_stats<<<512, 256, 0, stream>>>(ob, xb, Wo + l * DD * DD, tb, st1);
        k_ff_stats<<<512, 256, 0, stream>>>(tb, st1, bn1g + l * DD, bn1b + l * DD,
                                            fW1 + l * DD * FFD, fb1 + l * FFD,
                                            fW2 + l * FFD * DD, fb2 + l * DD,
                                            hA, hB, st2);
        k_bn2<<<BB * NN / 8, 256, 0, stream>>>(hB, st2, bn2g + l * DD, bn2b + l * DD,
                                               xb, xt, oW, obv, out, (l == 1) ? 1 : 0);
    }
}

// Round 4
// 300.845 us; speedup vs baseline: 1.9356x; 1.1334x over previous
//
#include <hip/hip_runtime.h>
#include <hip/hip_bf16.h>

#define BB 64
#define NN 512
#define DIN 33
#define DD 32
#define EE 8192
#define NHEADS 4
#define DH 8
#define FFD 64

typedef __attribute__((ext_vector_type(4))) float f32x4;
typedef __attribute__((ext_vector_type(4))) short bf16x4;

static __device__ __forceinline__ short f2bf(float x) {
    unsigned u = __float_as_uint(x);
    u = (u + 0x7FFFu + ((u >> 16) & 1u)) >> 16;
    return (short)u;
}

// truncation-round pack of two f32 -> two bf16 in one u32 (lo = a, hi = b)
static __device__ __forceinline__ unsigned pack_trunc(float a, float b) {
    return (__float_as_uint(a) >> 16) | (__float_as_uint(b) & 0xFFFF0000u);
}

static __device__ __forceinline__ void mfma16(f32x4& d, bf16x4 a, bf16x4 b) {
#if __has_builtin(__builtin_amdgcn_mfma_f32_16x16x16bf16_1k)
    d = __builtin_amdgcn_mfma_f32_16x16x16bf16_1k(a, b, d, 0, 0, 0);
#else
    asm volatile("s_nop 1\n\tv_mfma_f32_16x16x16_bf16 %0, %1, %2, %0\n\ts_nop 7"
                 : "+v"(d) : "v"(a), "v"(b));
#endif
}

// ---------------------------------------------------------------------------
// CSR build + zero BN stats: one block, 512 threads.
// ---------------------------------------------------------------------------
__global__ __launch_bounds__(512) void k_csr(const int* __restrict__ ei,
                                             float* __restrict__ cnt_f,
                                             int* __restrict__ csr_off,
                                             int* __restrict__ csr_src,
                                             float* __restrict__ stats) {
    __shared__ int cnt_s[NN];
    __shared__ int off_s[NN + 1];
    int tid = threadIdx.x;
    cnt_s[tid] = 0;
    if (tid < 256) stats[tid] = 0.f;   // [2 layers][bn1|bn2][sum|sumsq][32]
    __syncthreads();
    const int* src = ei;
    const int* dst = ei + EE;
    for (int e = tid; e < EE; e += 512) atomicAdd(&cnt_s[dst[e]], 1);
    __syncthreads();
    if (tid == 0) {
        int acc = 0;
        for (int n = 0; n < NN; ++n) { off_s[n] = acc; acc += cnt_s[n]; }
        off_s[NN] = acc;
    }
    __syncthreads();
    cnt_f[tid] = (float)cnt_s[tid];
    csr_off[tid] = off_s[tid];
    if (tid == 0) csr_off[NN] = off_s[NN];
    cnt_s[tid] = off_s[tid];   // reuse as cursors
    __syncthreads();
    for (int e = tid; e < EE; e += 512) {
        int d = dst[e];
        int p = atomicAdd(&cnt_s[d], 1);
        csr_src[p] = src[e];
    }
}

// ---------------------------------------------------------------------------
// Embedding: relu(H@W1+b1) -> relu(@W2+b2) -> LN.  Writes batch-major xb AND
// node-major xt.
// ---------------------------------------------------------------------------
__global__ __launch_bounds__(256) void k_emb(const float* __restrict__ H,
                                             const float* __restrict__ W1, const float* __restrict__ b1,
                                             const float* __restrict__ W2, const float* __restrict__ b2,
                                             const float* __restrict__ g,  const float* __restrict__ be,
                                             float* __restrict__ xb, float* __restrict__ xt) {
    __shared__ float sW1[DIN * DD];
    __shared__ float sW2[DD * DD];
    __shared__ float sb1[DD], sb2[DD], sg[DD], sbe[DD];
    __shared__ float sin_[8][DIN + 3];
    int tid = threadIdx.x;
    for (int i = tid; i < DIN * DD; i += 256) sW1[i] = W1[i];
    for (int i = tid; i < DD * DD; i += 256) sW2[i] = W2[i];
    if (tid < DD) { sb1[tid] = b1[tid]; sb2[tid] = b2[tid]; sg[tid] = g[tid]; sbe[tid] = be[tid]; }
    int grp = tid >> 5, lane = tid & 31;
    size_t node = (size_t)blockIdx.x * 8 + grp;
    const float* hrow = H + node * DIN;
    sin_[grp][lane] = hrow[lane];
    if (lane == 0) sin_[grp][32] = hrow[32];
    __syncthreads();
    float acc = sb1[lane];
    #pragma unroll
    for (int i = 0; i < DIN; ++i) acc += sin_[grp][i] * sW1[i * DD + lane];
    acc = fmaxf(acc, 0.f);
    float acc2 = sb2[lane];
    #pragma unroll
    for (int i = 0; i < DD; ++i) acc2 += __shfl(acc, i, 32) * sW2[i * DD + lane];
    acc2 = fmaxf(acc2, 0.f);
    float s = acc2;
    for (int off = 16; off; off >>= 1) s += __shfl_xor(s, off, 32);
    float m = s * (1.f / 32.f);
    float dv = acc2 - m;
    float sq = dv * dv;
    for (int off = 16; off; off >>= 1) sq += __shfl_xor(sq, off, 32);
    float var = sq * (1.f / 32.f);
    float v = dv * rsqrtf(var + 1e-5f) * sg[lane] + sbe[lane];
    xb[node * DD + lane] = v;
    int b = (int)(node >> 9), n = (int)(node & 511);
    xt[(size_t)n * 2048 + b * DD + lane] = v;
}

// ---------------------------------------------------------------------------
// GNN hop (node-major): block = (node, batch-half).  Uniform-index coalesced
// gather (4-deep unrolled) + bf16 MFMA for the 128x32 GEMM.
// ---------------------------------------------------------------------------
__global__ __launch_bounds__(256) void k_gnn(const float* __restrict__ xt, float* __restrict__ ht,
                                             const float* __restrict__ cnt_f,
                                             const int* __restrict__ csr_off,
                                             const int* __restrict__ csr_src,
                                             const float* __restrict__ W, const float* __restrict__ bias) {
    __shared__ short conc[32 * 132];   // [b_local][128] bf16, stride 132
    __shared__ short sWt[32 * 132];    // [d][128] bf16 (W transposed), stride 132
    __shared__ float sb[DD];
    int tid = threadIdx.x;
    int n = blockIdx.x >> 1, half = blockIdx.x & 1;
    for (int i = tid; i < 128 * DD; i += 256) {
        int k = i >> 5, d = i & 31;
        sWt[d * 132 + k] = f2bf(W[i]);
    }
    if (tid < DD) sb[tid] = bias[tid];
    const float* xbase = xt + (size_t)half * 1024 + tid * 4;
    float4 hv = *(const float4*)&xbase[(size_t)n * 2048];
    float4 s = {0.f, 0.f, 0.f, 0.f};
    float4 mx = {-1e30f, -1e30f, -1e30f, -1e30f};
    int beg = csr_off[n], end = csr_off[n + 1];
    int idx = beg;
    for (; idx + 3 < end; idx += 4) {
        int s0 = csr_src[idx], s1 = csr_src[idx + 1], s2 = csr_src[idx + 2], s3 = csr_src[idx + 3];
        float4 v0 = *(const float4*)&xbase[(size_t)s0 * 2048];
        float4 v1 = *(const float4*)&xbase[(size_t)s1 * 2048];
        float4 v2 = *(const float4*)&xbase[(size_t)s2 * 2048];
        float4 v3 = *(const float4*)&xbase[(size_t)s3 * 2048];
        s.x += (v0.x + v1.x) + (v2.x + v3.x);
        s.y += (v0.y + v1.y) + (v2.y + v3.y);
        s.z += (v0.z + v1.z) + (v2.z + v3.z);
        s.w += (v0.w + v1.w) + (v2.w + v3.w);
        mx.x = fmaxf(fmaxf(mx.x, v0.x), fmaxf(v1.x, fmaxf(v2.x, v3.x)));
        mx.y = fmaxf(fmaxf(mx.y, v0.y), fmaxf(v1.y, fmaxf(v2.y, v3.y)));
        mx.z = fmaxf(fmaxf(mx.z, v0.z), fmaxf(v1.z, fmaxf(v2.z, v3.z)));
        mx.w = fmaxf(fmaxf(mx.w, v0.w), fmaxf(v1.w, fmaxf(v2.w, v3.w)));
    }
    for (; idx < end; ++idx) {
        int s0 = csr_src[idx];
        float4 v0 = *(const float4*)&xbase[(size_t)s0 * 2048];
        s.x += v0.x; s.y += v0.y; s.z += v0.z; s.w += v0.w;
        mx.x = fmaxf(mx.x, v0.x); mx.y = fmaxf(mx.y, v0.y);
        mx.z = fmaxf(mx.z, v0.z); mx.w = fmaxf(mx.w, v0.w);
    }
    float c = cnt_f[n];
    float rinv = 1.f / fmaxf(c, 1.f);
    if (!(c > 0.f)) { mx.x = 0.f; mx.y = 0.f; mx.z = 0.f; mx.w = 0.f; }
    int bl = tid >> 3, d0 = (tid & 7) * 4;
    short* cp = &conc[bl * 132];
    bf16x4 t;
    t.x = f2bf(hv.x); t.y = f2bf(hv.y); t.z = f2bf(hv.z); t.w = f2bf(hv.w);
    *(bf16x4*)&cp[d0] = t;
    t.x = f2bf(s.x * rinv); t.y = f2bf(s.y * rinv); t.z = f2bf(s.z * rinv); t.w = f2bf(s.w * rinv);
    *(bf16x4*)&cp[32 + d0] = t;
    t.x = f2bf(mx.x); t.y = f2bf(mx.y); t.z = f2bf(mx.z); t.w = f2bf(mx.w);
    *(bf16x4*)&cp[64 + d0] = t;
    t.x = f2bf(s.x); t.y = f2bf(s.y); t.z = f2bf(s.z); t.w = f2bf(s.w);
    *(bf16x4*)&cp[96 + d0] = t;
    __syncthreads();
    // 32x32 output via 4 waves x one 16x16 C-tile, K=128 in 8 steps.
    int wid = tid >> 6, lane = tid & 63;
    int cc = lane & 15, g = lane >> 4;
    int arow = (wid >> 1) * 16 + cc;     // b_local row of A
    int bcol = (wid & 1) * 16 + cc;      // d col of B
    f32x4 acc = {0.f, 0.f, 0.f, 0.f};
    #pragma unroll
    for (int ks = 0; ks < 8; ++ks) {
        bf16x4 af = *(const bf16x4*)&conc[arow * 132 + ks * 16 + g * 4];
        bf16x4 bfr = *(const bf16x4*)&sWt[bcol * 132 + ks * 16 + g * 4];
        mfma16(acc, af, bfr);
    }
    float bia = sb[bcol];
    int brow = (wid >> 1) * 16 + g * 4;
    float* obase = &ht[(size_t)n * 2048 + half * 1024 + bcol];
    #pragma unroll
    for (int r = 0; r < 4; ++r) {
        obase[(size_t)(brow + r) * DD] = fmaxf(acc[r] + bia, 0.f);
    }
}

// ---------------------------------------------------------------------------
// QKV projections: h (node-major), x (batch-major) -> q,k,v batch-major BF16.
// q is pre-scaled by 1/sqrt(dh).
// ---------------------------------------------------------------------------
__global__ __launch_bounds__(256) void k_qkv(const float* __restrict__ ht, const float* __restrict__ x,
                                             const float* __restrict__ Wq, const float* __restrict__ Wk,
                                             const float* __restrict__ Wv,
                                             short* __restrict__ qb2, short* __restrict__ kb2,
                                             short* __restrict__ vb2) {
    __shared__ float sWq[DD * DD], sWk[DD * DD], sWv[DD * DD];
    int tid = threadIdx.x;
    for (int i = tid; i < DD * DD; i += 256) { sWq[i] = Wq[i]; sWk[i] = Wk[i]; sWv[i] = Wv[i]; }
    __syncthreads();
    int grp = tid >> 5, lane = tid & 31;
    size_t node = (size_t)blockIdx.x * 8 + grp;
    int b = (int)(node >> 9), n = (int)(node & 511);
    float hv = ht[(size_t)n * 2048 + b * DD + lane];
    float xv = x[node * DD + lane];
    float aq = 0.f, ak = 0.f, av = 0.f;
    #pragma unroll
    for (int i = 0; i < DD; ++i) {
        float hi = __shfl(hv, i, 32);
        float xi = __shfl(xv, i, 32);
        aq += hi * sWq[i * DD + lane];
        ak += hi * sWk[i * DD + lane];
        av += xi * sWv[i * DD + lane];
    }
    const float isq = 0.35355339059327373f;   // 1/sqrt(8)
    aq *= isq;
    float aqn = __shfl_down(aq, 1, 32);
    float akn = __shfl_down(ak, 1, 32);
    float avn = __shfl_down(av, 1, 32);
    if (!(lane & 1)) {
        size_t p = node * 16 + (lane >> 1);
        ((unsigned*)qb2)[p] = (unsigned short)f2bf(aq) | ((unsigned)(unsigned short)f2bf(aqn) << 16);
        ((unsigned*)kb2)[p] = (unsigned short)f2bf(ak) | ((unsigned)(unsigned short)f2bf(akn) << 16);
        ((unsigned*)vb2)[p] = (unsigned short)f2bf(av) | ((unsigned)(unsigned short)f2bf(avn) << 16);
    }
}

// ---------------------------------------------------------------------------
// MFMA attention, no-max softmax (scores are tiny by construction: weights
// ~N(0,0.0025), activations O(1) => |S| << 80, exp(S) safe in fp32).
// Block = (b, head, half of 256 q rows), 256 threads, 4 q-tiles/wave.
// S^T = mfma(K,Q); P^T trunc-packed to bf16 feeds O^T = mfma(V^T,P^T).
// l accumulated lane-locally, reduced once at the end (2 shfls).
// ---------------------------------------------------------------------------
__global__ __launch_bounds__(256) void k_attn(const short* __restrict__ qb2, const short* __restrict__ kb2,
                                              const short* __restrict__ vb2, float* __restrict__ ob) {
    __shared__ short Ks[NN * DH];      // [512][8] bf16, 8 KB
    __shared__ short Vt[DH * 528];     // [8][528] bf16 transposed, 8.25 KB
    __shared__ short Qs[256 * DH];     // [256][8] bf16 (pre-scaled), 4 KB
    int bid = blockIdx.x;
    int qs2 = bid & 1;
    int bh = bid >> 1;
    int h = bh & 3, b = bh >> 2;
    int tid = threadIdx.x;

    for (int r = tid; r < NN; r += 256) {
        size_t gofs = ((size_t)b * NN + r) * DD + h * DH;
        uint4 kv = *(const uint4*)&kb2[gofs];
        *(uint4*)&Ks[r * DH] = kv;
        uint4 vv = *(const uint4*)&vb2[gofs];
        short* vt = &Vt[r];
        vt[0 * 528] = (short)(vv.x);  vt[1 * 528] = (short)(vv.x >> 16);
        vt[2 * 528] = (short)(vv.y);  vt[3 * 528] = (short)(vv.y >> 16);
        vt[4 * 528] = (short)(vv.z);  vt[5 * 528] = (short)(vv.z >> 16);
        vt[6 * 528] = (short)(vv.w);  vt[7 * 528] = (short)(vv.w >> 16);
    }
    {
        int r = tid;   // 256 rows, one per thread
        size_t gofs = ((size_t)b * NN + qs2 * 256 + r) * DD + h * DH;
        *(uint4*)&Qs[r * DH] = *(const uint4*)&qb2[gofs];
    }
    __syncthreads();

    int wid = tid >> 6, lane = tid & 63;
    int c = lane & 15, g = lane >> 4;
    bf16x4 z4 = {0, 0, 0, 0};
    bf16x4 qf0 = z4, qf1 = z4, qf2 = z4, qf3 = z4;
    int lt0 = wid * 4;
    if (g < 2) {
        qf0 = *(const bf16x4*)&Qs[((lt0 + 0) * 16 + c) * DH + g * 4];
        qf1 = *(const bf16x4*)&Qs[((lt0 + 1) * 16 + c) * DH + g * 4];
        qf2 = *(const bf16x4*)&Qs[((lt0 + 2) * 16 + c) * DH + g * 4];
        qf3 = *(const bf16x4*)&Qs[((lt0 + 3) * 16 + c) * DH + g * 4];
    }
    float l0 = 0.f, l1 = 0.f, l2 = 0.f, l3 = 0.f;
    f32x4 o0 = {0.f, 0.f, 0.f, 0.f}, o1 = o0, o2 = o0, o3 = o0;
    int c7 = c & 7;

    union U { unsigned u[2]; bf16x4 v4; };

    for (int kc = 0; kc < 32; ++kc) {
        bf16x4 kf = z4;
        if (g < 2) kf = *(const bf16x4*)&Ks[(kc * 16 + c) * DH + g * 4];
        bf16x4 vf = z4;
        {
            bf16x4 vl = *(const bf16x4*)&Vt[c7 * 528 + kc * 16 + g * 4];
            if (c < 8) vf = vl;
        }
        f32x4 st0 = {0.f, 0.f, 0.f, 0.f}, st1 = st0, st2 = st0, st3 = st0;
        mfma16(st0, kf, qf0);
        mfma16(st1, kf, qf1);
        mfma16(st2, kf, qf2);
        mfma16(st3, kf, qf3);
        {
            float p0 = __expf(st0[0]), p1 = __expf(st0[1]), p2 = __expf(st0[2]), p3 = __expf(st0[3]);
            l0 += (p0 + p1) + (p2 + p3);
            U pu; pu.u[0] = pack_trunc(p0, p1); pu.u[1] = pack_trunc(p2, p3);
            mfma16(o0, vf, pu.v4);
        }
        {
            float p0 = __expf(st1[0]), p1 = __expf(st1[1]), p2 = __expf(st1[2]), p3 = __expf(st1[3]);
            l1 += (p0 + p1) + (p2 + p3);
            U pu; pu.u[0] = pack_trunc(p0, p1); pu.u[1] = pack_trunc(p2, p3);
            mfma16(o1, vf, pu.v4);
        }
        {
            float p0 = __expf(st2[0]), p1 = __expf(st2[1]), p2 = __expf(st2[2]), p3 = __expf(st2[3]);
            l2 += (p0 + p1) + (p2 + p3);
            U pu; pu.u[0] = pack_trunc(p0, p1); pu.u[1] = pack_trunc(p2, p3);
            mfma16(o2, vf, pu.v4);
        }
        {
            float p0 = __expf(st3[0]), p1 = __expf(st3[1]), p2 = __expf(st3[2]), p3 = __expf(st3[3]);
            l3 += (p0 + p1) + (p2 + p3);
            U pu; pu.u[0] = pack_trunc(p0, p1); pu.u[1] = pack_trunc(p2, p3);
            mfma16(o3, vf, pu.v4);
        }
    }
    l0 += __shfl_xor(l0, 16, 64); l0 += __shfl_xor(l0, 32, 64);
    l1 += __shfl_xor(l1, 16, 64); l1 += __shfl_xor(l1, 32, 64);
    l2 += __shfl_xor(l2, 16, 64); l2 += __shfl_xor(l2, 32, 64);
    l3 += __shfl_xor(l3, 16, 64); l3 += __shfl_xor(l3, 32, 64);
    if (g < 2) {
        float inv0 = 1.f / l0, inv1 = 1.f / l1, inv2 = 1.f / l2, inv3 = 1.f / l3;
        size_t base = ((size_t)b * NN + qs2 * 256) * DD + h * DH + g * 4;
        float4 r;
        r.x = o0[0] * inv0; r.y = o0[1] * inv0; r.z = o0[2] * inv0; r.w = o0[3] * inv0;
        *(float4*)&ob[base + (size_t)((lt0 + 0) * 16 + c) * DD] = r;
        r.x = o1[0] * inv1; r.y = o1[1] * inv1; r.z = o1[2] * inv1; r.w = o1[3] * inv1;
        *(float4*)&ob[base + (size_t)((lt0 + 1) * 16 + c) * DD] = r;
        r.x = o2[0] * inv2; r.y = o2[1] * inv2; r.z = o2[2] * inv2; r.w = o2[3] * inv2;
        *(float4*)&ob[base + (size_t)((lt0 + 2) * 16 + c) * DD] = r;
        r.x = o3[0] * inv3; r.y = o3[1] * inv3; r.z = o3[2] * inv3; r.w = o3[3] * inv3;
        *(float4*)&ob[base + (size_t)((lt0 + 3) * 16 + c) * DD] = r;
    }
}

// ---------------------------------------------------------------------------
// t = x + o@Wo ; per-channel sum/sumsq partials.
// ---------------------------------------------------------------------------
__global__ __launch_bounds__(256) void k_proj_stats(const float* __restrict__ ob, const float* __restrict__ x,
                                                    const float* __restrict__ Wo,
                                                    float* __restrict__ t, float* __restrict__ stats) {
    __shared__ float sW[DD * DD];
    __shared__ float rs[8][DD], rq[8][DD];
    int tid = threadIdx.x;
    for (int i = tid; i < DD * DD; i += 256) sW[i] = Wo[i];
    __syncthreads();
    int grp = tid >> 5, lane = tid & 31;
    float ls = 0.f, lsq = 0.f;
    for (int it = 0; it < 8; ++it) {
        size_t node = ((size_t)blockIdx.x * 8 + it) * 8 + grp;
        float ov = ob[node * DD + lane];
        float acc = 0.f;
        #pragma unroll
        for (int i = 0; i < DD; ++i) acc += __shfl(ov, i, 32) * sW[i * DD + lane];
        float tv = x[node * DD + lane] + acc;
        t[node * DD + lane] = tv;
        ls += tv; lsq += tv * tv;
    }
    rs[grp][lane] = ls; rq[grp][lane] = lsq;
    __syncthreads();
    if (tid < DD) {
        float a = 0.f, b2 = 0.f;
        for (int g2 = 0; g2 < 8; ++g2) { a += rs[g2][tid]; b2 += rq[g2][tid]; }
        atomicAdd(&stats[tid], a);
        atomicAdd(&stats[DD + tid], b2);
    }
}

// ---------------------------------------------------------------------------
// x1 = BN1(t) ; f = relu(x1@W1+b1)@W2+b2 ; t2 = x1+f ; stats2 accumulate.
// ---------------------------------------------------------------------------
__global__ __launch_bounds__(256) void k_ff_stats(const float* __restrict__ t, const float* __restrict__ stats,
                                                  const float* __restrict__ g1, const float* __restrict__ be1,
                                                  const float* __restrict__ W1, const float* __restrict__ fb1,
                                                  const float* __restrict__ W2, const float* __restrict__ fb2,
                                                  float* __restrict__ x1, float* __restrict__ t2,
                                                  float* __restrict__ stats2) {
    __shared__ float sW1[DD * FFD];
    __shared__ float sW2[FFD * DD];
    __shared__ float sfb1[FFD];
    __shared__ float rs[8][DD], rq[8][DD];
    int tid = threadIdx.x;
    for (int i = tid; i < DD * FFD; i += 256) { sW1[i] = W1[i]; sW2[i] = W2[i]; }
    if (tid < FFD) sfb1[tid] = fb1[tid];
    __syncthreads();
    int grp = tid >> 5, lane = tid & 31;
    float mean  = stats[lane] * (1.f / 32768.f);
    float var   = stats[DD + lane] * (1.f / 32768.f) - mean * mean;
    float scale = rsqrtf(var + 1e-5f) * g1[lane];
    float shift = be1[lane];
    float fb2v  = fb2[lane];
    float ls = 0.f, lsq = 0.f;
    for (int it = 0; it < 8; ++it) {
        size_t node = ((size_t)blockIdx.x * 8 + it) * 8 + grp;
        float tv = t[node * DD + lane];
        float xv = (tv - mean) * scale + shift;
        x1[node * DD + lane] = xv;
        float a0 = sfb1[lane], a1 = sfb1[lane + 32];
        #pragma unroll
        for (int i = 0; i < DD; ++i) {
            float xi = __shfl(xv, i, 32);
            a0 += xi * sW1[i * FFD + lane];
            a1 += xi * sW1[i * FFD + lane + 32];
        }
        a0 = fmaxf(a0, 0.f); a1 = fmaxf(a1, 0.f);
        float f = fb2v;
        #pragma unroll
        for (int i = 0; i < DD; ++i) {
            float h0 = __shfl(a0, i, 32);
            float h1 = __shfl(a1, i, 32);
            f += h0 * sW2[i * DD + lane] + h1 * sW2[(i + 32) * DD + lane];
        }
        float t2v = xv + f;
        t2[node * DD + lane] = t2v;
        ls += t2v; lsq += t2v * t2v;
    }
    rs[grp][lane] = ls; rq[grp][lane] = lsq;
    __syncthreads();
    if (tid < DD) {
        float a = 0.f, b2 = 0.f;
        for (int g2 = 0; g2 < 8; ++g2) { a += rs[g2][tid]; b2 += rq[g2][tid]; }
        atomicAdd(&stats2[tid], a);
        atomicAdd(&stats2[DD + tid], b2);
    }
}

// ---------------------------------------------------------------------------
// x = BN2(t2) -> xb, xt; if do_proj: out = x@out_W + out_b.
// ---------------------------------------------------------------------------
__global__ __launch_bounds__(256) void k_bn2(const float* __restrict__ t2, const float* __restrict__ stats2,
                                             const float* __restrict__ g, const float* __restrict__ be,
                                             float* __restrict__ xout, float* __restrict__ xtout,
                                             const float* __restrict__ outW, const float* __restrict__ outb,
                                             float* __restrict__ fout, int do_proj) {
    __shared__ float sW[DD * DD];
    int tid = threadIdx.x;
    if (do_proj) for (int i = tid; i < DD * DD; i += 256) sW[i] = outW[i];
    __syncthreads();
    int grp = tid >> 5, lane = tid & 31;
    float mean  = stats2[lane] * (1.f / 32768.f);
    float var   = stats2[DD + lane] * (1.f / 32768.f) - mean * mean;
    float scale = rsqrtf(var + 1e-5f) * g[lane];
    float shift = be[lane];
    size_t node = (size_t)blockIdx.x * 8 + grp;
    float tv = t2[node * DD + lane];
    float xv = (tv - mean) * scale + shift;
    xout[node * DD + lane] = xv;
    int b = (int)(node >> 9), n = (int)(node & 511);
    xtout[(size_t)n * 2048 + b * DD + lane] = xv;
    if (do_proj) {
        float acc = outb[lane];
        #pragma unroll
        for (int i = 0; i < DD; ++i) acc += __shfl(xv, i, 32) * sW[i * DD + lane];
        fout[node * DD + lane] = acc;
    }
}

// ---------------------------------------------------------------------------
extern "C" void kernel_launch(void* const* d_in, const int* in_sizes, int n_in,
                              void* d_out, int out_size, void* d_ws, size_t ws_size,
                              hipStream_t stream) {
    const float* H    = (const float*)d_in[0];
    const int*   ei   = (const int*)  d_in[1];
    const float* eW1  = (const float*)d_in[2];
    const float* eb1  = (const float*)d_in[3];
    const float* eW2  = (const float*)d_in[4];
    const float* eb2  = (const float*)d_in[5];
    const float* elg  = (const float*)d_in[6];
    const float* elb  = (const float*)d_in[7];
    const float* gW   = (const float*)d_in[8];
    const float* gb   = (const float*)d_in[9];
    const float* Wq   = (const float*)d_in[10];
    const float* Wk   = (const float*)d_in[11];
    const float* Wv   = (const float*)d_in[12];
    const float* Wo   = (const float*)d_in[13];
    const float* bn1g = (const float*)d_in[14];
    const float* bn1b = (const float*)d_in[15];
    const float* fW1  = (const float*)d_in[16];
    const float* fb1  = (const float*)d_in[17];
    const float* fW2  = (const float*)d_in[18];
    const float* fb2  = (const float*)d_in[19];
    const float* bn2g = (const float*)d_in[20];
    const float* bn2b = (const float*)d_in[21];
    const float* oW   = (const float*)d_in[22];
    const float* obv  = (const float*)d_in[23];
    float* out = (float*)d_out;

    float* ws = (float*)d_ws;
    const size_t BIGSZ = (size_t)BB * NN * DD;   // 1048576 floats
    float* xb = ws;                 // batch-major x
    float* xt = ws + 1 * BIGSZ;     // node-major x
    float* hA = ws + 2 * BIGSZ;     // gnn hop1 out (node-major) / x1 (batch-major)
    float* hB = ws + 3 * BIGSZ;     // gnn hop2 out (node-major) / t2 (batch-major)
    short* qb2 = (short*)(ws + 4 * BIGSZ);   // bf16 q (2MB)
    short* kb2 = qb2 + BIGSZ;                // bf16 k (2MB)
    short* vb2 = (short*)(ws + 5 * BIGSZ);   // bf16 v (2MB)
    float* ob = ws + 6 * BIGSZ;
    float* tb = ws + 7 * BIGSZ;
    float* smalls = ws + 8 * BIGSZ;
    float* cnt_f   = smalls;                       // 512
    int*   csr_off = (int*)(smalls + 512);         // 513 (+3 pad)
    int*   csr_src = (int*)(smalls + 512 + 516);   // 8192
    float* stats   = smalls + 512 + 516 + 8192;    // 256: [l][bn1|bn2][64]

    k_csr<<<1, 512, 0, stream>>>(ei, cnt_f, csr_off, csr_src, stats);
    k_emb<<<BB * NN / 8, 256, 0, stream>>>(H, eW1, eb1, eW2, eb2, elg, elb, xb, xt);

    for (int l = 0; l < 2; ++l) {
        const float* gW0 = gW + (size_t)(l * 2 + 0) * 128 * DD;
        const float* gW1 = gW + (size_t)(l * 2 + 1) * 128 * DD;
        const float* gb0 = gb + (size_t)(l * 2 + 0) * DD;
        const float* gb1 = gb + (size_t)(l * 2 + 1) * DD;
        float* st1 = stats + l * 128;
        float* st2 = stats + l * 128 + 64;
        k_gnn<<<NN * 2, 256, 0, stream>>>(xt, hA, cnt_f, csr_off, csr_src, gW0, gb0);
        k_gnn<<<NN * 2, 256, 0, stream>>>(hA, hB, cnt_f, csr_off, csr_src, gW1, gb1);
        k_qkv<<<BB * NN / 8, 256, 0, stream>>>(hB, xb, Wq + l * DD * DD, Wk + l * DD * DD,
                                               Wv + l * DD * DD, qb2, kb2, vb2);
        k_attn<<<BB * NHEADS * 2, 256, 0, stream>>>(qb2, kb2, vb2, ob);
        k_proj_stats<<<512, 256, 0, stream>>>(ob, xb, Wo + l * DD * DD, tb, st1);
        k_ff_stats<<<512, 256, 0, stream>>>(tb, st1, bn1g + l * DD, bn1b + l * DD,
                                            fW1 + l * DD * FFD, fb1 + l * FFD,
                                            fW2 + l * FFD * DD, fb2 + l * DD,
                                            hA, hB, st2);
        k_bn2<<<BB * NN / 8, 256, 0, stream>>>(hB, st2, bn2g + l * DD, bn2b + l * DD,
                                               xb, xt, oW, obv, out, (l == 1) ? 1 : 0);
    }
}

// Round 5
// 264.701 us; speedup vs baseline: 2.1999x; 1.1365x over previous
//
#include <hip/hip_runtime.h>
#include <hip/hip_bf16.h>

#define BB 64
#define NN 512
#define DIN 33
#define DD 32
#define EE 8192
#define NHEADS 4
#define DH 8
#define FFD 64

typedef __attribute__((ext_vector_type(4))) float f32x4;
typedef __attribute__((ext_vector_type(4))) short bf16x4;

static __device__ __forceinline__ short f2bf(float x) {
    unsigned u = __float_as_uint(x);
    u = (u + 0x7FFFu + ((u >> 16) & 1u)) >> 16;
    return (short)u;
}

// truncation-round pack of two f32 -> two bf16 in one u32 (lo = a, hi = b)
static __device__ __forceinline__ unsigned pack_trunc(float a, float b) {
    return (__float_as_uint(a) >> 16) | (__float_as_uint(b) & 0xFFFF0000u);
}

static __device__ __forceinline__ void mfma16(f32x4& d, bf16x4 a, bf16x4 b) {
#if __has_builtin(__builtin_amdgcn_mfma_f32_16x16x16bf16_1k)
    d = __builtin_amdgcn_mfma_f32_16x16x16bf16_1k(a, b, d, 0, 0, 0);
#else
    asm volatile("s_nop 1\n\tv_mfma_f32_16x16x16_bf16 %0, %1, %2, %0\n\ts_nop 7"
                 : "+v"(d) : "v"(a), "v"(b));
#endif
}

// ---------------------------------------------------------------------------
// CSR build + zero BN stats: one block, 512 threads.
// ---------------------------------------------------------------------------
__global__ __launch_bounds__(512) void k_csr(const int* __restrict__ ei,
                                             float* __restrict__ cnt_f,
                                             int* __restrict__ csr_off,
                                             int* __restrict__ csr_src,
                                             float* __restrict__ stats) {
    __shared__ int cnt_s[NN];
    __shared__ int off_s[NN + 1];
    int tid = threadIdx.x;
    cnt_s[tid] = 0;
    if (tid < 256) stats[tid] = 0.f;   // [2 layers][bn1|bn2][sum|sumsq][32]
    __syncthreads();
    const int* src = ei;
    const int* dst = ei + EE;
    for (int e = tid; e < EE; e += 512) atomicAdd(&cnt_s[dst[e]], 1);
    __syncthreads();
    if (tid == 0) {
        int acc = 0;
        for (int n = 0; n < NN; ++n) { off_s[n] = acc; acc += cnt_s[n]; }
        off_s[NN] = acc;
    }
    __syncthreads();
    cnt_f[tid] = (float)cnt_s[tid];
    csr_off[tid] = off_s[tid];
    if (tid == 0) csr_off[NN] = off_s[NN];
    cnt_s[tid] = off_s[tid];   // reuse as cursors
    __syncthreads();
    for (int e = tid; e < EE; e += 512) {
        int d = dst[e];
        int p = atomicAdd(&cnt_s[d], 1);
        csr_src[p] = src[e];
    }
}

// ---------------------------------------------------------------------------
// Embedding: relu(H@W1+b1) -> relu(@W2+b2) -> LN.  Writes batch-major xb AND
// node-major xt.
// ---------------------------------------------------------------------------
__global__ __launch_bounds__(256) void k_emb(const float* __restrict__ H,
                                             const float* __restrict__ W1, const float* __restrict__ b1,
                                             const float* __restrict__ W2, const float* __restrict__ b2,
                                             const float* __restrict__ g,  const float* __restrict__ be,
                                             float* __restrict__ xb, float* __restrict__ xt) {
    __shared__ float sW1[DIN * DD];
    __shared__ float sW2[DD * DD];
    __shared__ float sb1[DD], sb2[DD], sg[DD], sbe[DD];
    __shared__ float sin_[8][DIN + 3];
    int tid = threadIdx.x;
    for (int i = tid; i < DIN * DD; i += 256) sW1[i] = W1[i];
    for (int i = tid; i < DD * DD; i += 256) sW2[i] = W2[i];
    if (tid < DD) { sb1[tid] = b1[tid]; sb2[tid] = b2[tid]; sg[tid] = g[tid]; sbe[tid] = be[tid]; }
    int grp = tid >> 5, lane = tid & 31;
    size_t node = (size_t)blockIdx.x * 8 + grp;
    const float* hrow = H + node * DIN;
    sin_[grp][lane] = hrow[lane];
    if (lane == 0) sin_[grp][32] = hrow[32];
    __syncthreads();
    float acc = sb1[lane];
    #pragma unroll
    for (int i = 0; i < DIN; ++i) acc += sin_[grp][i] * sW1[i * DD + lane];
    acc = fmaxf(acc, 0.f);
    float acc2 = sb2[lane];
    #pragma unroll
    for (int i = 0; i < DD; ++i) acc2 += __shfl(acc, i, 32) * sW2[i * DD + lane];
    acc2 = fmaxf(acc2, 0.f);
    float s = acc2;
    for (int off = 16; off; off >>= 1) s += __shfl_xor(s, off, 32);
    float m = s * (1.f / 32.f);
    float dv = acc2 - m;
    float sq = dv * dv;
    for (int off = 16; off; off >>= 1) sq += __shfl_xor(sq, off, 32);
    float var = sq * (1.f / 32.f);
    float v = dv * rsqrtf(var + 1e-5f) * sg[lane] + sbe[lane];
    xb[node * DD + lane] = v;
    int b = (int)(node >> 9), n = (int)(node & 511);
    xt[(size_t)n * 2048 + b * DD + lane] = v;
}

// ---------------------------------------------------------------------------
// GNN hop (node-major): block = (node, batch-half of 32).  Uniform-index
// coalesced gather (4-deep unrolled) + bf16 MFMA for the 128x32 GEMM.
// do_qkv: instead of writing h, directly project q=h@Wq (pre-scaled),
// k=h@Wk, v=x@Wv with MFMA and write bf16 q/k/v (batch-major).
// ---------------------------------------------------------------------------
__global__ __launch_bounds__(256) void k_gnn(const float* __restrict__ gsrc, float* __restrict__ ht,
                                             const float* __restrict__ cnt_f,
                                             const int* __restrict__ csr_off,
                                             const int* __restrict__ csr_src,
                                             const float* __restrict__ W, const float* __restrict__ bias,
                                             int do_qkv,
                                             const float* __restrict__ xv_src,
                                             const float* __restrict__ Wq, const float* __restrict__ Wk,
                                             const float* __restrict__ Wv,
                                             short* __restrict__ qb2, short* __restrict__ kb2,
                                             short* __restrict__ vb2) {
    __shared__ short conc[32 * 132];   // [b_local][128] bf16, stride 132
    __shared__ short sWt[32 * 132];    // [d][128] bf16 (W transposed), stride 132
    __shared__ short sWqT[32 * 36], sWkT[32 * 36], sWvT[32 * 36];   // [col][k]
    __shared__ short h_lds[32 * 36], x_lds[32 * 36];                // [row][k]
    __shared__ float sb[DD];
    int tid = threadIdx.x;
    int n = blockIdx.x >> 1, half = blockIdx.x & 1;
    for (int i = tid; i < 128 * DD; i += 256) {
        int k = i >> 5, d = i & 31;
        sWt[d * 132 + k] = f2bf(W[i]);
    }
    if (tid < DD) sb[tid] = bias[tid];
    if (do_qkv) {
        const float isq = 0.35355339059327373f;   // 1/sqrt(8)
        for (int i = tid; i < 1024; i += 256) {
            int k = i >> 5, col = i & 31;
            sWqT[col * 36 + k] = f2bf(Wq[i] * isq);
            sWkT[col * 36 + k] = f2bf(Wk[i]);
            sWvT[col * 36 + k] = f2bf(Wv[i]);
        }
        int bl = tid >> 3, d0 = (tid & 7) * 4;
        float4 x4 = *(const float4*)&xv_src[(size_t)n * 2048 + half * 1024 + bl * 32 + d0];
        bf16x4 xp; xp.x = f2bf(x4.x); xp.y = f2bf(x4.y); xp.z = f2bf(x4.z); xp.w = f2bf(x4.w);
        *(bf16x4*)&x_lds[bl * 36 + d0] = xp;
    }
    const float* xbase = gsrc + (size_t)half * 1024 + tid * 4;
    float4 hv = *(const float4*)&xbase[(size_t)n * 2048];
    float4 s = {0.f, 0.f, 0.f, 0.f};
    float4 mx = {-1e30f, -1e30f, -1e30f, -1e30f};
    int beg = csr_off[n], end = csr_off[n + 1];
    int idx = beg;
    for (; idx + 3 < end; idx += 4) {
        int s0 = csr_src[idx], s1 = csr_src[idx + 1], s2 = csr_src[idx + 2], s3 = csr_src[idx + 3];
        float4 v0 = *(const float4*)&xbase[(size_t)s0 * 2048];
        float4 v1 = *(const float4*)&xbase[(size_t)s1 * 2048];
        float4 v2 = *(const float4*)&xbase[(size_t)s2 * 2048];
        float4 v3 = *(const float4*)&xbase[(size_t)s3 * 2048];
        s.x += (v0.x + v1.x) + (v2.x + v3.x);
        s.y += (v0.y + v1.y) + (v2.y + v3.y);
        s.z += (v0.z + v1.z) + (v2.z + v3.z);
        s.w += (v0.w + v1.w) + (v2.w + v3.w);
        mx.x = fmaxf(fmaxf(mx.x, v0.x), fmaxf(v1.x, fmaxf(v2.x, v3.x)));
        mx.y = fmaxf(fmaxf(mx.y, v0.y), fmaxf(v1.y, fmaxf(v2.y, v3.y)));
        mx.z = fmaxf(fmaxf(mx.z, v0.z), fmaxf(v1.z, fmaxf(v2.z, v3.z)));
        mx.w = fmaxf(fmaxf(mx.w, v0.w), fmaxf(v1.w, fmaxf(v2.w, v3.w)));
    }
    for (; idx < end; ++idx) {
        int s0 = csr_src[idx];
        float4 v0 = *(const float4*)&xbase[(size_t)s0 * 2048];
        s.x += v0.x; s.y += v0.y; s.z += v0.z; s.w += v0.w;
        mx.x = fmaxf(mx.x, v0.x); mx.y = fmaxf(mx.y, v0.y);
        mx.z = fmaxf(mx.z, v0.z); mx.w = fmaxf(mx.w, v0.w);
    }
    float c = cnt_f[n];
    float rinv = 1.f / fmaxf(c, 1.f);
    if (!(c > 0.f)) { mx.x = 0.f; mx.y = 0.f; mx.z = 0.f; mx.w = 0.f; }
    int bl = tid >> 3, d0 = (tid & 7) * 4;
    short* cp = &conc[bl * 132];
    bf16x4 t;
    t.x = f2bf(hv.x); t.y = f2bf(hv.y); t.z = f2bf(hv.z); t.w = f2bf(hv.w);
    *(bf16x4*)&cp[d0] = t;
    t.x = f2bf(s.x * rinv); t.y = f2bf(s.y * rinv); t.z = f2bf(s.z * rinv); t.w = f2bf(s.w * rinv);
    *(bf16x4*)&cp[32 + d0] = t;
    t.x = f2bf(mx.x); t.y = f2bf(mx.y); t.z = f2bf(mx.z); t.w = f2bf(mx.w);
    *(bf16x4*)&cp[64 + d0] = t;
    t.x = f2bf(s.x); t.y = f2bf(s.y); t.z = f2bf(s.z); t.w = f2bf(s.w);
    *(bf16x4*)&cp[96 + d0] = t;
    __syncthreads();
    // 32x32 output via 4 waves x one 16x16 C-tile, K=128 in 8 steps.
    int wid = tid >> 6, lane = tid & 63;
    int cc = lane & 15, g = lane >> 4;
    int arow = (wid >> 1) * 16 + cc;     // b_local row of A
    int bcol = (wid & 1) * 16 + cc;      // d col of B
    f32x4 acc = {0.f, 0.f, 0.f, 0.f};
    #pragma unroll
    for (int ks = 0; ks < 8; ++ks) {
        bf16x4 af = *(const bf16x4*)&conc[arow * 132 + ks * 16 + g * 4];
        bf16x4 bfr = *(const bf16x4*)&sWt[bcol * 132 + ks * 16 + g * 4];
        mfma16(acc, af, bfr);
    }
    float bia = sb[bcol];
    int brow = (wid >> 1) * 16 + g * 4;
    if (!do_qkv) {
        float* obase = &ht[(size_t)n * 2048 + half * 1024 + bcol];
        #pragma unroll
        for (int r = 0; r < 4; ++r) {
            obase[(size_t)(brow + r) * DD] = fmaxf(acc[r] + bia, 0.f);
        }
        return;
    }
    // stash relu'd h tile to LDS as A-fragments
    #pragma unroll
    for (int r = 0; r < 4; ++r) {
        h_lds[(brow + r) * 36 + bcol] = f2bf(fmaxf(acc[r] + bia, 0.f));
    }
    __syncthreads();
    // q/k/v projections: wave w -> tile (tr=w>>1, tc=w&1)
    int tr = wid >> 1, tc = wid & 1;
    f32x4 qa = {0.f, 0.f, 0.f, 0.f}, ka = qa, va = qa;
    #pragma unroll
    for (int ks = 0; ks < 2; ++ks) {
        bf16x4 ha = *(const bf16x4*)&h_lds[(tr * 16 + cc) * 36 + ks * 16 + g * 4];
        bf16x4 xa = *(const bf16x4*)&x_lds[(tr * 16 + cc) * 36 + ks * 16 + g * 4];
        bf16x4 wq = *(const bf16x4*)&sWqT[(tc * 16 + cc) * 36 + ks * 16 + g * 4];
        bf16x4 wk = *(const bf16x4*)&sWkT[(tc * 16 + cc) * 36 + ks * 16 + g * 4];
        bf16x4 wv = *(const bf16x4*)&sWvT[(tc * 16 + cc) * 36 + ks * 16 + g * 4];
        mfma16(qa, ha, wq);
        mfma16(ka, ha, wk);
        mfma16(va, xa, wv);
    }
    int dcol = tc * 16 + cc;
    size_t base = ((size_t)(half * 32 + tr * 16 + g * 4) * NN + n) * DD + dcol;
    #pragma unroll
    for (int r = 0; r < 4; ++r) {
        size_t p = base + (size_t)r * (NN * DD);
        qb2[p] = f2bf(qa[r]);
        kb2[p] = f2bf(ka[r]);
        vb2[p] = f2bf(va[r]);
    }
}

// ---------------------------------------------------------------------------
// MFMA attention, no-max softmax (scores are tiny by construction: weights
// ~N(0,0.0025), activations O(1) => |S| << 80, exp(S) safe in fp32).
// Block = (b, head, half of 256 q rows), 256 threads, 4 q-tiles/wave.
// S^T = mfma(K,Q); P^T trunc-packed to bf16 feeds O^T = mfma(V^T,P^T).
// ---------------------------------------------------------------------------
__global__ __launch_bounds__(256) void k_attn(const short* __restrict__ qb2, const short* __restrict__ kb2,
                                              const short* __restrict__ vb2, float* __restrict__ ob) {
    __shared__ short Ks[NN * DH];      // [512][8] bf16, 8 KB
    __shared__ short Vt[DH * 528];     // [8][528] bf16 transposed, 8.25 KB
    __shared__ short Qs[256 * DH];     // [256][8] bf16 (pre-scaled), 4 KB
    int bid = blockIdx.x;
    int qs2 = bid & 1;
    int bh = bid >> 1;
    int h = bh & 3, b = bh >> 2;
    int tid = threadIdx.x;

    {
        int r2 = tid * 2;   // rows r2, r2+1
        size_t g0 = ((size_t)b * NN + r2) * DD + h * DH;
        uint4 k0 = *(const uint4*)&kb2[g0];
        uint4 k1 = *(const uint4*)&kb2[g0 + DD];
        *(uint4*)&Ks[r2 * DH] = k0;
        *(uint4*)&Ks[(r2 + 1) * DH] = k1;
        uint4 v0 = *(const uint4*)&vb2[g0];
        uint4 v1 = *(const uint4*)&vb2[g0 + DD];
        unsigned* vt32 = (unsigned*)Vt;   // [d][264] u32, pair (r2,r2+1) at idx d*264+tid
        vt32[0 * 264 + tid] = (v0.x & 0xFFFFu) | (v1.x << 16);
        vt32[1 * 264 + tid] = (v0.x >> 16)     | (v1.x & 0xFFFF0000u);
        vt32[2 * 264 + tid] = (v0.y & 0xFFFFu) | (v1.y << 16);
        vt32[3 * 264 + tid] = (v0.y >> 16)     | (v1.y & 0xFFFF0000u);
        vt32[4 * 264 + tid] = (v0.z & 0xFFFFu) | (v1.z << 16);
        vt32[5 * 264 + tid] = (v0.z >> 16)     | (v1.z & 0xFFFF0000u);
        vt32[6 * 264 + tid] = (v0.w & 0xFFFFu) | (v1.w << 16);
        vt32[7 * 264 + tid] = (v0.w >> 16)     | (v1.w & 0xFFFF0000u);
    }
    {
        int r = tid;   // 256 q rows, one per thread
        size_t gofs = ((size_t)b * NN + qs2 * 256 + r) * DD + h * DH;
        *(uint4*)&Qs[r * DH] = *(const uint4*)&qb2[gofs];
    }
    __syncthreads();

    int wid = tid >> 6, lane = tid & 63;
    int c = lane & 15, g = lane >> 4;
    bf16x4 z4 = {0, 0, 0, 0};
    bf16x4 qf0 = z4, qf1 = z4, qf2 = z4, qf3 = z4;
    int lt0 = wid * 4;
    if (g < 2) {
        qf0 = *(const bf16x4*)&Qs[((lt0 + 0) * 16 + c) * DH + g * 4];
        qf1 = *(const bf16x4*)&Qs[((lt0 + 1) * 16 + c) * DH + g * 4];
        qf2 = *(const bf16x4*)&Qs[((lt0 + 2) * 16 + c) * DH + g * 4];
        qf3 = *(const bf16x4*)&Qs[((lt0 + 3) * 16 + c) * DH + g * 4];
    }
    float l0 = 0.f, l1 = 0.f, l2 = 0.f, l3 = 0.f;
    f32x4 o0 = {0.f, 0.f, 0.f, 0.f}, o1 = o0, o2 = o0, o3 = o0;
    int c7 = c & 7;

    union U { unsigned u[2]; bf16x4 v4; };

    for (int kc = 0; kc < 32; ++kc) {
        bf16x4 kf = z4;
        if (g < 2) kf = *(const bf16x4*)&Ks[(kc * 16 + c) * DH + g * 4];
        bf16x4 vf = z4;
        {
            bf16x4 vl = *(const bf16x4*)&Vt[c7 * 528 + kc * 16 + g * 4];
            if (c < 8) vf = vl;
        }
        f32x4 st0 = {0.f, 0.f, 0.f, 0.f}, st1 = st0, st2 = st0, st3 = st0;
        mfma16(st0, kf, qf0);
        mfma16(st1, kf, qf1);
        mfma16(st2, kf, qf2);
        mfma16(st3, kf, qf3);
        {
            float p0 = __expf(st0[0]), p1 = __expf(st0[1]), p2 = __expf(st0[2]), p3 = __expf(st0[3]);
            l0 += (p0 + p1) + (p2 + p3);
            U pu; pu.u[0] = pack_trunc(p0, p1); pu.u[1] = pack_trunc(p2, p3);
            mfma16(o0, vf, pu.v4);
        }
        {
            float p0 = __expf(st1[0]), p1 = __expf(st1[1]), p2 = __expf(st1[2]), p3 = __expf(st1[3]);
            l1 += (p0 + p1) + (p2 + p3);
            U pu; pu.u[0] = pack_trunc(p0, p1); pu.u[1] = pack_trunc(p2, p3);
            mfma16(o1, vf, pu.v4);
        }
        {
            float p0 = __expf(st2[0]), p1 = __expf(st2[1]), p2 = __expf(st2[2]), p3 = __expf(st2[3]);
            l2 += (p0 + p1) + (p2 + p3);
            U pu; pu.u[0] = pack_trunc(p0, p1); pu.u[1] = pack_trunc(p2, p3);
            mfma16(o2, vf, pu.v4);
        }
        {
            float p0 = __expf(st3[0]), p1 = __expf(st3[1]), p2 = __expf(st3[2]), p3 = __expf(st3[3]);
            l3 += (p0 + p1) + (p2 + p3);
            U pu; pu.u[0] = pack_trunc(p0, p1); pu.u[1] = pack_trunc(p2, p3);
            mfma16(o3, vf, pu.v4);
        }
    }
    l0 += __shfl_xor(l0, 16, 64); l0 += __shfl_xor(l0, 32, 64);
    l1 += __shfl_xor(l1, 16, 64); l1 += __shfl_xor(l1, 32, 64);
    l2 += __shfl_xor(l2, 16, 64); l2 += __shfl_xor(l2, 32, 64);
    l3 += __shfl_xor(l3, 16, 64); l3 += __shfl_xor(l3, 32, 64);
    if (g < 2) {
        float inv0 = 1.f / l0, inv1 = 1.f / l1, inv2 = 1.f / l2, inv3 = 1.f / l3;
        size_t base = ((size_t)b * NN + qs2 * 256) * DD + h * DH + g * 4;
        float4 r;
        r.x = o0[0] * inv0; r.y = o0[1] * inv0; r.z = o0[2] * inv0; r.w = o0[3] * inv0;
        *(float4*)&ob[base + (size_t)((lt0 + 0) * 16 + c) * DD] = r;
        r.x = o1[0] * inv1; r.y = o1[1] * inv1; r.z = o1[2] * inv1; r.w = o1[3] * inv1;
        *(float4*)&ob[base + (size_t)((lt0 + 1) * 16 + c) * DD] = r;
        r.x = o2[0] * inv2; r.y = o2[1] * inv2; r.z = o2[2] * inv2; r.w = o2[3] * inv2;
        *(float4*)&ob[base + (size_t)((lt0 + 2) * 16 + c) * DD] = r;
        r.x = o3[0] * inv3; r.y = o3[1] * inv3; r.z = o3[2] * inv3; r.w = o3[3] * inv3;
        *(float4*)&ob[base + (size_t)((lt0 + 3) * 16 + c) * DD] = r;
    }
}

// ---------------------------------------------------------------------------
// t = x + o@Wo ; per-channel sum/sumsq partials.
// ---------------------------------------------------------------------------
__global__ __launch_bounds__(256) void k_proj_stats(const float* __restrict__ ob, const float* __restrict__ x,
                                                    const float* __restrict__ Wo,
                                                    float* __restrict__ t, float* __restrict__ stats) {
    __shared__ float sW[DD * DD];
    __shared__ float rs[8][DD], rq[8][DD];
    int tid = threadIdx.x;
    for (int i = tid; i < DD * DD; i += 256) sW[i] = Wo[i];
    __syncthreads();
    int grp = tid >> 5, lane = tid & 31;
    float ls = 0.f, lsq = 0.f;
    for (int it = 0; it < 8; ++it) {
        size_t node = ((size_t)blockIdx.x * 8 + it) * 8 + grp;
        float ov = ob[node * DD + lane];
        float acc = 0.f;
        #pragma unroll
        for (int i = 0; i < DD; ++i) acc += __shfl(ov, i, 32) * sW[i * DD + lane];
        float tv = x[node * DD + lane] + acc;
        t[node * DD + lane] = tv;
        ls += tv; lsq += tv * tv;
    }
    rs[grp][lane] = ls; rq[grp][lane] = lsq;
    __syncthreads();
    if (tid < DD) {
        float a = 0.f, b2 = 0.f;
        for (int g2 = 0; g2 < 8; ++g2) { a += rs[g2][tid]; b2 += rq[g2][tid]; }
        atomicAdd(&stats[tid], a);
        atomicAdd(&stats[DD + tid], b2);
    }
}

// ---------------------------------------------------------------------------
// x1 = BN1(t) ; f = relu(x1@W1+b1)@W2+b2 ; t2 = x1+f ; stats2 accumulate.
// ---------------------------------------------------------------------------
__global__ __launch_bounds__(256) void k_ff_stats(const float* __restrict__ t, const float* __restrict__ stats,
                                                  const float* __restrict__ g1, const float* __restrict__ be1,
                                                  const float* __restrict__ W1, const float* __restrict__ fb1,
                                                  const float* __restrict__ W2, const float* __restrict__ fb2,
                                                  float* __restrict__ x1, float* __restrict__ t2,
                                                  float* __restrict__ stats2) {
    __shared__ float sW1[DD * FFD];
    __shared__ float sW2[FFD * DD];
    __shared__ float sfb1[FFD];
    __shared__ float rs[8][DD], rq[8][DD];
    int tid = threadIdx.x;
    for (int i = tid; i < DD * FFD; i += 256) { sW1[i] = W1[i]; sW2[i] = W2[i]; }
    if (tid < FFD) sfb1[tid] = fb1[tid];
    __syncthreads();
    int grp = tid >> 5, lane = tid & 31;
    float mean  = stats[lane] * (1.f / 32768.f);
    float var   = stats[DD + lane] * (1.f / 32768.f) - mean * mean;
    float scale = rsqrtf(var + 1e-5f) * g1[lane];
    float shift = be1[lane];
    float fb2v  = fb2[lane];
    float ls = 0.f, lsq = 0.f;
    for (int it = 0; it < 8; ++it) {
        size_t node = ((size_t)blockIdx.x * 8 + it) * 8 + grp;
        float tv = t[node * DD + lane];
        float xv = (tv - mean) * scale + shift;
        x1[node * DD + lane] = xv;
        float a0 = sfb1[lane], a1 = sfb1[lane + 32];
        #pragma unroll
        for (int i = 0; i < DD; ++i) {
            float xi = __shfl(xv, i, 32);
            a0 += xi * sW1[i * FFD + lane];
            a1 += xi * sW1[i * FFD + lane + 32];
        }
        a0 = fmaxf(a0, 0.f); a1 = fmaxf(a1, 0.f);
        float f = fb2v;
        #pragma unroll
        for (int i = 0; i < DD; ++i) {
            float h0 = __shfl(a0, i, 32);
            float h1 = __shfl(a1, i, 32);
            f += h0 * sW2[i * DD + lane] + h1 * sW2[(i + 32) * DD + lane];
        }
        float t2v = xv + f;
        t2[node * DD + lane] = t2v;
        ls += t2v; lsq += t2v * t2v;
    }
    rs[grp][lane] = ls; rq[grp][lane] = lsq;
    __syncthreads();
    if (tid < DD) {
        float a = 0.f, b2 = 0.f;
        for (int g2 = 0; g2 < 8; ++g2) { a += rs[g2][tid]; b2 += rq[g2][tid]; }
        atomicAdd(&stats2[tid], a);
        atomicAdd(&stats2[DD + tid], b2);
    }
}

// ---------------------------------------------------------------------------
// x = BN2(t2) -> xb, xt; if do_proj: out = x@out_W + out_b.
// ---------------------------------------------------------------------------
__global__ __launch_bounds__(256) void k_bn2(const float* __restrict__ t2, const float* __restrict__ stats2,
                                             const float* __restrict__ g, const float* __restrict__ be,
                                             float* __restrict__ xout, float* __restrict__ xtout,
                                             const float* __restrict__ outW, const float* __restrict__ outb,
                                             float* __restrict__ fout, int do_proj) {
    __shared__ float sW[DD * DD];
    int tid = threadIdx.x;
    if (do_proj) for (int i = tid; i < DD * DD; i += 256) sW[i] = outW[i];
    __syncthreads();
    int grp = tid >> 5, lane = tid & 31;
    float mean  = stats2[lane] * (1.f / 32768.f);
    float var   = stats2[DD + lane] * (1.f / 32768.f) - mean * mean;
    float scale = rsqrtf(var + 1e-5f) * g[lane];
    float shift = be[lane];
    size_t node = (size_t)blockIdx.x * 8 + grp;
    float tv = t2[node * DD + lane];
    float xv = (tv - mean) * scale + shift;
    xout[node * DD + lane] = xv;
    int b = (int)(node >> 9), n = (int)(node & 511);
    xtout[(size_t)n * 2048 + b * DD + lane] = xv;
    if (do_proj) {
        float acc = outb[lane];
        #pragma unroll
        for (int i = 0; i < DD; ++i) acc += __shfl(xv, i, 32) * sW[i * DD + lane];
        fout[node * DD + lane] = acc;
    }
}

// ---------------------------------------------------------------------------
extern "C" void kernel_launch(void* const* d_in, const int* in_sizes, int n_in,
                              void* d_out, int out_size, void* d_ws, size_t ws_size,
                              hipStream_t stream) {
    const float* H    = (const float*)d_in[0];
    const int*   ei   = (const int*)  d_in[1];
    const float* eW1  = (const float*)d_in[2];
    const float* eb1  = (const float*)d_in[3];
    const float* eW2  = (const float*)d_in[4];
    const float* eb2  = (const float*)d_in[5];
    const float* elg  = (const float*)d_in[6];
    const float* elb  = (const float*)d_in[7];
    const float* gW   = (const float*)d_in[8];
    const float* gb   = (const float*)d_in[9];
    const float* Wq   = (const float*)d_in[10];
    const float* Wk   = (const float*)d_in[11];
    const float* Wv   = (const float*)d_in[12];
    const float* Wo   = (const float*)d_in[13];
    const float* bn1g = (const float*)d_in[14];
    const float* bn1b = (const float*)d_in[15];
    const float* fW1  = (const float*)d_in[16];
    const float* fb1  = (const float*)d_in[17];
    const float* fW2  = (const float*)d_in[18];
    const float* fb2  = (const float*)d_in[19];
    const float* bn2g = (const float*)d_in[20];
    const float* bn2b = (const float*)d_in[21];
    const float* oW   = (const float*)d_in[22];
    const float* obv  = (const float*)d_in[23];
    float* out = (float*)d_out;

    float* ws = (float*)d_ws;
    const size_t BIGSZ = (size_t)BB * NN * DD;   // 1048576 floats
    float* xb = ws;                 // batch-major x
    float* xt = ws + 1 * BIGSZ;     // node-major x
    float* hA = ws + 2 * BIGSZ;     // gnn hop1 out (node-major) / x1 (batch-major)
    float* hB = ws + 3 * BIGSZ;     // t2 (batch-major)
    short* qb2 = (short*)(ws + 4 * BIGSZ);   // bf16 q (2MB)
    short* kb2 = qb2 + BIGSZ;                // bf16 k (2MB)
    short* vb2 = (short*)(ws + 5 * BIGSZ);   // bf16 v (2MB)
    float* ob = ws + 6 * BIGSZ;
    float* tb = ws + 7 * BIGSZ;
    float* smalls = ws + 8 * BIGSZ;
    float* cnt_f   = smalls;                       // 512
    int*   csr_off = (int*)(smalls + 512);         // 513 (+3 pad)
    int*   csr_src = (int*)(smalls + 512 + 516);   // 8192
    float* stats   = smalls + 512 + 516 + 8192;    // 256: [l][bn1|bn2][64]

    k_csr<<<1, 512, 0, stream>>>(ei, cnt_f, csr_off, csr_src, stats);
    k_emb<<<BB * NN / 8, 256, 0, stream>>>(H, eW1, eb1, eW2, eb2, elg, elb, xb, xt);

    for (int l = 0; l < 2; ++l) {
        const float* gW0 = gW + (size_t)(l * 2 + 0) * 128 * DD;
        const float* gW1 = gW + (size_t)(l * 2 + 1) * 128 * DD;
        const float* gb0 = gb + (size_t)(l * 2 + 0) * DD;
        const float* gb1 = gb + (size_t)(l * 2 + 1) * DD;
        float* st1 = stats + l * 128;
        float* st2 = stats + l * 128 + 64;
        k_gnn<<<NN * 2, 256, 0, stream>>>(xt, hA, cnt_f, csr_off, csr_src, gW0, gb0,
                                          0, nullptr, nullptr, nullptr, nullptr,
                                          nullptr, nullptr, nullptr);
        k_gnn<<<NN * 2, 256, 0, stream>>>(hA, nullptr, cnt_f, csr_off, csr_src, gW1, gb1,
                                          1, xt, Wq + l * DD * DD, Wk + l * DD * DD,
                                          Wv + l * DD * DD, qb2, kb2, vb2);
        k_attn<<<BB * NHEADS * 2, 256, 0, stream>>>(qb2, kb2, vb2, ob);
        k_proj_stats<<<512, 256, 0, stream>>>(ob, xb, Wo + l * DD * DD, tb, st1);
        k_ff_stats<<<512, 256, 0, stream>>>(tb, st1, bn1g + l * DD, bn1b + l * DD,
                                            fW1 + l * DD * FFD, fb1 + l * FFD,
                                            fW2 + l * FFD * DD, fb2 + l * DD,
                                            hA, hB, st2);
        k_bn2<<<BB * NN / 8, 256, 0, stream>>>(hB, st2, bn2g + l * DD, bn2b + l * DD,
                                               xb, xt, oW, obv, out, (l == 1) ? 1 : 0);
    }
}

// Round 6
// 218.868 us; speedup vs baseline: 2.6605x; 1.2094x over previous
//
#include <hip/hip_runtime.h>
#include <hip/hip_bf16.h>

#define BB 64
#define NN 512
#define DIN 33
#define DD 32
#define EE 8192
#define NHEADS 4
#define DH 8
#define FFD 64

typedef __attribute__((ext_vector_type(4))) float f32x4;
typedef __attribute__((ext_vector_type(4))) short bf16x4;

static __device__ __forceinline__ short f2bf(float x) {
    unsigned u = __float_as_uint(x);
    u = (u + 0x7FFFu + ((u >> 16) & 1u)) >> 16;
    return (short)u;
}

// truncation-round pack of two f32 -> two bf16 in one u32 (lo = a, hi = b)
static __device__ __forceinline__ unsigned pack_trunc(float a, float b) {
    return (__float_as_uint(a) >> 16) | (__float_as_uint(b) & 0xFFFF0000u);
}

static __device__ __forceinline__ void mfma16(f32x4& d, bf16x4 a, bf16x4 b) {
#if __has_builtin(__builtin_amdgcn_mfma_f32_16x16x16bf16_1k)
    d = __builtin_amdgcn_mfma_f32_16x16x16bf16_1k(a, b, d, 0, 0, 0);
#else
    asm volatile("s_nop 1\n\tv_mfma_f32_16x16x16_bf16 %0, %1, %2, %0\n\ts_nop 7"
                 : "+v"(d) : "v"(a), "v"(b));
#endif
}

// ---------------------------------------------------------------------------
// CSR build + zero BN stats: one block, 512 threads.
// ---------------------------------------------------------------------------
__global__ __launch_bounds__(512) void k_csr(const int* __restrict__ ei,
                                             float* __restrict__ cnt_f,
                                             int* __restrict__ csr_off,
                                             int* __restrict__ csr_src,
                                             float* __restrict__ stats) {
    __shared__ int cnt_s[NN];
    __shared__ int off_s[NN + 1];
    int tid = threadIdx.x;
    cnt_s[tid] = 0;
    if (tid < 256) stats[tid] = 0.f;   // [2 layers][bn1|bn2][sum|sumsq][32]
    __syncthreads();
    const int* src = ei;
    const int* dst = ei + EE;
    for (int e = tid; e < EE; e += 512) atomicAdd(&cnt_s[dst[e]], 1);
    __syncthreads();
    if (tid == 0) {
        int acc = 0;
        for (int n = 0; n < NN; ++n) { off_s[n] = acc; acc += cnt_s[n]; }
        off_s[NN] = acc;
    }
    __syncthreads();
    cnt_f[tid] = (float)cnt_s[tid];
    csr_off[tid] = off_s[tid];
    if (tid == 0) csr_off[NN] = off_s[NN];
    cnt_s[tid] = off_s[tid];   // reuse as cursors
    __syncthreads();
    for (int e = tid; e < EE; e += 512) {
        int d = dst[e];
        int p = atomicAdd(&cnt_s[d], 1);
        csr_src[p] = src[e];
    }
}

// ---------------------------------------------------------------------------
// Embedding: relu(H@W1+b1) -> relu(@W2+b2) -> LN.  Writes batch-major xb AND
// node-major xt.
// ---------------------------------------------------------------------------
__global__ __launch_bounds__(256) void k_emb(const float* __restrict__ H,
                                             const float* __restrict__ W1, const float* __restrict__ b1,
                                             const float* __restrict__ W2, const float* __restrict__ b2,
                                             const float* __restrict__ g,  const float* __restrict__ be,
                                             float* __restrict__ xb, float* __restrict__ xt) {
    __shared__ float sW1[DIN * DD];
    __shared__ float sW2[DD * DD];
    __shared__ float sb1[DD], sb2[DD], sg[DD], sbe[DD];
    __shared__ float sin_[8][DIN + 3];
    int tid = threadIdx.x;
    for (int i = tid; i < DIN * DD; i += 256) sW1[i] = W1[i];
    for (int i = tid; i < DD * DD; i += 256) sW2[i] = W2[i];
    if (tid < DD) { sb1[tid] = b1[tid]; sb2[tid] = b2[tid]; sg[tid] = g[tid]; sbe[tid] = be[tid]; }
    int grp = tid >> 5, lane = tid & 31;
    size_t node = (size_t)blockIdx.x * 8 + grp;
    const float* hrow = H + node * DIN;
    sin_[grp][lane] = hrow[lane];
    if (lane == 0) sin_[grp][32] = hrow[32];
    __syncthreads();
    float acc = sb1[lane];
    #pragma unroll
    for (int i = 0; i < DIN; ++i) acc += sin_[grp][i] * sW1[i * DD + lane];
    acc = fmaxf(acc, 0.f);
    float acc2 = sb2[lane];
    #pragma unroll
    for (int i = 0; i < DD; ++i) acc2 += __shfl(acc, i, 32) * sW2[i * DD + lane];
    acc2 = fmaxf(acc2, 0.f);
    float s = acc2;
    for (int off = 16; off; off >>= 1) s += __shfl_xor(s, off, 32);
    float m = s * (1.f / 32.f);
    float dv = acc2 - m;
    float sq = dv * dv;
    for (int off = 16; off; off >>= 1) sq += __shfl_xor(sq, off, 32);
    float var = sq * (1.f / 32.f);
    float v = dv * rsqrtf(var + 1e-5f) * sg[lane] + sbe[lane];
    xb[node * DD + lane] = v;
    int b = (int)(node >> 9), n = (int)(node & 511);
    xt[(size_t)n * 2048 + b * DD + lane] = v;
}

// ---------------------------------------------------------------------------
// GNN hop (node-major): block = (node, batch-half of 32).  Uniform-index
// coalesced gather (4-deep unrolled) + bf16 MFMA for the 128x32 GEMM.
// do_qkv: project q=h@Wq (pre-scaled), k=h@Wk, v=x@Wv, write bf16 batch-major.
// ---------------------------------------------------------------------------
__global__ __launch_bounds__(256) void k_gnn(const float* __restrict__ gsrc, float* __restrict__ ht,
                                             const float* __restrict__ cnt_f,
                                             const int* __restrict__ csr_off,
                                             const int* __restrict__ csr_src,
                                             const float* __restrict__ W, const float* __restrict__ bias,
                                             int do_qkv,
                                             const float* __restrict__ xv_src,
                                             const float* __restrict__ Wq, const float* __restrict__ Wk,
                                             const float* __restrict__ Wv,
                                             short* __restrict__ qb2, short* __restrict__ kb2,
                                             short* __restrict__ vb2) {
    __shared__ short conc[32 * 132];   // [b_local][128] bf16, stride 132
    __shared__ short sWt[32 * 132];    // [d][128] bf16 (W transposed), stride 132
    __shared__ short sWqT[32 * 36], sWkT[32 * 36], sWvT[32 * 36];   // [col][k]
    __shared__ short h_lds[32 * 36], x_lds[32 * 36];                // [row][k]
    __shared__ float sb[DD];
    int tid = threadIdx.x;
    int n = blockIdx.x >> 1, half = blockIdx.x & 1;
    for (int i = tid; i < 128 * DD; i += 256) {
        int k = i >> 5, d = i & 31;
        sWt[d * 132 + k] = f2bf(W[i]);
    }
    if (tid < DD) sb[tid] = bias[tid];
    if (do_qkv) {
        const float isq = 0.35355339059327373f;   // 1/sqrt(8)
        for (int i = tid; i < 1024; i += 256) {
            int k = i >> 5, col = i & 31;
            sWqT[col * 36 + k] = f2bf(Wq[i] * isq);
            sWkT[col * 36 + k] = f2bf(Wk[i]);
            sWvT[col * 36 + k] = f2bf(Wv[i]);
        }
        int bl = tid >> 3, d0 = (tid & 7) * 4;
        float4 x4 = *(const float4*)&xv_src[(size_t)n * 2048 + half * 1024 + bl * 32 + d0];
        bf16x4 xp; xp.x = f2bf(x4.x); xp.y = f2bf(x4.y); xp.z = f2bf(x4.z); xp.w = f2bf(x4.w);
        *(bf16x4*)&x_lds[bl * 36 + d0] = xp;
    }
    const float* xbase = gsrc + (size_t)half * 1024 + tid * 4;
    float4 hv = *(const float4*)&xbase[(size_t)n * 2048];
    float4 s = {0.f, 0.f, 0.f, 0.f};
    float4 mx = {-1e30f, -1e30f, -1e30f, -1e30f};
    int beg = csr_off[n], end = csr_off[n + 1];
    int idx = beg;
    for (; idx + 3 < end; idx += 4) {
        int s0 = csr_src[idx], s1 = csr_src[idx + 1], s2 = csr_src[idx + 2], s3 = csr_src[idx + 3];
        float4 v0 = *(const float4*)&xbase[(size_t)s0 * 2048];
        float4 v1 = *(const float4*)&xbase[(size_t)s1 * 2048];
        float4 v2 = *(const float4*)&xbase[(size_t)s2 * 2048];
        float4 v3 = *(const float4*)&xbase[(size_t)s3 * 2048];
        s.x += (v0.x + v1.x) + (v2.x + v3.x);
        s.y += (v0.y + v1.y) + (v2.y + v3.y);
        s.z += (v0.z + v1.z) + (v2.z + v3.z);
        s.w += (v0.w + v1.w) + (v2.w + v3.w);
        mx.x = fmaxf(fmaxf(mx.x, v0.x), fmaxf(v1.x, fmaxf(v2.x, v3.x)));
        mx.y = fmaxf(fmaxf(mx.y, v0.y), fmaxf(v1.y, fmaxf(v2.y, v3.y)));
        mx.z = fmaxf(fmaxf(mx.z, v0.z), fmaxf(v1.z, fmaxf(v2.z, v3.z)));
        mx.w = fmaxf(fmaxf(mx.w, v0.w), fmaxf(v1.w, fmaxf(v2.w, v3.w)));
    }
    for (; idx < end; ++idx) {
        int s0 = csr_src[idx];
        float4 v0 = *(const float4*)&xbase[(size_t)s0 * 2048];
        s.x += v0.x; s.y += v0.y; s.z += v0.z; s.w += v0.w;
        mx.x = fmaxf(mx.x, v0.x); mx.y = fmaxf(mx.y, v0.y);
        mx.z = fmaxf(mx.z, v0.z); mx.w = fmaxf(mx.w, v0.w);
    }
    float c = cnt_f[n];
    float rinv = 1.f / fmaxf(c, 1.f);
    if (!(c > 0.f)) { mx.x = 0.f; mx.y = 0.f; mx.z = 0.f; mx.w = 0.f; }
    int bl = tid >> 3, d0 = (tid & 7) * 4;
    short* cp = &conc[bl * 132];
    bf16x4 t;
    t.x = f2bf(hv.x); t.y = f2bf(hv.y); t.z = f2bf(hv.z); t.w = f2bf(hv.w);
    *(bf16x4*)&cp[d0] = t;
    t.x = f2bf(s.x * rinv); t.y = f2bf(s.y * rinv); t.z = f2bf(s.z * rinv); t.w = f2bf(s.w * rinv);
    *(bf16x4*)&cp[32 + d0] = t;
    t.x = f2bf(mx.x); t.y = f2bf(mx.y); t.z = f2bf(mx.z); t.w = f2bf(mx.w);
    *(bf16x4*)&cp[64 + d0] = t;
    t.x = f2bf(s.x); t.y = f2bf(s.y); t.z = f2bf(s.z); t.w = f2bf(s.w);
    *(bf16x4*)&cp[96 + d0] = t;
    __syncthreads();
    // 32x32 output via 4 waves x one 16x16 C-tile, K=128 in 8 steps.
    int wid = tid >> 6, lane = tid & 63;
    int cc = lane & 15, g = lane >> 4;
    int arow = (wid >> 1) * 16 + cc;     // b_local row of A
    int bcol = (wid & 1) * 16 + cc;      // d col of B
    f32x4 acc = {0.f, 0.f, 0.f, 0.f};
    #pragma unroll
    for (int ks = 0; ks < 8; ++ks) {
        bf16x4 af = *(const bf16x4*)&conc[arow * 132 + ks * 16 + g * 4];
        bf16x4 bfr = *(const bf16x4*)&sWt[bcol * 132 + ks * 16 + g * 4];
        mfma16(acc, af, bfr);
    }
    float bia = sb[bcol];
    int brow = (wid >> 1) * 16 + g * 4;
    if (!do_qkv) {
        float* obase = &ht[(size_t)n * 2048 + half * 1024 + bcol];
        #pragma unroll
        for (int r = 0; r < 4; ++r) {
            obase[(size_t)(brow + r) * DD] = fmaxf(acc[r] + bia, 0.f);
        }
        return;
    }
    #pragma unroll
    for (int r = 0; r < 4; ++r) {
        h_lds[(brow + r) * 36 + bcol] = f2bf(fmaxf(acc[r] + bia, 0.f));
    }
    __syncthreads();
    int tr = wid >> 1, tc = wid & 1;
    f32x4 qa = {0.f, 0.f, 0.f, 0.f}, ka = qa, va = qa;
    #pragma unroll
    for (int ks = 0; ks < 2; ++ks) {
        bf16x4 ha = *(const bf16x4*)&h_lds[(tr * 16 + cc) * 36 + ks * 16 + g * 4];
        bf16x4 xa = *(const bf16x4*)&x_lds[(tr * 16 + cc) * 36 + ks * 16 + g * 4];
        bf16x4 wq = *(const bf16x4*)&sWqT[(tc * 16 + cc) * 36 + ks * 16 + g * 4];
        bf16x4 wk = *(const bf16x4*)&sWkT[(tc * 16 + cc) * 36 + ks * 16 + g * 4];
        bf16x4 wv = *(const bf16x4*)&sWvT[(tc * 16 + cc) * 36 + ks * 16 + g * 4];
        mfma16(qa, ha, wq);
        mfma16(ka, ha, wk);
        mfma16(va, xa, wv);
    }
    int dcol = tc * 16 + cc;
    size_t base = ((size_t)(half * 32 + tr * 16 + g * 4) * NN + n) * DD + dcol;
    #pragma unroll
    for (int r = 0; r < 4; ++r) {
        size_t p = base + (size_t)r * (NN * DD);
        qb2[p] = f2bf(qa[r]);
        kb2[p] = f2bf(ka[r]);
        vb2[p] = f2bf(va[r]);
    }
}

// ---------------------------------------------------------------------------
// Attention + Wo projection + residual + BN1 stats.
// Block = (b, 64-q-row slice qs of 8), 256 threads, wave = head.
// K,Q fragments read directly from global (each row consumed once, L2-hot);
// V transposed in LDS.  No-max softmax (|S| tiny by construction).
// Epilogue: O (bf16, LDS) @ Wo via MFMA + x residual -> t, and BN1 partial
// sums accumulated to stats.
// ---------------------------------------------------------------------------
__global__ __launch_bounds__(256) void k_attn_proj(const short* __restrict__ qb2,
                                                   const short* __restrict__ kb2,
                                                   const short* __restrict__ vb2,
                                                   const float* __restrict__ x,
                                                   const float* __restrict__ Wo,
                                                   float* __restrict__ t,
                                                   float* __restrict__ stats) {
    __shared__ short Vt[NHEADS * DH * 528];   // [h][d][528] bf16, 33 KB
    __shared__ short Ot[64 * 36];             // o rows x 32 feat, 4.6 KB
    __shared__ short sWoT[DD * 36];           // [col][k], 2.3 KB
    __shared__ float rs[4][DD], rq[4][DD];
    int bid = blockIdx.x;
    int qs = bid & 7, b = bid >> 3;
    int tid = threadIdx.x;

    for (int i = tid; i < 1024; i += 256) {
        int k = i >> 5, col = i & 31;
        sWoT[col * 36 + k] = f2bf(Wo[i]);
    }
    {   // V transpose staging: thread -> row pair (2*tid, 2*tid+1)
        size_t g0 = ((size_t)b * NN + tid * 2) * DD;
        #pragma unroll
        for (int h2 = 0; h2 < 4; ++h2) {
            uint4 v0 = *(const uint4*)&vb2[g0 + h2 * 8];
            uint4 v1 = *(const uint4*)&vb2[g0 + DD + h2 * 8];
            unsigned* vt = (unsigned*)&Vt[h2 * DH * 528];
            vt[0 * 264 + tid] = (v0.x & 0xFFFFu) | (v1.x << 16);
            vt[1 * 264 + tid] = (v0.x >> 16)     | (v1.x & 0xFFFF0000u);
            vt[2 * 264 + tid] = (v0.y & 0xFFFFu) | (v1.y << 16);
            vt[3 * 264 + tid] = (v0.y >> 16)     | (v1.y & 0xFFFF0000u);
            vt[4 * 264 + tid] = (v0.z & 0xFFFFu) | (v1.z << 16);
            vt[5 * 264 + tid] = (v0.z >> 16)     | (v1.z & 0xFFFF0000u);
            vt[6 * 264 + tid] = (v0.w & 0xFFFFu) | (v1.w << 16);
            vt[7 * 264 + tid] = (v0.w >> 16)     | (v1.w & 0xFFFF0000u);
        }
    }
    __syncthreads();

    int h = tid >> 6, lane = tid & 63;
    int c = lane & 15, g = lane >> 4;
    int c7 = c & 7;
    bf16x4 z4 = {0, 0, 0, 0};
    bf16x4 qf0 = z4, qf1 = z4, qf2 = z4, qf3 = z4;
    if (g < 2) {
        const short* qbase = &qb2[(((size_t)b * NN + qs * 64) * DD) + h * DH + g * 4];
        qf0 = *(const bf16x4*)&qbase[(size_t)(c) * DD];
        qf1 = *(const bf16x4*)&qbase[(size_t)(16 + c) * DD];
        qf2 = *(const bf16x4*)&qbase[(size_t)(32 + c) * DD];
        qf3 = *(const bf16x4*)&qbase[(size_t)(48 + c) * DD];
    }
    const short* kbase = &kb2[((size_t)b * NN) * DD + h * DH + g * 4];
    float l0 = 0.f, l1 = 0.f, l2 = 0.f, l3 = 0.f;
    f32x4 o0 = {0.f, 0.f, 0.f, 0.f}, o1 = o0, o2 = o0, o3 = o0;
    union U { unsigned u[2]; bf16x4 v4; };

    for (int kc = 0; kc < 32; ++kc) {
        bf16x4 kf = z4;
        if (g < 2) kf = *(const bf16x4*)&kbase[(size_t)(kc * 16 + c) * DD];
        bf16x4 vf = z4;
        {
            bf16x4 vl = *(const bf16x4*)&Vt[(h * DH + c7) * 528 + kc * 16 + g * 4];
            if (c < 8) vf = vl;
        }
        f32x4 st0 = {0.f, 0.f, 0.f, 0.f}, st1 = st0, st2 = st0, st3 = st0;
        mfma16(st0, kf, qf0);
        mfma16(st1, kf, qf1);
        mfma16(st2, kf, qf2);
        mfma16(st3, kf, qf3);
        {
            float p0 = __expf(st0[0]), p1 = __expf(st0[1]), p2 = __expf(st0[2]), p3 = __expf(st0[3]);
            l0 += (p0 + p1) + (p2 + p3);
            U pu; pu.u[0] = pack_trunc(p0, p1); pu.u[1] = pack_trunc(p2, p3);
            mfma16(o0, vf, pu.v4);
        }
        {
            float p0 = __expf(st1[0]), p1 = __expf(st1[1]), p2 = __expf(st1[2]), p3 = __expf(st1[3]);
            l1 += (p0 + p1) + (p2 + p3);
            U pu; pu.u[0] = pack_trunc(p0, p1); pu.u[1] = pack_trunc(p2, p3);
            mfma16(o1, vf, pu.v4);
        }
        {
            float p0 = __expf(st2[0]), p1 = __expf(st2[1]), p2 = __expf(st2[2]), p3 = __expf(st2[3]);
            l2 += (p0 + p1) + (p2 + p3);
            U pu; pu.u[0] = pack_trunc(p0, p1); pu.u[1] = pack_trunc(p2, p3);
            mfma16(o2, vf, pu.v4);
        }
        {
            float p0 = __expf(st3[0]), p1 = __expf(st3[1]), p2 = __expf(st3[2]), p3 = __expf(st3[3]);
            l3 += (p0 + p1) + (p2 + p3);
            U pu; pu.u[0] = pack_trunc(p0, p1); pu.u[1] = pack_trunc(p2, p3);
            mfma16(o3, vf, pu.v4);
        }
    }
    l0 += __shfl_xor(l0, 16, 64); l0 += __shfl_xor(l0, 32, 64);
    l1 += __shfl_xor(l1, 16, 64); l1 += __shfl_xor(l1, 32, 64);
    l2 += __shfl_xor(l2, 16, 64); l2 += __shfl_xor(l2, 32, 64);
    l3 += __shfl_xor(l3, 16, 64); l3 += __shfl_xor(l3, 32, 64);
    if (g < 2) {
        float inv0 = 1.f / l0, inv1 = 1.f / l1, inv2 = 1.f / l2, inv3 = 1.f / l3;
        int fb = h * DH + g * 4;
        #pragma unroll
        for (int r = 0; r < 4; ++r) {
            Ot[(c) * 36 + fb + r]      = f2bf(o0[r] * inv0);
            Ot[(16 + c) * 36 + fb + r] = f2bf(o1[r] * inv1);
            Ot[(32 + c) * 36 + fb + r] = f2bf(o2[r] * inv2);
            Ot[(48 + c) * 36 + fb + r] = f2bf(o3[r] * inv3);
        }
    }
    __syncthreads();
    // t = x + O@Wo ; wave h handles rows h*16..h*16+15, both 16-col tiles.
    f32x4 pa0 = {0.f, 0.f, 0.f, 0.f}, pa1 = pa0;
    #pragma unroll
    for (int ks = 0; ks < 2; ++ks) {
        bf16x4 af = *(const bf16x4*)&Ot[(h * 16 + c) * 36 + ks * 16 + g * 4];
        bf16x4 b0 = *(const bf16x4*)&sWoT[c * 36 + ks * 16 + g * 4];
        bf16x4 b1 = *(const bf16x4*)&sWoT[(16 + c) * 36 + ks * 16 + g * 4];
        mfma16(pa0, af, b0);
        mfma16(pa1, af, b1);
    }
    float ls0 = 0.f, lq0 = 0.f, ls1 = 0.f, lq1 = 0.f;
    size_t rowbase = ((size_t)b * NN + qs * 64 + h * 16 + g * 4) * DD;
    #pragma unroll
    for (int r = 0; r < 4; ++r) {
        float xv0 = x[rowbase + (size_t)r * DD + c];
        float tv0 = xv0 + pa0[r];
        t[rowbase + (size_t)r * DD + c] = tv0;
        ls0 += tv0; lq0 += tv0 * tv0;
        float xv1 = x[rowbase + (size_t)r * DD + 16 + c];
        float tv1 = xv1 + pa1[r];
        t[rowbase + (size_t)r * DD + 16 + c] = tv1;
        ls1 += tv1; lq1 += tv1 * tv1;
    }
    ls0 += __shfl_xor(ls0, 16, 64); ls0 += __shfl_xor(ls0, 32, 64);
    lq0 += __shfl_xor(lq0, 16, 64); lq0 += __shfl_xor(lq0, 32, 64);
    ls1 += __shfl_xor(ls1, 16, 64); ls1 += __shfl_xor(ls1, 32, 64);
    lq1 += __shfl_xor(lq1, 16, 64); lq1 += __shfl_xor(lq1, 32, 64);
    if (g == 0) {
        rs[h][c] = ls0; rs[h][16 + c] = ls1;
        rq[h][c] = lq0; rq[h][16 + c] = lq1;
    }
    __syncthreads();
    if (tid < DD) {
        float a = (rs[0][tid] + rs[1][tid]) + (rs[2][tid] + rs[3][tid]);
        float b2 = (rq[0][tid] + rq[1][tid]) + (rq[2][tid] + rq[3][tid]);
        atomicAdd(&stats[tid], a);
        atomicAdd(&stats[DD + tid], b2);
    }
}

// ---------------------------------------------------------------------------
// FF (MFMA): x1 = BN1(t); mid = relu(x1@W1+b1); t2 = x1 + mid@W2+b2; stats2.
// Block = 64 nodes, 256 threads.  x1 lives only in LDS (bf16 for MFMA A,
// f32 for the residual).
// ---------------------------------------------------------------------------
__global__ __launch_bounds__(256) void k_ff(const float* __restrict__ t, const float* __restrict__ stats,
                                            const float* __restrict__ g1, const float* __restrict__ be1,
                                            const float* __restrict__ W1, const float* __restrict__ fb1,
                                            const float* __restrict__ W2, const float* __restrict__ fb2,
                                            float* __restrict__ t2, float* __restrict__ stats2) {
    __shared__ short x1b[64 * 36];     // bf16 x1, 4.6 KB
    __shared__ float x1f[64 * 33];     // f32 x1, 8.4 KB
    __shared__ short hm[64 * 68];      // bf16 mid, 8.7 KB
    __shared__ short sW1T[FFD * 36];   // [col][k], 4.6 KB
    __shared__ short sW2T[DD * 68];    // [col][k], 4.4 KB
    __shared__ float sc[DD], sm[DD], sbe[DD], sb2v[DD];
    __shared__ float sb1v[FFD];
    __shared__ float rs[4][DD], rq[4][DD];
    int tid = threadIdx.x;
    for (int i = tid; i < 2048; i += 256) {
        int k = i >> 6, col = i & 63;
        sW1T[col * 36 + k] = f2bf(W1[i]);
        int k2 = i >> 5, col2 = i & 31;
        sW2T[col2 * 68 + k2] = f2bf(W2[i]);
    }
    if (tid < DD) {
        float mean = stats[tid] * (1.f / 32768.f);
        float var  = stats[DD + tid] * (1.f / 32768.f) - mean * mean;
        sc[tid] = rsqrtf(var + 1e-5f) * g1[tid];
        sm[tid] = mean; sbe[tid] = be1[tid]; sb2v[tid] = fb2[tid];
    }
    if (tid < FFD) sb1v[tid] = fb1[tid];
    __syncthreads();
    size_t node0 = (size_t)blockIdx.x * 64;
    {   // phase 1: x1 = BN1(t) -> LDS (bf16 + f32)
        int row = tid >> 2, cb = (tid & 3) * 8;
        const float* tp = &t[(node0 + row) * DD + cb];
        float4 a = *(const float4*)tp;
        float4 bq = *(const float4*)(tp + 4);
        float v0 = (a.x - sm[cb + 0]) * sc[cb + 0] + sbe[cb + 0];
        float v1 = (a.y - sm[cb + 1]) * sc[cb + 1] + sbe[cb + 1];
        float v2 = (a.z - sm[cb + 2]) * sc[cb + 2] + sbe[cb + 2];
        float v3 = (a.w - sm[cb + 3]) * sc[cb + 3] + sbe[cb + 3];
        float v4 = (bq.x - sm[cb + 4]) * sc[cb + 4] + sbe[cb + 4];
        float v5 = (bq.y - sm[cb + 5]) * sc[cb + 5] + sbe[cb + 5];
        float v6 = (bq.z - sm[cb + 6]) * sc[cb + 6] + sbe[cb + 6];
        float v7 = (bq.w - sm[cb + 7]) * sc[cb + 7] + sbe[cb + 7];
        float* xf = &x1f[row * 33 + cb];
        xf[0] = v0; xf[1] = v1; xf[2] = v2; xf[3] = v3;
        xf[4] = v4; xf[5] = v5; xf[6] = v6; xf[7] = v7;
        bf16x4 p0; p0.x = f2bf(v0); p0.y = f2bf(v1); p0.z = f2bf(v2); p0.w = f2bf(v3);
        bf16x4 p1; p1.x = f2bf(v4); p1.y = f2bf(v5); p1.z = f2bf(v6); p1.w = f2bf(v7);
        *(bf16x4*)&x1b[row * 36 + cb] = p0;
        *(bf16x4*)&x1b[row * 36 + cb + 4] = p1;
    }
    __syncthreads();
    int w = tid >> 6, lane = tid & 63, c = lane & 15, g = lane >> 4;
    // phase 2: mid = relu(x1@W1 + b1); wave w -> rows w*16..+15, 4 col tiles.
    f32x4 m0 = {0.f, 0.f, 0.f, 0.f}, m1 = m0, m2 = m0, m3 = m0;
    #pragma unroll
    for (int ks = 0; ks < 2; ++ks) {
        bf16x4 af = *(const bf16x4*)&x1b[(w * 16 + c) * 36 + ks * 16 + g * 4];
        mfma16(m0, af, *(const bf16x4*)&sW1T[(c) * 36 + ks * 16 + g * 4]);
        mfma16(m1, af, *(const bf16x4*)&sW1T[(16 + c) * 36 + ks * 16 + g * 4]);
        mfma16(m2, af, *(const bf16x4*)&sW1T[(32 + c) * 36 + ks * 16 + g * 4]);
        mfma16(m3, af, *(const bf16x4*)&sW1T[(48 + c) * 36 + ks * 16 + g * 4]);
    }
    {
        float b0 = sb1v[c], b1 = sb1v[16 + c], b2 = sb1v[32 + c], b3 = sb1v[48 + c];
        #pragma unroll
        for (int r = 0; r < 4; ++r) {
            short* hr = &hm[(w * 16 + g * 4 + r) * 68];
            hr[c]      = f2bf(fmaxf(m0[r] + b0, 0.f));
            hr[16 + c] = f2bf(fmaxf(m1[r] + b1, 0.f));
            hr[32 + c] = f2bf(fmaxf(m2[r] + b2, 0.f));
            hr[48 + c] = f2bf(fmaxf(m3[r] + b3, 0.f));
        }
    }
    __syncthreads();
    // phase 3: f = mid@W2 + b2 ; t2 = x1 + f ; stats.
    f32x4 f0 = {0.f, 0.f, 0.f, 0.f}, f1 = f0;
    #pragma unroll
    for (int ks = 0; ks < 4; ++ks) {
        bf16x4 af = *(const bf16x4*)&hm[(w * 16 + c) * 68 + ks * 16 + g * 4];
        mfma16(f0, af, *(const bf16x4*)&sW2T[(c) * 68 + ks * 16 + g * 4]);
        mfma16(f1, af, *(const bf16x4*)&sW2T[(16 + c) * 68 + ks * 16 + g * 4]);
    }
    float ls0 = 0.f, lq0 = 0.f, ls1 = 0.f, lq1 = 0.f;
    float bb0 = sb2v[c], bb1 = sb2v[16 + c];
    #pragma unroll
    for (int r = 0; r < 4; ++r) {
        int row = w * 16 + g * 4 + r;
        float tv0 = x1f[row * 33 + c] + f0[r] + bb0;
        t2[(node0 + row) * DD + c] = tv0;
        ls0 += tv0; lq0 += tv0 * tv0;
        float tv1 = x1f[row * 33 + 16 + c] + f1[r] + bb1;
        t2[(node0 + row) * DD + 16 + c] = tv1;
        ls1 += tv1; lq1 += tv1 * tv1;
    }
    ls0 += __shfl_xor(ls0, 16, 64); ls0 += __shfl_xor(ls0, 32, 64);
    lq0 += __shfl_xor(lq0, 16, 64); lq0 += __shfl_xor(lq0, 32, 64);
    ls1 += __shfl_xor(ls1, 16, 64); ls1 += __shfl_xor(ls1, 32, 64);
    lq1 += __shfl_xor(lq1, 16, 64); lq1 += __shfl_xor(lq1, 32, 64);
    if (g == 0) {
        rs[w][c] = ls0; rs[w][16 + c] = ls1;
        rq[w][c] = lq0; rq[w][16 + c] = lq1;
    }
    __syncthreads();
    if (tid < DD) {
        float a = (rs[0][tid] + rs[1][tid]) + (rs[2][tid] + rs[3][tid]);
        float bsum = (rq[0][tid] + rq[1][tid]) + (rq[2][tid] + rq[3][tid]);
        atomicAdd(&stats2[tid], a);
        atomicAdd(&stats2[DD + tid], bsum);
    }
}

// ---------------------------------------------------------------------------
// x = BN2(t2) -> xb, xt; if do_proj: out = x@out_W + out_b.
// ---------------------------------------------------------------------------
__global__ __launch_bounds__(256) void k_bn2(const float* __restrict__ t2, const float* __restrict__ stats2,
                                             const float* __restrict__ g, const float* __restrict__ be,
                                             float* __restrict__ xout, float* __restrict__ xtout,
                                             const float* __restrict__ outW, const float* __restrict__ outb,
                                             float* __restrict__ fout, int do_proj) {
    __shared__ float sW[DD * DD];
    int tid = threadIdx.x;
    if (do_proj) for (int i = tid; i < DD * DD; i += 256) sW[i] = outW[i];
    __syncthreads();
    int grp = tid >> 5, lane = tid & 31;
    float mean  = stats2[lane] * (1.f / 32768.f);
    float var   = stats2[DD + lane] * (1.f / 32768.f) - mean * mean;
    float scale = rsqrtf(var + 1e-5f) * g[lane];
    float shift = be[lane];
    size_t node = (size_t)blockIdx.x * 8 + grp;
    float tv = t2[node * DD + lane];
    float xv = (tv - mean) * scale + shift;
    xout[node * DD + lane] = xv;
    int b = (int)(node >> 9), n = (int)(node & 511);
    xtout[(size_t)n * 2048 + b * DD + lane] = xv;
    if (do_proj) {
        float acc = outb[lane];
        #pragma unroll
        for (int i = 0; i < DD; ++i) acc += __shfl(xv, i, 32) * sW[i * DD + lane];
        fout[node * DD + lane] = acc;
    }
}

// ---------------------------------------------------------------------------
extern "C" void kernel_launch(void* const* d_in, const int* in_sizes, int n_in,
                              void* d_out, int out_size, void* d_ws, size_t ws_size,
                              hipStream_t stream) {
    const float* H    = (const float*)d_in[0];
    const int*   ei   = (const int*)  d_in[1];
    const float* eW1  = (const float*)d_in[2];
    const float* eb1  = (const float*)d_in[3];
    const float* eW2  = (const float*)d_in[4];
    const float* eb2  = (const float*)d_in[5];
    const float* elg  = (const float*)d_in[6];
    const float* elb  = (const float*)d_in[7];
    const float* gW   = (const float*)d_in[8];
    const float* gb   = (const float*)d_in[9];
    const float* Wq   = (const float*)d_in[10];
    const float* Wk   = (const float*)d_in[11];
    const float* Wv   = (const float*)d_in[12];
    const float* Wo   = (const float*)d_in[13];
    const float* bn1g = (const float*)d_in[14];
    const float* bn1b = (const float*)d_in[15];
    const float* fW1  = (const float*)d_in[16];
    const float* fb1  = (const float*)d_in[17];
    const float* fW2  = (const float*)d_in[18];
    const float* fb2  = (const float*)d_in[19];
    const float* bn2g = (const float*)d_in[20];
    const float* bn2b = (const float*)d_in[21];
    const float* oW   = (const float*)d_in[22];
    const float* obv  = (const float*)d_in[23];
    float* out = (float*)d_out;

    float* ws = (float*)d_ws;
    const size_t BIGSZ = (size_t)BB * NN * DD;   // 1048576 floats
    float* xb = ws;                 // batch-major x
    float* xt = ws + 1 * BIGSZ;     // node-major x
    float* hA = ws + 2 * BIGSZ;     // gnn hop1 out (node-major)
    float* hB = ws + 3 * BIGSZ;     // t2 (batch-major)
    short* qb2 = (short*)(ws + 4 * BIGSZ);   // bf16 q (2MB)
    short* kb2 = qb2 + BIGSZ;                // bf16 k (2MB)
    short* vb2 = (short*)(ws + 5 * BIGSZ);   // bf16 v (2MB)
    float* tb = ws + 7 * BIGSZ;     // t (batch-major)
    float* smalls = ws + 8 * BIGSZ;
    float* cnt_f   = smalls;                       // 512
    int*   csr_off = (int*)(smalls + 512);         // 513 (+3 pad)
    int*   csr_src = (int*)(smalls + 512 + 516);   // 8192
    float* stats   = smalls + 512 + 516 + 8192;    // 256: [l][bn1|bn2][64]

    k_csr<<<1, 512, 0, stream>>>(ei, cnt_f, csr_off, csr_src, stats);
    k_emb<<<BB * NN / 8, 256, 0, stream>>>(H, eW1, eb1, eW2, eb2, elg, elb, xb, xt);

    for (int l = 0; l < 2; ++l) {
        const float* gW0 = gW + (size_t)(l * 2 + 0) * 128 * DD;
        const float* gW1 = gW + (size_t)(l * 2 + 1) * 128 * DD;
        const float* gb0 = gb + (size_t)(l * 2 + 0) * DD;
        const float* gb1 = gb + (size_t)(l * 2 + 1) * DD;
        float* st1 = stats + l * 128;
        float* st2 = stats + l * 128 + 64;
        k_gnn<<<NN * 2, 256, 0, stream>>>(xt, hA, cnt_f, csr_off, csr_src, gW0, gb0,
                                          0, nullptr, nullptr, nullptr, nullptr,
                                          nullptr, nullptr, nullptr);
        k_gnn<<<NN * 2, 256, 0, stream>>>(hA, nullptr, cnt_f, csr_off, csr_src, gW1, gb1,
                                          1, xt, Wq + l * DD * DD, Wk + l * DD * DD,
                                          Wv + l * DD * DD, qb2, kb2, vb2);
        k_attn_proj<<<BB * 8, 256, 0, stream>>>(qb2, kb2, vb2, xb, Wo + l * DD * DD, tb, st1);
        k_ff<<<512, 256, 0, stream>>>(tb, st1, bn1g + l * DD, bn1b + l * DD,
                                      fW1 + l * DD * FFD, fb1 + l * FFD,
                                      fW2 + l * FFD * DD, fb2 + l * DD,
                                      hB, st2);
        k_bn2<<<BB * NN / 8, 256, 0, stream>>>(hB, st2, bn2g + l * DD, bn2b + l * DD,
                                               xb, xt, oW, obv, out, (l == 1) ? 1 : 0);
    }
}

// Round 7
// 204.612 us; speedup vs baseline: 2.8459x; 1.0697x over previous
//
#include <hip/hip_runtime.h>
#include <hip/hip_bf16.h>

#define BB 64
#define NN 512
#define DIN 33
#define DD 32
#define EE 8192
#define NHEADS 4
#define DH 8
#define FFD 64

typedef __attribute__((ext_vector_type(4))) float f32x4;
typedef __attribute__((ext_vector_type(4))) short bf16x4;

static __device__ __forceinline__ short f2bf(float x) {
    unsigned u = __float_as_uint(x);
    u = (u + 0x7FFFu + ((u >> 16) & 1u)) >> 16;
    return (short)u;
}

static __device__ __forceinline__ unsigned pack_trunc(float a, float b) {
    return (__float_as_uint(a) >> 16) | (__float_as_uint(b) & 0xFFFF0000u);
}

static __device__ __forceinline__ void mfma16(f32x4& d, bf16x4 a, bf16x4 b) {
#if __has_builtin(__builtin_amdgcn_mfma_f32_16x16x16bf16_1k)
    d = __builtin_amdgcn_mfma_f32_16x16x16bf16_1k(a, b, d, 0, 0, 0);
#else
    asm volatile("s_nop 1\n\tv_mfma_f32_16x16x16_bf16 %0, %1, %2, %0\n\ts_nop 7"
                 : "+v"(d) : "v"(a), "v"(b));
#endif
}

// ---------------------------------------------------------------------------
// CSR build + zero BN stats.  One block, 512 threads, parallel scan.
// ---------------------------------------------------------------------------
__global__ __launch_bounds__(512) void k_csr(const int* __restrict__ ei,
                                             float* __restrict__ cnt_f,
                                             int* __restrict__ csr_off,
                                             int* __restrict__ csr_src,
                                             float* __restrict__ stats) {
    __shared__ int cnt_s[NN];
    __shared__ int wsum[8];
    int tid = threadIdx.x;
    cnt_s[tid] = 0;
    if (tid < 256) stats[tid] = 0.f;   // [2 layers][bn1|bn2][sum|sumsq][32]
    __syncthreads();
    const int* src = ei;
    const int* dst = ei + EE;
    for (int e = tid; e < EE; e += 512) atomicAdd(&cnt_s[dst[e]], 1);
    __syncthreads();
    int c = cnt_s[tid];
    int lane = tid & 63, w = tid >> 6;
    int sc_ = c;
    #pragma unroll
    for (int off = 1; off < 64; off <<= 1) {
        int nv = __shfl_up(sc_, off, 64);
        if (lane >= off) sc_ += nv;
    }
    if (lane == 63) wsum[w] = sc_;
    __syncthreads();
    if (tid == 0) {
        int a = 0;
        #pragma unroll
        for (int i = 0; i < 8; ++i) { int t = wsum[i]; wsum[i] = a; a += t; }
    }
    __syncthreads();
    int excl = sc_ - c + wsum[w];
    cnt_f[tid] = (float)c;
    csr_off[tid] = excl;
    if (tid == 511) csr_off[NN] = excl + c;
    __syncthreads();
    cnt_s[tid] = excl;   // cursors
    __syncthreads();
    for (int e = tid; e < EE; e += 512) {
        int d = dst[e];
        int p = atomicAdd(&cnt_s[d], 1);
        csr_src[p] = src[e];
    }
}

// ---------------------------------------------------------------------------
// Embedding: relu(H@W1+b1) -> relu(@W2+b2) -> LN.  Writes xb (batch-major)
// and xt (node-major).
// ---------------------------------------------------------------------------
__global__ __launch_bounds__(256) void k_emb(const float* __restrict__ H,
                                             const float* __restrict__ W1, const float* __restrict__ b1,
                                             const float* __restrict__ W2, const float* __restrict__ b2,
                                             const float* __restrict__ g,  const float* __restrict__ be,
                                             float* __restrict__ xb, float* __restrict__ xt) {
    __shared__ float sW1[DIN * DD];
    __shared__ float sW2[DD * DD];
    __shared__ float sb1[DD], sb2[DD], sg[DD], sbe[DD];
    __shared__ float sin_[8][DIN + 3];
    int tid = threadIdx.x;
    for (int i = tid; i < DIN * DD; i += 256) sW1[i] = W1[i];
    for (int i = tid; i < DD * DD; i += 256) sW2[i] = W2[i];
    if (tid < DD) { sb1[tid] = b1[tid]; sb2[tid] = b2[tid]; sg[tid] = g[tid]; sbe[tid] = be[tid]; }
    int grp = tid >> 5, lane = tid & 31;
    size_t node = (size_t)blockIdx.x * 8 + grp;
    const float* hrow = H + node * DIN;
    sin_[grp][lane] = hrow[lane];
    if (lane == 0) sin_[grp][32] = hrow[32];
    __syncthreads();
    float acc = sb1[lane];
    #pragma unroll
    for (int i = 0; i < DIN; ++i) acc += sin_[grp][i] * sW1[i * DD + lane];
    acc = fmaxf(acc, 0.f);
    float acc2 = sb2[lane];
    #pragma unroll
    for (int i = 0; i < DD; ++i) acc2 += __shfl(acc, i, 32) * sW2[i * DD + lane];
    acc2 = fmaxf(acc2, 0.f);
    float s = acc2;
    for (int off = 16; off; off >>= 1) s += __shfl_xor(s, off, 32);
    float m = s * (1.f / 32.f);
    float dv = acc2 - m;
    float sq = dv * dv;
    for (int off = 16; off; off >>= 1) sq += __shfl_xor(sq, off, 32);
    float var = sq * (1.f / 32.f);
    float v = dv * rsqrtf(var + 1e-5f) * sg[lane] + sbe[lane];
    xb[node * DD + lane] = v;
    int b = (int)(node >> 9), n = (int)(node & 511);
    xt[(size_t)n * 2048 + b * DD + lane] = v;
}

// ---------------------------------------------------------------------------
// GNN hop 1: gather (optionally BN-normalized src) + MFMA GEMM -> ht.
// ---------------------------------------------------------------------------
__global__ __launch_bounds__(256) void k_gnn1(const float* __restrict__ src, float* __restrict__ ht,
                                              const float* __restrict__ cnt_f,
                                              const int* __restrict__ csr_off,
                                              const int* __restrict__ csr_src,
                                              const float* __restrict__ W, const float* __restrict__ bias,
                                              const float* __restrict__ bnstats,
                                              const float* __restrict__ bng, const float* __restrict__ bnb) {
    __shared__ short conc[32 * 132];
    __shared__ short sWt[32 * 132];
    __shared__ float sb[DD];
    __shared__ float scv[DD], offv[DD];
    int tid = threadIdx.x;
    int n = blockIdx.x >> 1, half = blockIdx.x & 1;
    for (int i = tid; i < 128 * DD; i += 256) {
        int k = i >> 5, d = i & 31;
        sWt[d * 132 + k] = f2bf(W[i]);
    }
    if (tid < DD) {
        sb[tid] = bias[tid];
        if (bnstats) {
            float mean = bnstats[tid] * (1.f / 32768.f);
            float var  = bnstats[DD + tid] * (1.f / 32768.f) - mean * mean;
            float sc = rsqrtf(var + 1e-5f) * bng[tid];
            scv[tid] = sc; offv[tid] = bnb[tid] - mean * sc;
        } else { scv[tid] = 1.f; offv[tid] = 0.f; }
    }
    __syncthreads();
    float4 sc4, of4;
    { int d0 = (tid * 4) & 31;
      sc4.x = scv[d0]; sc4.y = scv[d0 + 1]; sc4.z = scv[d0 + 2]; sc4.w = scv[d0 + 3];
      of4.x = offv[d0]; of4.y = offv[d0 + 1]; of4.z = offv[d0 + 2]; of4.w = offv[d0 + 3]; }
    const float* xbase = src + (size_t)half * 1024 + tid * 4;
    float4 hv = *(const float4*)&xbase[(size_t)n * 2048];
    hv.x = fmaf(hv.x, sc4.x, of4.x); hv.y = fmaf(hv.y, sc4.y, of4.y);
    hv.z = fmaf(hv.z, sc4.z, of4.z); hv.w = fmaf(hv.w, sc4.w, of4.w);
    float4 s = {0.f, 0.f, 0.f, 0.f};
    float4 mx = {-1e30f, -1e30f, -1e30f, -1e30f};
    int beg = csr_off[n], end = csr_off[n + 1];
    int idx = beg;
    for (; idx + 3 < end; idx += 4) {
        int s0 = csr_src[idx], s1 = csr_src[idx + 1], s2 = csr_src[idx + 2], s3 = csr_src[idx + 3];
        float4 v0 = *(const float4*)&xbase[(size_t)s0 * 2048];
        float4 v1 = *(const float4*)&xbase[(size_t)s1 * 2048];
        float4 v2 = *(const float4*)&xbase[(size_t)s2 * 2048];
        float4 v3 = *(const float4*)&xbase[(size_t)s3 * 2048];
        v0.x = fmaf(v0.x, sc4.x, of4.x); v0.y = fmaf(v0.y, sc4.y, of4.y);
        v0.z = fmaf(v0.z, sc4.z, of4.z); v0.w = fmaf(v0.w, sc4.w, of4.w);
        v1.x = fmaf(v1.x, sc4.x, of4.x); v1.y = fmaf(v1.y, sc4.y, of4.y);
        v1.z = fmaf(v1.z, sc4.z, of4.z); v1.w = fmaf(v1.w, sc4.w, of4.w);
        v2.x = fmaf(v2.x, sc4.x, of4.x); v2.y = fmaf(v2.y, sc4.y, of4.y);
        v2.z = fmaf(v2.z, sc4.z, of4.z); v2.w = fmaf(v2.w, sc4.w, of4.w);
        v3.x = fmaf(v3.x, sc4.x, of4.x); v3.y = fmaf(v3.y, sc4.y, of4.y);
        v3.z = fmaf(v3.z, sc4.z, of4.z); v3.w = fmaf(v3.w, sc4.w, of4.w);
        s.x += (v0.x + v1.x) + (v2.x + v3.x);
        s.y += (v0.y + v1.y) + (v2.y + v3.y);
        s.z += (v0.z + v1.z) + (v2.z + v3.z);
        s.w += (v0.w + v1.w) + (v2.w + v3.w);
        mx.x = fmaxf(fmaxf(mx.x, v0.x), fmaxf(v1.x, fmaxf(v2.x, v3.x)));
        mx.y = fmaxf(fmaxf(mx.y, v0.y), fmaxf(v1.y, fmaxf(v2.y, v3.y)));
        mx.z = fmaxf(fmaxf(mx.z, v0.z), fmaxf(v1.z, fmaxf(v2.z, v3.z)));
        mx.w = fmaxf(fmaxf(mx.w, v0.w), fmaxf(v1.w, fmaxf(v2.w, v3.w)));
    }
    for (; idx < end; ++idx) {
        int s0 = csr_src[idx];
        float4 v0 = *(const float4*)&xbase[(size_t)s0 * 2048];
        v0.x = fmaf(v0.x, sc4.x, of4.x); v0.y = fmaf(v0.y, sc4.y, of4.y);
        v0.z = fmaf(v0.z, sc4.z, of4.z); v0.w = fmaf(v0.w, sc4.w, of4.w);
        s.x += v0.x; s.y += v0.y; s.z += v0.z; s.w += v0.w;
        mx.x = fmaxf(mx.x, v0.x); mx.y = fmaxf(mx.y, v0.y);
        mx.z = fmaxf(mx.z, v0.z); mx.w = fmaxf(mx.w, v0.w);
    }
    float c = cnt_f[n];
    float rinv = 1.f / fmaxf(c, 1.f);
    if (!(c > 0.f)) { mx.x = 0.f; mx.y = 0.f; mx.z = 0.f; mx.w = 0.f; }
    int bl = tid >> 3, d0 = (tid & 7) * 4;
    short* cp = &conc[bl * 132];
    bf16x4 t;
    t.x = f2bf(hv.x); t.y = f2bf(hv.y); t.z = f2bf(hv.z); t.w = f2bf(hv.w);
    *(bf16x4*)&cp[d0] = t;
    t.x = f2bf(s.x * rinv); t.y = f2bf(s.y * rinv); t.z = f2bf(s.z * rinv); t.w = f2bf(s.w * rinv);
    *(bf16x4*)&cp[32 + d0] = t;
    t.x = f2bf(mx.x); t.y = f2bf(mx.y); t.z = f2bf(mx.z); t.w = f2bf(mx.w);
    *(bf16x4*)&cp[64 + d0] = t;
    t.x = f2bf(s.x); t.y = f2bf(s.y); t.z = f2bf(s.z); t.w = f2bf(s.w);
    *(bf16x4*)&cp[96 + d0] = t;
    __syncthreads();
    int wid = tid >> 6, lane = tid & 63;
    int cc = lane & 15, g = lane >> 4;
    int arow = (wid >> 1) * 16 + cc;
    int bcol = (wid & 1) * 16 + cc;
    f32x4 acc = {0.f, 0.f, 0.f, 0.f};
    #pragma unroll
    for (int ks = 0; ks < 8; ++ks) {
        bf16x4 af = *(const bf16x4*)&conc[arow * 132 + ks * 16 + g * 4];
        bf16x4 bfr = *(const bf16x4*)&sWt[bcol * 132 + ks * 16 + g * 4];
        mfma16(acc, af, bfr);
    }
    float bia = sb[bcol];
    int brow = (wid >> 1) * 16 + g * 4;
    float* obase = &ht[(size_t)n * 2048 + half * 1024 + bcol];
    #pragma unroll
    for (int r = 0; r < 4; ++r) {
        obase[(size_t)(brow + r) * DD] = fmaxf(acc[r] + bia, 0.f);
    }
}

// ---------------------------------------------------------------------------
// GNN hop 2 + QKV: gather from ht (no BN) + GEMM -> h (LDS only), then
// q=h@Wq (pre-scaled), k=h@Wk, v=x@Wv (x optionally BN-normalized).
// ---------------------------------------------------------------------------
__global__ __launch_bounds__(256) void k_gnn2(const float* __restrict__ hsrc,
                                              const float* __restrict__ cnt_f,
                                              const int* __restrict__ csr_off,
                                              const int* __restrict__ csr_src,
                                              const float* __restrict__ W, const float* __restrict__ bias,
                                              const float* __restrict__ xsrc,
                                              const float* __restrict__ bnstats,
                                              const float* __restrict__ bng, const float* __restrict__ bnb,
                                              const float* __restrict__ Wq, const float* __restrict__ Wk,
                                              const float* __restrict__ Wv,
                                              short* __restrict__ qb2, short* __restrict__ kb2,
                                              short* __restrict__ vb2) {
    __shared__ short conc[32 * 132];
    __shared__ short sWt[32 * 132];
    __shared__ short sWqT[32 * 36], sWkT[32 * 36], sWvT[32 * 36];
    __shared__ short h_lds[32 * 36], x_lds[32 * 36];
    __shared__ float sb[DD];
    __shared__ float scv[DD], offv[DD];
    int tid = threadIdx.x;
    int n = blockIdx.x >> 1, half = blockIdx.x & 1;
    for (int i = tid; i < 128 * DD; i += 256) {
        int k = i >> 5, d = i & 31;
        sWt[d * 132 + k] = f2bf(W[i]);
    }
    {
        const float isq = 0.35355339059327373f;
        for (int i = tid; i < 1024; i += 256) {
            int k = i >> 5, col = i & 31;
            sWqT[col * 36 + k] = f2bf(Wq[i] * isq);
            sWkT[col * 36 + k] = f2bf(Wk[i]);
            sWvT[col * 36 + k] = f2bf(Wv[i]);
        }
    }
    if (tid < DD) {
        sb[tid] = bias[tid];
        if (bnstats) {
            float mean = bnstats[tid] * (1.f / 32768.f);
            float var  = bnstats[DD + tid] * (1.f / 32768.f) - mean * mean;
            float sc = rsqrtf(var + 1e-5f) * bng[tid];
            scv[tid] = sc; offv[tid] = bnb[tid] - mean * sc;
        } else { scv[tid] = 1.f; offv[tid] = 0.f; }
    }
    __syncthreads();
    {   // x (BN-normalized) -> LDS bf16
        int bl = tid >> 3, d0 = (tid & 7) * 4;
        float4 x4 = *(const float4*)&xsrc[(size_t)n * 2048 + half * 1024 + bl * 32 + d0];
        x4.x = fmaf(x4.x, scv[d0], offv[d0]);
        x4.y = fmaf(x4.y, scv[d0 + 1], offv[d0 + 1]);
        x4.z = fmaf(x4.z, scv[d0 + 2], offv[d0 + 2]);
        x4.w = fmaf(x4.w, scv[d0 + 3], offv[d0 + 3]);
        bf16x4 xp; xp.x = f2bf(x4.x); xp.y = f2bf(x4.y); xp.z = f2bf(x4.z); xp.w = f2bf(x4.w);
        *(bf16x4*)&x_lds[bl * 36 + d0] = xp;
    }
    const float* xbase = hsrc + (size_t)half * 1024 + tid * 4;
    float4 hv = *(const float4*)&xbase[(size_t)n * 2048];
    float4 s = {0.f, 0.f, 0.f, 0.f};
    float4 mx = {-1e30f, -1e30f, -1e30f, -1e30f};
    int beg = csr_off[n], end = csr_off[n + 1];
    int idx = beg;
    for (; idx + 3 < end; idx += 4) {
        int s0 = csr_src[idx], s1 = csr_src[idx + 1], s2 = csr_src[idx + 2], s3 = csr_src[idx + 3];
        float4 v0 = *(const float4*)&xbase[(size_t)s0 * 2048];
        float4 v1 = *(const float4*)&xbase[(size_t)s1 * 2048];
        float4 v2 = *(const float4*)&xbase[(size_t)s2 * 2048];
        float4 v3 = *(const float4*)&xbase[(size_t)s3 * 2048];
        s.x += (v0.x + v1.x) + (v2.x + v3.x);
        s.y += (v0.y + v1.y) + (v2.y + v3.y);
        s.z += (v0.z + v1.z) + (v2.z + v3.z);
        s.w += (v0.w + v1.w) + (v2.w + v3.w);
        mx.x = fmaxf(fmaxf(mx.x, v0.x), fmaxf(v1.x, fmaxf(v2.x, v3.x)));
        mx.y = fmaxf(fmaxf(mx.y, v0.y), fmaxf(v1.y, fmaxf(v2.y, v3.y)));
        mx.z = fmaxf(fmaxf(mx.z, v0.z), fmaxf(v1.z, fmaxf(v2.z, v3.z)));
        mx.w = fmaxf(fmaxf(mx.w, v0.w), fmaxf(v1.w, fmaxf(v2.w, v3.w)));
    }
    for (; idx < end; ++idx) {
        int s0 = csr_src[idx];
        float4 v0 = *(const float4*)&xbase[(size_t)s0 * 2048];
        s.x += v0.x; s.y += v0.y; s.z += v0.z; s.w += v0.w;
        mx.x = fmaxf(mx.x, v0.x); mx.y = fmaxf(mx.y, v0.y);
        mx.z = fmaxf(mx.z, v0.z); mx.w = fmaxf(mx.w, v0.w);
    }
    float c = cnt_f[n];
    float rinv = 1.f / fmaxf(c, 1.f);
    if (!(c > 0.f)) { mx.x = 0.f; mx.y = 0.f; mx.z = 0.f; mx.w = 0.f; }
    int bl = tid >> 3, d0 = (tid & 7) * 4;
    short* cp = &conc[bl * 132];
    bf16x4 t;
    t.x = f2bf(hv.x); t.y = f2bf(hv.y); t.z = f2bf(hv.z); t.w = f2bf(hv.w);
    *(bf16x4*)&cp[d0] = t;
    t.x = f2bf(s.x * rinv); t.y = f2bf(s.y * rinv); t.z = f2bf(s.z * rinv); t.w = f2bf(s.w * rinv);
    *(bf16x4*)&cp[32 + d0] = t;
    t.x = f2bf(mx.x); t.y = f2bf(mx.y); t.z = f2bf(mx.z); t.w = f2bf(mx.w);
    *(bf16x4*)&cp[64 + d0] = t;
    t.x = f2bf(s.x); t.y = f2bf(s.y); t.z = f2bf(s.z); t.w = f2bf(s.w);
    *(bf16x4*)&cp[96 + d0] = t;
    __syncthreads();
    int wid = tid >> 6, lane = tid & 63;
    int cc = lane & 15, g = lane >> 4;
    int arow = (wid >> 1) * 16 + cc;
    int bcol = (wid & 1) * 16 + cc;
    f32x4 acc = {0.f, 0.f, 0.f, 0.f};
    #pragma unroll
    for (int ks = 0; ks < 8; ++ks) {
        bf16x4 af = *(const bf16x4*)&conc[arow * 132 + ks * 16 + g * 4];
        bf16x4 bfr = *(const bf16x4*)&sWt[bcol * 132 + ks * 16 + g * 4];
        mfma16(acc, af, bfr);
    }
    float bia = sb[bcol];
    int brow = (wid >> 1) * 16 + g * 4;
    #pragma unroll
    for (int r = 0; r < 4; ++r) {
        h_lds[(brow + r) * 36 + bcol] = f2bf(fmaxf(acc[r] + bia, 0.f));
    }
    __syncthreads();
    int tr = wid >> 1, tc = wid & 1;
    f32x4 qa = {0.f, 0.f, 0.f, 0.f}, ka = qa, va = qa;
    #pragma unroll
    for (int ks = 0; ks < 2; ++ks) {
        bf16x4 ha = *(const bf16x4*)&h_lds[(tr * 16 + cc) * 36 + ks * 16 + g * 4];
        bf16x4 xa = *(const bf16x4*)&x_lds[(tr * 16 + cc) * 36 + ks * 16 + g * 4];
        bf16x4 wq = *(const bf16x4*)&sWqT[(tc * 16 + cc) * 36 + ks * 16 + g * 4];
        bf16x4 wk = *(const bf16x4*)&sWkT[(tc * 16 + cc) * 36 + ks * 16 + g * 4];
        bf16x4 wv = *(const bf16x4*)&sWvT[(tc * 16 + cc) * 36 + ks * 16 + g * 4];
        mfma16(qa, ha, wq);
        mfma16(ka, ha, wk);
        mfma16(va, xa, wv);
    }
    int dcol = tc * 16 + cc;
    size_t base = ((size_t)(half * 32 + tr * 16 + g * 4) * NN + n) * DD + dcol;
    #pragma unroll
    for (int r = 0; r < 4; ++r) {
        size_t p = base + (size_t)r * (NN * DD);
        qb2[p] = f2bf(qa[r]);
        kb2[p] = f2bf(ka[r]);
        vb2[p] = f2bf(va[r]);
    }
}

// ---------------------------------------------------------------------------
// Attention + Wo projection + residual (optionally BN-normalized x) + BN1
// stats.  Block = (b, 64-q-row slice of 8), wave = head.
// ---------------------------------------------------------------------------
__global__ __launch_bounds__(256) void k_attn_proj(const short* __restrict__ qb2,
                                                   const short* __restrict__ kb2,
                                                   const short* __restrict__ vb2,
                                                   const float* __restrict__ x,
                                                   const float* __restrict__ bnstats,
                                                   const float* __restrict__ bng,
                                                   const float* __restrict__ bnb,
                                                   const float* __restrict__ Wo,
                                                   float* __restrict__ t,
                                                   float* __restrict__ stats) {
    __shared__ short Vt[NHEADS * DH * 528];
    __shared__ short Ot[64 * 36];
    __shared__ short sWoT[DD * 36];
    __shared__ float rs[4][DD], rq[4][DD];
    __shared__ float scv[DD], offv[DD];
    int bid = blockIdx.x;
    int qs = bid & 7, b = bid >> 3;
    int tid = threadIdx.x;

    for (int i = tid; i < 1024; i += 256) {
        int k = i >> 5, col = i & 31;
        sWoT[col * 36 + k] = f2bf(Wo[i]);
    }
    if (tid < DD) {
        if (bnstats) {
            float mean = bnstats[tid] * (1.f / 32768.f);
            float var  = bnstats[DD + tid] * (1.f / 32768.f) - mean * mean;
            float sc = rsqrtf(var + 1e-5f) * bng[tid];
            scv[tid] = sc; offv[tid] = bnb[tid] - mean * sc;
        } else { scv[tid] = 1.f; offv[tid] = 0.f; }
    }
    {
        size_t g0 = ((size_t)b * NN + tid * 2) * DD;
        #pragma unroll
        for (int h2 = 0; h2 < 4; ++h2) {
            uint4 v0 = *(const uint4*)&vb2[g0 + h2 * 8];
            uint4 v1 = *(const uint4*)&vb2[g0 + DD + h2 * 8];
            unsigned* vt = (unsigned*)&Vt[h2 * DH * 528];
            vt[0 * 264 + tid] = (v0.x & 0xFFFFu) | (v1.x << 16);
            vt[1 * 264 + tid] = (v0.x >> 16)     | (v1.x & 0xFFFF0000u);
            vt[2 * 264 + tid] = (v0.y & 0xFFFFu) | (v1.y << 16);
            vt[3 * 264 + tid] = (v0.y >> 16)     | (v1.y & 0xFFFF0000u);
            vt[4 * 264 + tid] = (v0.z & 0xFFFFu) | (v1.z << 16);
            vt[5 * 264 + tid] = (v0.z >> 16)     | (v1.z & 0xFFFF0000u);
            vt[6 * 264 + tid] = (v0.w & 0xFFFFu) | (v1.w << 16);
            vt[7 * 264 + tid] = (v0.w >> 16)     | (v1.w & 0xFFFF0000u);
        }
    }
    __syncthreads();

    int h = tid >> 6, lane = tid & 63;
    int c = lane & 15, g = lane >> 4;
    int c7 = c & 7;
    bf16x4 z4 = {0, 0, 0, 0};
    bf16x4 qf0 = z4, qf1 = z4, qf2 = z4, qf3 = z4;
    if (g < 2) {
        const short* qbase = &qb2[(((size_t)b * NN + qs * 64) * DD) + h * DH + g * 4];
        qf0 = *(const bf16x4*)&qbase[(size_t)(c) * DD];
        qf1 = *(const bf16x4*)&qbase[(size_t)(16 + c) * DD];
        qf2 = *(const bf16x4*)&qbase[(size_t)(32 + c) * DD];
        qf3 = *(const bf16x4*)&qbase[(size_t)(48 + c) * DD];
    }
    const short* kbase = &kb2[((size_t)b * NN) * DD + h * DH + g * 4];
    float l0 = 0.f, l1 = 0.f, l2 = 0.f, l3 = 0.f;
    f32x4 o0 = {0.f, 0.f, 0.f, 0.f}, o1 = o0, o2 = o0, o3 = o0;
    union U { unsigned u[2]; bf16x4 v4; };

    for (int kc = 0; kc < 32; ++kc) {
        bf16x4 kf = z4;
        if (g < 2) kf = *(const bf16x4*)&kbase[(size_t)(kc * 16 + c) * DD];
        bf16x4 vf = z4;
        {
            bf16x4 vl = *(const bf16x4*)&Vt[(h * DH + c7) * 528 + kc * 16 + g * 4];
            if (c < 8) vf = vl;
        }
        f32x4 st0 = {0.f, 0.f, 0.f, 0.f}, st1 = st0, st2 = st0, st3 = st0;
        mfma16(st0, kf, qf0);
        mfma16(st1, kf, qf1);
        mfma16(st2, kf, qf2);
        mfma16(st3, kf, qf3);
        {
            float p0 = __expf(st0[0]), p1 = __expf(st0[1]), p2 = __expf(st0[2]), p3 = __expf(st0[3]);
            l0 += (p0 + p1) + (p2 + p3);
            U pu; pu.u[0] = pack_trunc(p0, p1); pu.u[1] = pack_trunc(p2, p3);
            mfma16(o0, vf, pu.v4);
        }
        {
            float p0 = __expf(st1[0]), p1 = __expf(st1[1]), p2 = __expf(st1[2]), p3 = __expf(st1[3]);
            l1 += (p0 + p1) + (p2 + p3);
            U pu; pu.u[0] = pack_trunc(p0, p1); pu.u[1] = pack_trunc(p2, p3);
            mfma16(o1, vf, pu.v4);
        }
        {
            float p0 = __expf(st2[0]), p1 = __expf(st2[1]), p2 = __expf(st2[2]), p3 = __expf(st2[3]);
            l2 += (p0 + p1) + (p2 + p3);
            U pu; pu.u[0] = pack_trunc(p0, p1); pu.u[1] = pack_trunc(p2, p3);
            mfma16(o2, vf, pu.v4);
        }
        {
            float p0 = __expf(st3[0]), p1 = __expf(st3[1]), p2 = __expf(st3[2]), p3 = __expf(st3[3]);
            l3 += (p0 + p1) + (p2 + p3);
            U pu; pu.u[0] = pack_trunc(p0, p1); pu.u[1] = pack_trunc(p2, p3);
            mfma16(o3, vf, pu.v4);
        }
    }
    l0 += __shfl_xor(l0, 16, 64); l0 += __shfl_xor(l0, 32, 64);
    l1 += __shfl_xor(l1, 16, 64); l1 += __shfl_xor(l1, 32, 64);
    l2 += __shfl_xor(l2, 16, 64); l2 += __shfl_xor(l2, 32, 64);
    l3 += __shfl_xor(l3, 16, 64); l3 += __shfl_xor(l3, 32, 64);
    if (g < 2) {
        float inv0 = 1.f / l0, inv1 = 1.f / l1, inv2 = 1.f / l2, inv3 = 1.f / l3;
        int fb = h * DH + g * 4;
        #pragma unroll
        for (int r = 0; r < 4; ++r) {
            Ot[(c) * 36 + fb + r]      = f2bf(o0[r] * inv0);
            Ot[(16 + c) * 36 + fb + r] = f2bf(o1[r] * inv1);
            Ot[(32 + c) * 36 + fb + r] = f2bf(o2[r] * inv2);
            Ot[(48 + c) * 36 + fb + r] = f2bf(o3[r] * inv3);
        }
    }
    __syncthreads();
    f32x4 pa0 = {0.f, 0.f, 0.f, 0.f}, pa1 = pa0;
    #pragma unroll
    for (int ks = 0; ks < 2; ++ks) {
        bf16x4 af = *(const bf16x4*)&Ot[(h * 16 + c) * 36 + ks * 16 + g * 4];
        bf16x4 b0 = *(const bf16x4*)&sWoT[c * 36 + ks * 16 + g * 4];
        bf16x4 b1 = *(const bf16x4*)&sWoT[(16 + c) * 36 + ks * 16 + g * 4];
        mfma16(pa0, af, b0);
        mfma16(pa1, af, b1);
    }
    float sc0 = scv[c], of0 = offv[c], sc1 = scv[16 + c], of1 = offv[16 + c];
    float ls0 = 0.f, lq0 = 0.f, ls1 = 0.f, lq1 = 0.f;
    size_t rowbase = ((size_t)b * NN + qs * 64 + h * 16 + g * 4) * DD;
    #pragma unroll
    for (int r = 0; r < 4; ++r) {
        float xv0 = fmaf(x[rowbase + (size_t)r * DD + c], sc0, of0);
        float tv0 = xv0 + pa0[r];
        t[rowbase + (size_t)r * DD + c] = tv0;
        ls0 += tv0; lq0 += tv0 * tv0;
        float xv1 = fmaf(x[rowbase + (size_t)r * DD + 16 + c], sc1, of1);
        float tv1 = xv1 + pa1[r];
        t[rowbase + (size_t)r * DD + 16 + c] = tv1;
        ls1 += tv1; lq1 += tv1 * tv1;
    }
    ls0 += __shfl_xor(ls0, 16, 64); ls0 += __shfl_xor(ls0, 32, 64);
    lq0 += __shfl_xor(lq0, 16, 64); lq0 += __shfl_xor(lq0, 32, 64);
    ls1 += __shfl_xor(ls1, 16, 64); ls1 += __shfl_xor(ls1, 32, 64);
    lq1 += __shfl_xor(lq1, 16, 64); lq1 += __shfl_xor(lq1, 32, 64);
    if (g == 0) {
        rs[h][c] = ls0; rs[h][16 + c] = ls1;
        rq[h][c] = lq0; rq[h][16 + c] = lq1;
    }
    __syncthreads();
    if (tid < DD) {
        float a = (rs[0][tid] + rs[1][tid]) + (rs[2][tid] + rs[3][tid]);
        float b2 = (rq[0][tid] + rq[1][tid]) + (rq[2][tid] + rq[3][tid]);
        atomicAdd(&stats[tid], a);
        atomicAdd(&stats[DD + tid], b2);
    }
}

// ---------------------------------------------------------------------------
// FF (MFMA): x1 = BN1(t); mid = relu(x1@W1+b1); t2 = x1 + mid@W2+b2; stats2.
// Writes t2 batch-major and (optionally) node-major.
// ---------------------------------------------------------------------------
__global__ __launch_bounds__(256) void k_ff(const float* __restrict__ t, const float* __restrict__ stats,
                                            const float* __restrict__ g1, const float* __restrict__ be1,
                                            const float* __restrict__ W1, const float* __restrict__ fb1,
                                            const float* __restrict__ W2, const float* __restrict__ fb2,
                                            float* __restrict__ t2, float* __restrict__ t2n,
                                            float* __restrict__ stats2) {
    __shared__ short x1b[64 * 36];
    __shared__ float x1f[64 * 33];
    __shared__ short hm[64 * 68];      // phase2 mid (bf16); reused as f32 t2 tile
    __shared__ short sW1T[FFD * 36];
    __shared__ short sW2T[DD * 68];
    __shared__ float sc[DD], sm[DD], sbe[DD], sb2v[DD];
    __shared__ float sb1v[FFD];
    __shared__ float rs[4][DD], rq[4][DD];
    int tid = threadIdx.x;
    for (int i = tid; i < 2048; i += 256) {
        int k = i >> 6, col = i & 63;
        sW1T[col * 36 + k] = f2bf(W1[i]);
        int k2 = i >> 5, col2 = i & 31;
        sW2T[col2 * 68 + k2] = f2bf(W2[i]);
    }
    if (tid < DD) {
        float mean = stats[tid] * (1.f / 32768.f);
        float var  = stats[DD + tid] * (1.f / 32768.f) - mean * mean;
        sc[tid] = rsqrtf(var + 1e-5f) * g1[tid];
        sm[tid] = mean; sbe[tid] = be1[tid]; sb2v[tid] = fb2[tid];
    }
    if (tid < FFD) sb1v[tid] = fb1[tid];
    __syncthreads();
    size_t node0 = (size_t)blockIdx.x * 64;
    {
        int row = tid >> 2, cb = (tid & 3) * 8;
        const float* tp = &t[(node0 + row) * DD + cb];
        float4 a = *(const float4*)tp;
        float4 bq = *(const float4*)(tp + 4);
        float v0 = (a.x - sm[cb + 0]) * sc[cb + 0] + sbe[cb + 0];
        float v1 = (a.y - sm[cb + 1]) * sc[cb + 1] + sbe[cb + 1];
        float v2 = (a.z - sm[cb + 2]) * sc[cb + 2] + sbe[cb + 2];
        float v3 = (a.w - sm[cb + 3]) * sc[cb + 3] + sbe[cb + 3];
        float v4 = (bq.x - sm[cb + 4]) * sc[cb + 4] + sbe[cb + 4];
        float v5 = (bq.y - sm[cb + 5]) * sc[cb + 5] + sbe[cb + 5];
        float v6 = (bq.z - sm[cb + 6]) * sc[cb + 6] + sbe[cb + 6];
        float v7 = (bq.w - sm[cb + 7]) * sc[cb + 7] + sbe[cb + 7];
        float* xf = &x1f[row * 33 + cb];
        xf[0] = v0; xf[1] = v1; xf[2] = v2; xf[3] = v3;
        xf[4] = v4; xf[5] = v5; xf[6] = v6; xf[7] = v7;
        bf16x4 p0; p0.x = f2bf(v0); p0.y = f2bf(v1); p0.z = f2bf(v2); p0.w = f2bf(v3);
        bf16x4 p1; p1.x = f2bf(v4); p1.y = f2bf(v5); p1.z = f2bf(v6); p1.w = f2bf(v7);
        *(bf16x4*)&x1b[row * 36 + cb] = p0;
        *(bf16x4*)&x1b[row * 36 + cb + 4] = p1;
    }
    __syncthreads();
    int w = tid >> 6, lane = tid & 63, c = lane & 15, g = lane >> 4;
    f32x4 m0 = {0.f, 0.f, 0.f, 0.f}, m1 = m0, m2 = m0, m3 = m0;
    #pragma unroll
    for (int ks = 0; ks < 2; ++ks) {
        bf16x4 af = *(const bf16x4*)&x1b[(w * 16 + c) * 36 + ks * 16 + g * 4];
        mfma16(m0, af, *(const bf16x4*)&sW1T[(c) * 36 + ks * 16 + g * 4]);
        mfma16(m1, af, *(const bf16x4*)&sW1T[(16 + c) * 36 + ks * 16 + g * 4]);
        mfma16(m2, af, *(const bf16x4*)&sW1T[(32 + c) * 36 + ks * 16 + g * 4]);
        mfma16(m3, af, *(const bf16x4*)&sW1T[(48 + c) * 36 + ks * 16 + g * 4]);
    }
    {
        float b0 = sb1v[c], b1 = sb1v[16 + c], b2 = sb1v[32 + c], b3 = sb1v[48 + c];
        #pragma unroll
        for (int r = 0; r < 4; ++r) {
            short* hr = &hm[(w * 16 + g * 4 + r) * 68];
            hr[c]      = f2bf(fmaxf(m0[r] + b0, 0.f));
            hr[16 + c] = f2bf(fmaxf(m1[r] + b1, 0.f));
            hr[32 + c] = f2bf(fmaxf(m2[r] + b2, 0.f));
            hr[48 + c] = f2bf(fmaxf(m3[r] + b3, 0.f));
        }
    }
    __syncthreads();
    f32x4 f0 = {0.f, 0.f, 0.f, 0.f}, f1 = f0;
    #pragma unroll
    for (int ks = 0; ks < 4; ++ks) {
        bf16x4 af = *(const bf16x4*)&hm[(w * 16 + c) * 68 + ks * 16 + g * 4];
        mfma16(f0, af, *(const bf16x4*)&sW2T[(c) * 68 + ks * 16 + g * 4]);
        mfma16(f1, af, *(const bf16x4*)&sW2T[(16 + c) * 68 + ks * 16 + g * 4]);
    }
    __syncthreads();   // all hm reads done -> safe to reuse as f32 tile
    float* t2s = (float*)hm;
    float ls0 = 0.f, lq0 = 0.f, ls1 = 0.f, lq1 = 0.f;
    float bb0 = sb2v[c], bb1 = sb2v[16 + c];
    #pragma unroll
    for (int r = 0; r < 4; ++r) {
        int row = w * 16 + g * 4 + r;
        float tv0 = x1f[row * 33 + c] + f0[r] + bb0;
        t2[(node0 + row) * DD + c] = tv0;
        t2s[row * DD + c] = tv0;
        ls0 += tv0; lq0 += tv0 * tv0;
        float tv1 = x1f[row * 33 + 16 + c] + f1[r] + bb1;
        t2[(node0 + row) * DD + 16 + c] = tv1;
        t2s[row * DD + 16 + c] = tv1;
        ls1 += tv1; lq1 += tv1 * tv1;
    }
    ls0 += __shfl_xor(ls0, 16, 64); ls0 += __shfl_xor(ls0, 32, 64);
    lq0 += __shfl_xor(lq0, 16, 64); lq0 += __shfl_xor(lq0, 32, 64);
    ls1 += __shfl_xor(ls1, 16, 64); ls1 += __shfl_xor(ls1, 32, 64);
    lq1 += __shfl_xor(lq1, 16, 64); lq1 += __shfl_xor(lq1, 32, 64);
    if (g == 0) {
        rs[w][c] = ls0; rs[w][16 + c] = ls1;
        rq[w][c] = lq0; rq[w][16 + c] = lq1;
    }
    __syncthreads();
    if (tid < DD) {
        float a = (rs[0][tid] + rs[1][tid]) + (rs[2][tid] + rs[3][tid]);
        float bsum = (rq[0][tid] + rq[1][tid]) + (rq[2][tid] + rq[3][tid]);
        atomicAdd(&stats2[tid], a);
        atomicAdd(&stats2[DD + tid], bsum);
    }
    if (t2n) {
        int bb = (int)(node0 >> 9), nn0 = (int)(node0 & 511);
        for (int i = tid; i < 512; i += 256) {
            int row = i >> 3, c4 = i & 7;
            float4 v = *(const float4*)&t2s[row * DD + c4 * 4];
            *(float4*)&t2n[(size_t)(nn0 + row) * 2048 + bb * DD + c4 * 4] = v;
        }
    }
}

// ---------------------------------------------------------------------------
// Final: out = BN2(t2) @ out_W + out_b  (MFMA).  Block = 64 nodes.
// ---------------------------------------------------------------------------
__global__ __launch_bounds__(256) void k_out(const float* __restrict__ t2, const float* __restrict__ stats,
                                             const float* __restrict__ g2, const float* __restrict__ be2,
                                             const float* __restrict__ outW, const float* __restrict__ outb,
                                             float* __restrict__ out) {
    __shared__ short x1b[64 * 36];
    __shared__ short sWoT[DD * 36];
    __shared__ float scv[DD], offv[DD], sbo[DD];
    int tid = threadIdx.x;
    for (int i = tid; i < 1024; i += 256) {
        int k = i >> 5, col = i & 31;
        sWoT[col * 36 + k] = f2bf(outW[i]);
    }
    if (tid < DD) {
        float mean = stats[tid] * (1.f / 32768.f);
        float var  = stats[DD + tid] * (1.f / 32768.f) - mean * mean;
        float sc = rsqrtf(var + 1e-5f) * g2[tid];
        scv[tid] = sc; offv[tid] = be2[tid] - mean * sc;
        sbo[tid] = outb[tid];
    }
    __syncthreads();
    size_t node0 = (size_t)blockIdx.x * 64;
    {
        int row = tid >> 2, cb = (tid & 3) * 8;
        const float* tp = &t2[(node0 + row) * DD + cb];
        float4 a = *(const float4*)tp;
        float4 bq = *(const float4*)(tp + 4);
        bf16x4 p0, p1;
        p0.x = f2bf(fmaf(a.x, scv[cb + 0], offv[cb + 0]));
        p0.y = f2bf(fmaf(a.y, scv[cb + 1], offv[cb + 1]));
        p0.z = f2bf(fmaf(a.z, scv[cb + 2], offv[cb + 2]));
        p0.w = f2bf(fmaf(a.w, scv[cb + 3], offv[cb + 3]));
        p1.x = f2bf(fmaf(bq.x, scv[cb + 4], offv[cb + 4]));
        p1.y = f2bf(fmaf(bq.y, scv[cb + 5], offv[cb + 5]));
        p1.z = f2bf(fmaf(bq.z, scv[cb + 6], offv[cb + 6]));
        p1.w = f2bf(fmaf(bq.w, scv[cb + 7], offv[cb + 7]));
        *(bf16x4*)&x1b[row * 36 + cb] = p0;
        *(bf16x4*)&x1b[row * 36 + cb + 4] = p1;
    }
    __syncthreads();
    int w = tid >> 6, lane = tid & 63, c = lane & 15, g = lane >> 4;
    f32x4 a0 = {0.f, 0.f, 0.f, 0.f}, a1 = a0;
    #pragma unroll
    for (int ks = 0; ks < 2; ++ks) {
        bf16x4 af = *(const bf16x4*)&x1b[(w * 16 + c) * 36 + ks * 16 + g * 4];
        mfma16(a0, af, *(const bf16x4*)&sWoT[(c) * 36 + ks * 16 + g * 4]);
        mfma16(a1, af, *(const bf16x4*)&sWoT[(16 + c) * 36 + ks * 16 + g * 4]);
    }
    float b0 = sbo[c], b1 = sbo[16 + c];
    #pragma unroll
    for (int r = 0; r < 4; ++r) {
        int row = w * 16 + g * 4 + r;
        out[(node0 + row) * DD + c]      = a0[r] + b0;
        out[(node0 + row) * DD + 16 + c] = a1[r] + b1;
    }
}

// ---------------------------------------------------------------------------
extern "C" void kernel_launch(void* const* d_in, const int* in_sizes, int n_in,
                              void* d_out, int out_size, void* d_ws, size_t ws_size,
                              hipStream_t stream) {
    const float* H    = (const float*)d_in[0];
    const int*   ei   = (const int*)  d_in[1];
    const float* eW1  = (const float*)d_in[2];
    const float* eb1  = (const float*)d_in[3];
    const float* eW2  = (const float*)d_in[4];
    const float* eb2  = (const float*)d_in[5];
    const float* elg  = (const float*)d_in[6];
    const float* elb  = (const float*)d_in[7];
    const float* gW   = (const float*)d_in[8];
    const float* gb   = (const float*)d_in[9];
    const float* Wq   = (const float*)d_in[10];
    const float* Wk   = (const float*)d_in[11];
    const float* Wv   = (const float*)d_in[12];
    const float* Wo   = (const float*)d_in[13];
    const float* bn1g = (const float*)d_in[14];
    const float* bn1b = (const float*)d_in[15];
    const float* fW1  = (const float*)d_in[16];
    const float* fb1  = (const float*)d_in[17];
    const float* fW2  = (const float*)d_in[18];
    const float* fb2  = (const float*)d_in[19];
    const float* bn2g = (const float*)d_in[20];
    const float* bn2b = (const float*)d_in[21];
    const float* oW   = (const float*)d_in[22];
    const float* obv  = (const float*)d_in[23];
    float* out = (float*)d_out;

    float* ws = (float*)d_ws;
    const size_t BIGSZ = (size_t)BB * NN * DD;   // 1048576 floats
    float* xb  = ws;                  // emb batch-major
    float* xt  = ws + 1 * BIGSZ;      // emb node-major
    float* hA  = ws + 2 * BIGSZ;      // hop1 out (node-major)
    float* hB  = ws + 3 * BIGSZ;      // t2 batch-major
    short* qb2 = (short*)(ws + 4 * BIGSZ);
    short* kb2 = qb2 + BIGSZ;
    short* vb2 = (short*)(ws + 5 * BIGSZ);
    float* t2n = ws + 6 * BIGSZ;      // t2 node-major
    float* tb  = ws + 7 * BIGSZ;      // t batch-major
    float* smalls = ws + 8 * BIGSZ;
    float* cnt_f   = smalls;
    int*   csr_off = (int*)(smalls + 512);
    int*   csr_src = (int*)(smalls + 512 + 516);
    float* stats   = smalls + 512 + 516 + 8192;   // 256: [l][bn1|bn2][64]

    k_csr<<<1, 512, 0, stream>>>(ei, cnt_f, csr_off, csr_src, stats);
    k_emb<<<BB * NN / 8, 256, 0, stream>>>(H, eW1, eb1, eW2, eb2, elg, elb, xb, xt);

    for (int l = 0; l < 2; ++l) {
        const float* gW0 = gW + (size_t)(l * 2 + 0) * 128 * DD;
        const float* gW1 = gW + (size_t)(l * 2 + 1) * 128 * DD;
        const float* gb0 = gb + (size_t)(l * 2 + 0) * DD;
        const float* gb1 = gb + (size_t)(l * 2 + 1) * DD;
        float* st1 = stats + l * 128;
        float* st2 = stats + l * 128 + 64;
        const float* pstats = (l == 0) ? nullptr : stats + 64;   // bn2 stats of layer 0
        const float* pg = (l == 0) ? nullptr : bn2g;
        const float* pb = (l == 0) ? nullptr : bn2b;
        const float* gsrc = (l == 0) ? xt : t2n;
        const float* xres = (l == 0) ? xb : hB;   // residual source (batch-major)

        k_gnn1<<<NN * 2, 256, 0, stream>>>(gsrc, hA, cnt_f, csr_off, csr_src, gW0, gb0,
                                           pstats, pg, pb);
        k_gnn2<<<NN * 2, 256, 0, stream>>>(hA, cnt_f, csr_off, csr_src, gW1, gb1,
                                           gsrc, pstats, pg, pb,
                                           Wq + l * DD * DD, Wk + l * DD * DD, Wv + l * DD * DD,
                                           qb2, kb2, vb2);
        k_attn_proj<<<BB * 8, 256, 0, stream>>>(qb2, kb2, vb2, xres, pstats, pg, pb,
                                                Wo + l * DD * DD, tb, st1);
        k_ff<<<512, 256, 0, stream>>>(tb, st1, bn1g + l * DD, bn1b + l * DD,
                                      fW1 + l * DD * FFD, fb1 + l * FFD,
                                      fW2 + l * FFD * DD, fb2 + l * DD,
                                      hB, (l == 0) ? t2n : nullptr, st2);
    }
    k_out<<<512, 256, 0, stream>>>(hB, stats + 192, bn2g + DD, bn2b + DD, oW, obv, out);
}